// Round 12
// baseline (179.750 us; speedup 1.0000x reference)
//
#include <hip/hip_runtime.h>
#include <hip/hip_bf16.h>
#include <math.h>

#define NDIM 512
#define NPTS 4096
#define VZ 16

typedef __attribute__((ext_vector_type(4))) float f32x4;
typedef __attribute__((ext_vector_type(8))) short short8;

__device__ __forceinline__ const float* xrow(const float* x0, const float* x1, int r){
  return (r < 256) ? (x0 + (size_t)r * NPTS) : (x1 + (size_t)(r - 256) * NPTS);
}
__device__ __forceinline__ unsigned short f2bf(float f){
  __hip_bfloat16 h = __float2bfloat16(f);
  return *reinterpret_cast<unsigned short*>(&h);
}
__device__ __forceinline__ float bf2f(unsigned short u){
  return __uint_as_float(((unsigned int)u) << 16);
}
__device__ __forceinline__ void gload16(const void* g, void* l){
  __builtin_amdgcn_global_load_lds((const __attribute__((address_space(1))) void*)g,
                                   (__attribute__((address_space(3))) void*)l, 16, 0, 0);
}
// grid-wide barrier: all 128 blocks guaranteed co-resident (4 waves, 15KB LDS)
__device__ __forceinline__ void gsync(int* cnt, int target){
  __syncthreads();
  if (threadIdx.x == 0){
    __threadfence();
    atomicAdd(cnt, 1);
    while (__hip_atomic_load(cnt, __ATOMIC_RELAXED, __HIP_MEMORY_SCOPE_AGENT) < target){
      __builtin_amdgcn_s_sleep(8);
    }
    __threadfence();
  }
  __syncthreads();
}

// ---------------- row means of X (512 rows x 4096) ----------------
__global__ void k_rowmean(const float* __restrict__ x0, const float* __restrict__ x1,
                          float* __restrict__ mu){
  int r = blockIdx.x;
  const float4* row4 = (const float4*)xrow(x0, x1, r);
  float s = 0.f;
  for (int c = threadIdx.x; c < NPTS/4; c += 256){
    float4 v = row4[c];
    s += v.x + v.y + v.z + v.w;
  }
  __shared__ float red[256];
  red[threadIdx.x] = s; __syncthreads();
  for (int off = 128; off > 0; off >>= 1){
    if (threadIdx.x < off) red[threadIdx.x] += red[threadIdx.x + off];
    __syncthreads();
  }
  if (threadIdx.x == 0) mu[r] = red[0] * (1.0f / NPTS);
}

// ------- prep: centered X in bf16 hi/lo, both layouts -------
__global__ __launch_bounds__(256) void k_prep(const float* __restrict__ x0, const float* __restrict__ x1,
      const float* __restrict__ mu,
      unsigned short* __restrict__ Xch, unsigned short* __restrict__ Xcl,
      unsigned short* __restrict__ Xth, unsigned short* __restrict__ Xtl){
  __shared__ float tile[64][65];
  int i0 = blockIdx.x * 64, a0 = blockIdx.y * 64;
  int t = threadIdx.x;
  int r = t >> 2, cg = (t & 3) * 16;
  const float* row = xrow(x0, x1, a0 + r);
  float m = mu[a0 + r];
  unsigned short h16[16] __attribute__((aligned(16)));
  unsigned short l16[16] __attribute__((aligned(16)));
  #pragma unroll
  for (int e = 0; e < 16; e += 4){
    float4 v = *(const float4*)(row + i0 + cg + e);
    v.x -= m; v.y -= m; v.z -= m; v.w -= m;
    tile[r][cg+e] = v.x; tile[r][cg+e+1] = v.y; tile[r][cg+e+2] = v.z; tile[r][cg+e+3] = v.w;
    h16[e]   = f2bf(v.x); l16[e]   = f2bf(v.x - bf2f(h16[e]));
    h16[e+1] = f2bf(v.y); l16[e+1] = f2bf(v.y - bf2f(h16[e+1]));
    h16[e+2] = f2bf(v.z); l16[e+2] = f2bf(v.z - bf2f(h16[e+2]));
    h16[e+3] = f2bf(v.w); l16[e+3] = f2bf(v.w - bf2f(h16[e+3]));
  }
  unsigned short* dst = Xch + (size_t)(a0+r)*NPTS + i0 + cg;
  *(uint4*)dst = *(uint4*)&h16[0]; *(uint4*)(dst+8) = *(uint4*)&h16[8];
  dst = Xcl + (size_t)(a0+r)*NPTS + i0 + cg;
  *(uint4*)dst = *(uint4*)&l16[0]; *(uint4*)(dst+8) = *(uint4*)&l16[8];
  __syncthreads();
  unsigned short th[16] __attribute__((aligned(16)));
  unsigned short tl[16] __attribute__((aligned(16)));
  #pragma unroll
  for (int e = 0; e < 16; e++){
    float v = tile[cg+e][r];
    th[e] = f2bf(v); tl[e] = f2bf(v - bf2f(th[e]));
  }
  unsigned short* d2 = Xth + (size_t)(i0 + r)*NDIM + a0 + cg;
  *(uint4*)d2 = *(uint4*)&th[0]; *(uint4*)(d2+8) = *(uint4*)&th[8];
  d2 = Xtl + (size_t)(i0 + r)*NDIM + a0 + cg;
  *(uint4*)d2 = *(uint4*)&tl[0]; *(uint4*)(d2+8) = *(uint4*)&tl[8];
}

// ------- V2: 16-wave blocks, 128x128 tri-tiles x 16 K-slices, 3-buf DMA pipeline -------
__global__ __launch_bounds__(1024) void k_V2(const unsigned short* __restrict__ Xch,
        const unsigned short* __restrict__ Xcl, float* __restrict__ Vp,
        int* __restrict__ cnt){
  if (blockIdx.x == 0 && blockIdx.y == 0 && threadIdx.x == 0) *cnt = 0;  // reset gsync ctr
  int b = blockIdx.x;                  // 0..9 upper-tri tile of 4x4
  int ti = 0, rem = b;
  while (rem >= 4 - ti){ rem -= 4 - ti; ti++; }
  int tj = ti + rem;
  int i0 = ti*128, j0 = tj*128;
  int z = blockIdx.y;                  // 0..15
  size_t kbase = (size_t)z * (NPTS/VZ);  // 256-wide K slice

  __shared__ __align__(16) unsigned short SM[3][4][128*32];
  int t = threadIdx.x, lane = t & 63, wave = t >> 6;
  int wr = wave >> 2, wc = wave & 3;
  f32x4 acc[2][2];
  #pragma unroll
  for (int a = 0; a < 2; a++)
    #pragma unroll
    for (int c = 0; c < 2; c++) acc[a][c] = (f32x4){0.f,0.f,0.f,0.f};

  int srow = lane >> 2;
  int sgk  = (lane & 3) ^ ((srow >> 1) & 3);
  int lrow = lane & 15, glog = lane >> 4;

  int sl0 = wave*2, sl1 = wave*2 + 1;
  int m0 = sl0 >> 3, g0 = sl0 & 7;
  int m1 = sl1 >> 3, g1 = sl1 & 7;
  const unsigned short* b0 = (m0 & 1) ? Xcl : Xch;
  const unsigned short* b1 = (m1 & 1) ? Xcl : Xch;
  int r0 = ((m0 < 2) ? i0 : j0) + g0*16 + srow;
  int r1 = ((m1 < 2) ? i0 : j0) + g1*16 + srow;
  const unsigned short* src0 = b0 + (size_t)r0*NPTS + kbase + sgk*8;
  const unsigned short* src1 = b1 + (size_t)r1*NPTS + kbase + sgk*8;

  #define VISSUE(batch) { int kb = (batch)*32; int bf = (batch)%3; \
    gload16(src0 + kb, &SM[bf][m0][g0*512]); \
    gload16(src1 + kb, &SM[bf][m1][g1*512]); }

  VISSUE(0); VISSUE(1);
  for (int kt = 0; kt < 8; kt++){
    int bf = kt % 3;
    if (kt + 2 < 8) VISSUE(kt + 2);
    if (kt < 6)       { asm volatile("s_waitcnt vmcnt(4)" ::: "memory"); }
    else if (kt == 6) { asm volatile("s_waitcnt vmcnt(2)" ::: "memory"); }
    else              { asm volatile("s_waitcnt vmcnt(0)" ::: "memory"); }
    __builtin_amdgcn_sched_barrier(0);
    __builtin_amdgcn_s_barrier();
    __builtin_amdgcn_sched_barrier(0);

    short8 ah[2], al[2], bh[2], bl[2];
    #pragma unroll
    for (int f = 0; f < 2; f++){
      int fra = wr*32 + f*16 + lrow;
      int offa = fra*32 + ((glog ^ ((fra>>1)&3))<<3);
      ah[f] = *(const short8*)&SM[bf][0][offa];
      al[f] = *(const short8*)&SM[bf][1][offa];
      int frb = wc*32 + f*16 + lrow;
      int offb = frb*32 + ((glog ^ ((frb>>1)&3))<<3);
      bh[f] = *(const short8*)&SM[bf][2][offb];
      bl[f] = *(const short8*)&SM[bf][3][offb];
    }
    #pragma unroll
    for (int fi = 0; fi < 2; fi++)
      #pragma unroll
      for (int fj = 0; fj < 2; fj++){
        acc[fi][fj] = __builtin_amdgcn_mfma_f32_16x16x32_bf16(ah[fi], bh[fj], acc[fi][fj], 0,0,0);
        acc[fi][fj] = __builtin_amdgcn_mfma_f32_16x16x32_bf16(ah[fi], bl[fj], acc[fi][fj], 0,0,0);
        acc[fi][fj] = __builtin_amdgcn_mfma_f32_16x16x32_bf16(al[fi], bh[fj], acc[fi][fj], 0,0,0);
      }
    __builtin_amdgcn_sched_barrier(0);
    __builtin_amdgcn_s_barrier();
  }
  #undef VISSUE

  float* dst = Vp + (size_t)z*NDIM*NDIM;
  #pragma unroll
  for (int fi = 0; fi < 2; fi++)
    #pragma unroll
    for (int fj = 0; fj < 2; fj++)
      #pragma unroll
      for (int e = 0; e < 4; e++){
        int gi = i0 + wr*32 + fi*16 + (lane>>4)*4 + e;
        int gj = j0 + wc*32 + fj*16 + lrow;
        dst[(size_t)gi*NDIM + gj] = acc[fi][fj][e];
        if (ti != tj) dst[(size_t)gj*NDIM + gi] = acc[fi][fj][e];
      }
}

// ------- fused Newton chain: finVinit -> 3x NS -> resid -> final, one launch -------
__global__ __launch_bounds__(256) void k_newton(const float* __restrict__ Vp,
      unsigned short* __restrict__ Vh, unsigned short* __restrict__ Vl,
      unsigned short* __restrict__ E0, unsigned short* __restrict__ E1,
      unsigned short* __restrict__ P0, unsigned short* __restrict__ P1,
      unsigned short* __restrict__ Rh, unsigned short* __restrict__ Rl,
      unsigned short* __restrict__ VIh, unsigned short* __restrict__ VIl,
      int* __restrict__ cnt){
  __shared__ __align__(16) unsigned short SA[64*40], SB[64*40], SC[64*40];
  int t = threadIdx.x, lane = t & 63, wave = t >> 6;
  int blk = blockIdx.x;                 // 0..127
  int wr = wave >> 1, wc = wave & 1;
  int lrow = lane & 15, kc = (lane>>4)*8;
  int rS = t >> 2, c8 = (t & 3)*8;      // staging coords (256 thr)

  // ---- stage A: V = sum(Vp)/4095; Vh/Vl; E0 = I-cV; P0 = cI.  4 rows/block ----
  {
    const float cc = 0.869565217f;
    int r = blk*4 + wave;
    const size_t S = (size_t)NDIM*NDIM;
    float a[8] = {0,0,0,0,0,0,0,0};
    #pragma unroll
    for (int z = 0; z < VZ; z++){
      const float* p = Vp + z*S + (size_t)r*NDIM + lane*8;
      float4 u = *(const float4*)p;
      float4 v = *(const float4*)(p+4);
      a[0]+=u.x; a[1]+=u.y; a[2]+=u.z; a[3]+=u.w;
      a[4]+=v.x; a[5]+=v.y; a[6]+=v.z; a[7]+=v.w;
    }
    const float s = 1.0f/4095.0f;
    unsigned short vh[8] __attribute__((aligned(16))), vl[8] __attribute__((aligned(16)));
    unsigned short e8[8] __attribute__((aligned(16))), p8[8] __attribute__((aligned(16)));
    #pragma unroll
    for (int e = 0; e < 8; e++){
      float v = a[e]*s;
      vh[e] = f2bf(v); vl[e] = f2bf(v - bf2f(vh[e]));
      int col = lane*8 + e;
      e8[e] = f2bf(((col==r)?1.f:0.f) - cc*v);
      p8[e] = f2bf((col==r)?cc:0.f);
    }
    size_t o = (size_t)r*NDIM + lane*8;
    *(uint4*)&Vh[o] = *(uint4*)vh; *(uint4*)&Vl[o] = *(uint4*)vl;
    *(uint4*)&E0[o] = *(uint4*)e8; *(uint4*)&P0[o] = *(uint4*)p8;
  }
  gsync(cnt, 128);

  // ---- stage B: 3 fused NS iterations ----
  unsigned short *Ec = E0, *En = E1, *Pc = P0, *Pn = P1;
  for (int it = 0; it < 3; ++it){
    int half = blk >> 6, tile = blk & 63;
    int i0 = (tile>>3)*64, j0 = (tile&7)*64;
    const unsigned short* Asrc = half ? Pc : Ec;
    f32x4 acc[2][2];
    #pragma unroll
    for (int a = 0; a < 2; a++)
      #pragma unroll
      for (int c = 0; c < 2; c++) acc[a][c] = (f32x4){0.f,0.f,0.f,0.f};
    const unsigned short* pA = Asrc + (size_t)(i0+rS)*NDIM + c8;
    const unsigned short* pB = Ec + (size_t)(j0+rS)*NDIM + c8;
    uint4 ra = *(const uint4*)pA, rb = *(const uint4*)pB;
    for (int kt = 0; kt < 16; kt++){
      *(uint4*)&SA[rS*40 + c8] = ra;
      *(uint4*)&SB[rS*40 + c8] = rb;
      __syncthreads();
      if (kt < 15){
        pA += 32; pB += 32;
        ra = *(const uint4*)pA; rb = *(const uint4*)pB;
      }
      short8 fa[2], fb[2];
      #pragma unroll
      for (int f = 0; f < 2; f++){
        fa[f] = *(const short8*)&SA[(wr*32 + f*16 + lrow)*40 + kc];
        fb[f] = *(const short8*)&SB[(wc*32 + f*16 + lrow)*40 + kc];
      }
      #pragma unroll
      for (int fi = 0; fi < 2; fi++)
        #pragma unroll
        for (int fj = 0; fj < 2; fj++)
          acc[fi][fj] = __builtin_amdgcn_mfma_f32_16x16x32_bf16(fa[fi], fb[fj], acc[fi][fj], 0,0,0);
      __syncthreads();
    }
    #pragma unroll
    for (int fi = 0; fi < 2; fi++)
      #pragma unroll
      for (int fj = 0; fj < 2; fj++)
        #pragma unroll
        for (int e = 0; e < 4; e++){
          int gi = i0 + wr*32 + fi*16 + (lane>>4)*4 + e;
          int gj = j0 + wc*32 + fj*16 + lrow;
          size_t o = (size_t)gi*NDIM + gj;
          if (half) Pn[o] = f2bf(bf2f(Pc[o]) + acc[fi][fj][e]);
          else      En[o] = f2bf(acc[fi][fj][e]);
        }
    gsync(cnt, 128*(2+it));
    unsigned short* tmp;
    tmp = Ec; Ec = En; En = tmp;
    tmp = Pc; Pc = Pn; Pn = tmp;
  }

  // ---- stage C: resid R = I - (Vh+Vl)*P, stored transposed hi/lo (blocks 0-63) ----
  if (blk < 64){
    int i0 = (blk>>3)*64, j0 = (blk&7)*64;
    f32x4 acc[2][2];
    #pragma unroll
    for (int a = 0; a < 2; a++)
      #pragma unroll
      for (int c = 0; c < 2; c++) acc[a][c] = (f32x4){0.f,0.f,0.f,0.f};
    const unsigned short* pAh = Vh + (size_t)(i0+rS)*NDIM + c8;
    const unsigned short* pAl = Vl + (size_t)(i0+rS)*NDIM + c8;
    const unsigned short* pB  = Pc + (size_t)(j0+rS)*NDIM + c8;
    uint4 rah = *(const uint4*)pAh, ral = *(const uint4*)pAl, rb = *(const uint4*)pB;
    for (int kt = 0; kt < 16; kt++){
      *(uint4*)&SA[rS*40 + c8] = rah;
      *(uint4*)&SC[rS*40 + c8] = ral;
      *(uint4*)&SB[rS*40 + c8] = rb;
      __syncthreads();
      if (kt < 15){
        pAh += 32; pAl += 32; pB += 32;
        rah = *(const uint4*)pAh; ral = *(const uint4*)pAl; rb = *(const uint4*)pB;
      }
      short8 fah[2], fal[2], fb[2];
      #pragma unroll
      for (int f = 0; f < 2; f++){
        fah[f] = *(const short8*)&SA[(wr*32 + f*16 + lrow)*40 + kc];
        fal[f] = *(const short8*)&SC[(wr*32 + f*16 + lrow)*40 + kc];
        fb[f]  = *(const short8*)&SB[(wc*32 + f*16 + lrow)*40 + kc];
      }
      #pragma unroll
      for (int fi = 0; fi < 2; fi++)
        #pragma unroll
        for (int fj = 0; fj < 2; fj++){
          acc[fi][fj] = __builtin_amdgcn_mfma_f32_16x16x32_bf16(fah[fi], fb[fj], acc[fi][fj], 0,0,0);
          acc[fi][fj] = __builtin_amdgcn_mfma_f32_16x16x32_bf16(fal[fi], fb[fj], acc[fi][fj], 0,0,0);
        }
      __syncthreads();
    }
    #pragma unroll
    for (int fi = 0; fi < 2; fi++)
      #pragma unroll
      for (int fj = 0; fj < 2; fj++)
        #pragma unroll
        for (int e = 0; e < 4; e++){
          int gi = i0 + wr*32 + fi*16 + (lane>>4)*4 + e;
          int gj = j0 + wc*32 + fj*16 + lrow;
          float rv = ((gi==gj)?1.f:0.f) - acc[fi][fj][e];
          unsigned short hi = f2bf(rv);
          size_t o = (size_t)gj*NDIM + gi;   // transposed store
          Rh[o] = hi; Rl[o] = f2bf(rv - bf2f(hi));
        }
  }
  gsync(cnt, 128*5);

  // ---- stage D: VI = P + P*R (blocks 0-63) ----
  if (blk < 64){
    int i0 = (blk>>3)*64, j0 = (blk&7)*64;
    f32x4 acc[2][2];
    #pragma unroll
    for (int a = 0; a < 2; a++)
      #pragma unroll
      for (int c = 0; c < 2; c++) acc[a][c] = (f32x4){0.f,0.f,0.f,0.f};
    const unsigned short* pA  = Pc + (size_t)(i0+rS)*NDIM + c8;
    const unsigned short* pBh = Rh + (size_t)(j0+rS)*NDIM + c8;
    const unsigned short* pBl = Rl + (size_t)(j0+rS)*NDIM + c8;
    uint4 ra = *(const uint4*)pA, rbh = *(const uint4*)pBh, rbl = *(const uint4*)pBl;
    for (int kt = 0; kt < 16; kt++){
      *(uint4*)&SA[rS*40 + c8] = ra;
      *(uint4*)&SB[rS*40 + c8] = rbh;
      *(uint4*)&SC[rS*40 + c8] = rbl;
      __syncthreads();
      if (kt < 15){
        pA += 32; pBh += 32; pBl += 32;
        ra = *(const uint4*)pA; rbh = *(const uint4*)pBh; rbl = *(const uint4*)pBl;
      }
      short8 fa[2], fbh[2], fbl[2];
      #pragma unroll
      for (int f = 0; f < 2; f++){
        fa[f]  = *(const short8*)&SA[(wr*32 + f*16 + lrow)*40 + kc];
        fbh[f] = *(const short8*)&SB[(wc*32 + f*16 + lrow)*40 + kc];
        fbl[f] = *(const short8*)&SC[(wc*32 + f*16 + lrow)*40 + kc];
      }
      #pragma unroll
      for (int fi = 0; fi < 2; fi++)
        #pragma unroll
        for (int fj = 0; fj < 2; fj++){
          acc[fi][fj] = __builtin_amdgcn_mfma_f32_16x16x32_bf16(fa[fi], fbh[fj], acc[fi][fj], 0,0,0);
          acc[fi][fj] = __builtin_amdgcn_mfma_f32_16x16x32_bf16(fa[fi], fbl[fj], acc[fi][fj], 0,0,0);
        }
      __syncthreads();
    }
    #pragma unroll
    for (int fi = 0; fi < 2; fi++)
      #pragma unroll
      for (int fj = 0; fj < 2; fj++)
        #pragma unroll
        for (int e = 0; e < 4; e++){
          int gi = i0 + wr*32 + fi*16 + (lane>>4)*4 + e;
          int gj = j0 + wc*32 + fj*16 + lrow;
          size_t o = (size_t)gi*NDIM + gj;
          float vi = bf2f(Pc[o]) + acc[fi][fj][e];
          unsigned short hi = f2bf(vi);
          VIh[o] = hi; VIl[o] = f2bf(vi - bf2f(hi));
        }
  }
}

// ------- Z2: 16-wave, tile 128(i) x 64(a), 3-buf DMA pipeline -------
__global__ __launch_bounds__(1024) void k_gemmZ2(const unsigned short* __restrict__ Xth,
    const unsigned short* __restrict__ Xtl, const unsigned short* __restrict__ VIh,
    const unsigned short* __restrict__ VIl, unsigned short* __restrict__ Zt){
  int i0 = blockIdx.x * 128, j0 = blockIdx.y * 64;
  __shared__ __align__(16) unsigned short SMA[3][2][128*32];
  __shared__ __align__(16) unsigned short SMB[3][2][64*32];
  int t = threadIdx.x, lane = t & 63, wave = t >> 6;
  int wr = wave >> 2, wc = wave & 3;
  f32x4 acc[2];
  acc[0] = (f32x4){0.f,0.f,0.f,0.f}; acc[1] = (f32x4){0.f,0.f,0.f,0.f};

  int srow = lane >> 2;
  int sgk  = (lane & 3) ^ ((srow >> 1) & 3);
  int lrow = lane & 15, glog = lane >> 4;

  const unsigned short* srcA0 = Xth + (size_t)(i0 + (wave&7)*16 + srow)*NDIM + sgk*8;
  const unsigned short* srcA1 = Xtl + (size_t)(i0 + (wave&7)*16 + srow)*NDIM + sgk*8;
  int gB = wave & 3;
  const unsigned short* srcB = ((wave < 12) ? VIh : VIl) + (size_t)(j0 + gB*16 + srow)*NDIM + sgk*8;
  int mB = (wave < 12) ? 0 : 1;
  int gA = wave & 7;

  #define ZISSUE(batch) { int kb = (batch)*32; int bf = (batch)%3; \
    if (wave < 8){ gload16(srcA0 + kb, &SMA[bf][0][gA*512]); \
                   gload16(srcA1 + kb, &SMA[bf][1][gA*512]); } \
    else         { gload16(srcB  + kb, &SMB[bf][mB][gB*512]); } }

  ZISSUE(0); ZISSUE(1);
  for (int kt = 0; kt < 16; kt++){
    int bf = kt % 3;
    if (kt + 2 < 16) ZISSUE(kt + 2);
    if (wave < 8){
      if (kt < 14)       { asm volatile("s_waitcnt vmcnt(4)" ::: "memory"); }
      else if (kt == 14) { asm volatile("s_waitcnt vmcnt(2)" ::: "memory"); }
      else               { asm volatile("s_waitcnt vmcnt(0)" ::: "memory"); }
    } else {
      if (kt < 14)       { asm volatile("s_waitcnt vmcnt(2)" ::: "memory"); }
      else if (kt == 14) { asm volatile("s_waitcnt vmcnt(1)" ::: "memory"); }
      else               { asm volatile("s_waitcnt vmcnt(0)" ::: "memory"); }
    }
    __builtin_amdgcn_sched_barrier(0);
    __builtin_amdgcn_s_barrier();
    __builtin_amdgcn_sched_barrier(0);

    short8 ah[2], al[2], bh, bl;
    #pragma unroll
    for (int f = 0; f < 2; f++){
      int fra = wr*32 + f*16 + lrow;
      int offa = fra*32 + ((glog ^ ((fra>>1)&3))<<3);
      ah[f] = *(const short8*)&SMA[bf][0][offa];
      al[f] = *(const short8*)&SMA[bf][1][offa];
    }
    {
      int frb = wc*16 + lrow;
      int offb = frb*32 + ((glog ^ ((frb>>1)&3))<<3);
      bh = *(const short8*)&SMB[bf][0][offb];
      bl = *(const short8*)&SMB[bf][1][offb];
    }
    #pragma unroll
    for (int fi = 0; fi < 2; fi++){
      acc[fi] = __builtin_amdgcn_mfma_f32_16x16x32_bf16(ah[fi], bh, acc[fi], 0,0,0);
      acc[fi] = __builtin_amdgcn_mfma_f32_16x16x32_bf16(ah[fi], bl, acc[fi], 0,0,0);
      acc[fi] = __builtin_amdgcn_mfma_f32_16x16x32_bf16(al[fi], bh, acc[fi], 0,0,0);
    }
    __builtin_amdgcn_sched_barrier(0);
    __builtin_amdgcn_s_barrier();
  }
  #undef ZISSUE

  #pragma unroll
  for (int fi = 0; fi < 2; fi++)
    #pragma unroll
    for (int e = 0; e < 4; e++){
      int gi = i0 + wr*32 + fi*16 + (lane>>4)*4 + e;
      int gj = j0 + wc*16 + lrow;
      Zt[(size_t)gi*NDIM + gj] = f2bf(acc[fi][e]);
    }
}

// ---------------- q[i] = dot(Xth[i,:], Zt[i,:]) ----------------
__global__ void k_q(const unsigned short* __restrict__ Xt, const unsigned short* __restrict__ Zt,
                    float* __restrict__ q){
  int wave = threadIdx.x >> 6, lane = threadIdx.x & 63;
  int i = blockIdx.x * 4 + wave;
  uint4 xv = *(const uint4*)(Xt + (size_t)i*NDIM + lane*8);
  uint4 zv = *(const uint4*)(Zt + (size_t)i*NDIM + lane*8);
  const unsigned short* xs = (const unsigned short*)&xv;
  const unsigned short* zs = (const unsigned short*)&zv;
  float s = 0.f;
  #pragma unroll
  for (int e = 0; e < 8; e++) s += bf2f(xs[e]) * bf2f(zs[e]);
  #pragma unroll
  for (int off = 32; off > 0; off >>= 1) s += __shfl_down(s, off, 64);
  if (lane == 0) q[i] = s;
}

// ------- G: 16-wave (1024-thread) blocks, BK=32, 4-buffer depth-3 DMA pipeline -------
__global__ __launch_bounds__(1024) void k_G(const unsigned short* __restrict__ Xt,
        const unsigned short* __restrict__ Zt, const float* __restrict__ q,
        float* __restrict__ out){
  const int NT = NPTS/128; // 32
  int b = (int)blockIdx.x;
  b = (b & 7) * 66 + (b >> 3);
  int ti = 0, rem = b;
  while (rem >= NT - ti){ rem -= NT - ti; ti++; }
  int tj = ti + rem;
  int i0 = ti*128, j0 = tj*128;

  __shared__ __align__(16) unsigned short SMEM[2*4*128*32];
  unsigned short (*At)[128*32] = (unsigned short (*)[128*32])SMEM;
  unsigned short (*Bt)[128*32] = (unsigned short (*)[128*32])(SMEM + 4*128*32);
  float* fsm = (float*)SMEM;

  int t = threadIdx.x, lane = t & 63, wave = t >> 6;
  int wr = wave >> 2, wc = wave & 3;
  f32x4 acc[2][2];
  #pragma unroll
  for (int a = 0; a < 2; a++)
    #pragma unroll
    for (int c = 0; c < 2; c++) acc[a][c] = (f32x4){0.f,0.f,0.f,0.f};

  int srow = lane >> 2;
  int sgk  = (lane & 3) ^ ((srow >> 1) & 3);
  int lrow = lane & 15;
  int glog = lane >> 4;

  int sg = wave & 7;
  int srcrow = sg*16 + srow;
  const unsigned short* src = (wave < 8)
      ? (Xt + (size_t)(i0 + srcrow)*NDIM + sgk*8)
      : (Zt + (size_t)(j0 + srcrow)*NDIM + sgk*8);
  unsigned short (*dstb)[128*32] = (wave < 8) ? At : Bt;

  #define ISSUE(batch) { int kb = (batch)*32; int bf = (batch)&3; \
    gload16(src + kb, &dstb[bf][sg*512]); }

  ISSUE(0); ISSUE(1); ISSUE(2);

  for (int kt = 0; kt < 16; kt++){
    int cur = kt & 3;
    if (kt + 3 < 16) ISSUE(kt + 3);
    if (kt <= 12)      { asm volatile("s_waitcnt vmcnt(3)" ::: "memory"); }
    else if (kt == 13) { asm volatile("s_waitcnt vmcnt(2)" ::: "memory"); }
    else if (kt == 14) { asm volatile("s_waitcnt vmcnt(1)" ::: "memory"); }
    else               { asm volatile("s_waitcnt vmcnt(0)" ::: "memory"); }
    __builtin_amdgcn_sched_barrier(0);
    __builtin_amdgcn_s_barrier();
    __builtin_amdgcn_sched_barrier(0);

    short8 af[2], bfr[2];
    #pragma unroll
    for (int f = 0; f < 2; f++){
      int fra = wr*32 + f*16 + lrow;
      int frb = wc*32 + f*16 + lrow;
      af[f]  = *(const short8*)&At[cur][fra*32 + ((glog ^ ((fra>>1)&3))<<3)];
      bfr[f] = *(const short8*)&Bt[cur][frb*32 + ((glog ^ ((frb>>1)&3))<<3)];
    }
    #pragma unroll
    for (int fi = 0; fi < 2; fi++)
      #pragma unroll
      for (int fj = 0; fj < 2; fj++)
        acc[fi][fj] = __builtin_amdgcn_mfma_f32_16x16x32_bf16(af[fi], bfr[fj], acc[fi][fj], 0, 0, 0);

    __builtin_amdgcn_sched_barrier(0);
    __builtin_amdgcn_s_barrier();
  }
  #undef ISSUE

  #pragma unroll
  for (int fi = 0; fi < 2; fi++)
    #pragma unroll
    for (int fj = 0; fj < 2; fj++)
      #pragma unroll
      for (int e = 0; e < 4; e++){
        int r = wr*32 + fi*16 + (lane >> 4)*4 + e;
        int c = wc*32 + fj*16 + lrow;
        fsm[r*128 + c] = acc[fi][fj][e];
      }
  __syncthreads();

  #pragma unroll
  for (int i = 0; i < 8; i++){
    int row = wave*8 + i;
    int gi = i0 + row;
    float qi = q[gi];
    size_t rowbase = (size_t)gi*NPTS - ((size_t)gi*(gi+1))/2 - (size_t)gi - 1;
    float2 vv = *(float2*)&fsm[row*128 + lane*2];
    int gj0 = j0 + lane*2, gj1 = gj0 + 1;
    if (gi < gj0) out[rowbase + gj0] = sqrtf(fmaxf(qi + q[gj0] - 2.0f*vv.x, 1e-12f));
    if (gi < gj1) out[rowbase + gj1] = sqrtf(fmaxf(qi + q[gj1] - 2.0f*vv.y, 1e-12f));
  }
}

extern "C" void kernel_launch(void* const* d_in, const int* in_sizes, int n_in,
                              void* d_out, int out_size, void* d_ws, size_t ws_size,
                              hipStream_t stream) {
  (void)in_sizes; (void)n_in; (void)out_size; (void)ws_size;
  const float* x0 = (const float*)d_in[0];
  const float* x1 = (const float*)d_in[1];
  float* out = (float*)d_out;

  char* w = (char*)d_ws;
  float* mu     = (float*)w; w += 4096;
  float* q      = (float*)w; w += NPTS*4;
  int*   scnt   = (int*)w;   w += 4096;
  unsigned short* Vh = (unsigned short*)w; w += (size_t)NDIM*NDIM*2;
  unsigned short* Vl = (unsigned short*)w; w += (size_t)NDIM*NDIM*2;
  unsigned short* E0 = (unsigned short*)w; w += (size_t)NDIM*NDIM*2;
  unsigned short* E1 = (unsigned short*)w; w += (size_t)NDIM*NDIM*2;
  unsigned short* P0 = (unsigned short*)w; w += (size_t)NDIM*NDIM*2;
  unsigned short* P1 = (unsigned short*)w; w += (size_t)NDIM*NDIM*2;
  unsigned short* Xch = (unsigned short*)w; w += (size_t)NDIM*NPTS*2;
  unsigned short* Xcl = (unsigned short*)w; w += (size_t)NDIM*NPTS*2;
  unsigned short* Xth = (unsigned short*)w; w += (size_t)NDIM*NPTS*2;
  unsigned short* Xtl = (unsigned short*)w; w += (size_t)NDIM*NPTS*2;
  char* uspan = w;
  unsigned short* Rh  = (unsigned short*)uspan;
  unsigned short* Rl  = Rh + (size_t)NDIM*NDIM;
  unsigned short* VIh = Rl + (size_t)NDIM*NDIM;
  unsigned short* VIl = VIh + (size_t)NDIM*NDIM;
  unsigned short* Zt  = VIl + (size_t)NDIM*NDIM;
  float* Vp = (float*)uspan;  // VZ x 1MB partials, dead after k_newton stage A

  k_rowmean<<<dim3(512), dim3(256), 0, stream>>>(x0, x1, mu);
  k_prep<<<dim3(64,8), dim3(256), 0, stream>>>(x0, x1, mu, Xch, Xcl, Xth, Xtl);
  k_V2<<<dim3(10, VZ), dim3(1024), 0, stream>>>(Xch, Xcl, Vp, scnt);
  k_newton<<<dim3(128), dim3(256), 0, stream>>>(Vp, Vh, Vl, E0, E1, P0, P1,
                                                Rh, Rl, VIh, VIl, scnt);
  k_gemmZ2<<<dim3(32,8), dim3(1024), 0, stream>>>(Xth, Xtl, VIh, VIl, Zt);
  k_q<<<dim3(1024), dim3(256), 0, stream>>>(Xth, Zt, q);
  k_G<<<dim3(528), dim3(1024), 0, stream>>>(Xth, Zt, q, out);
}

// Round 13
// 146.337 us; speedup vs baseline: 1.2283x; 1.2283x over previous
//
#include <hip/hip_runtime.h>
#include <hip/hip_bf16.h>
#include <math.h>

#define NDIM 512
#define NPTS 4096
#define VZ 16

typedef __attribute__((ext_vector_type(4))) float f32x4;
typedef __attribute__((ext_vector_type(8))) short short8;

__device__ __forceinline__ const float* xrow(const float* x0, const float* x1, int r){
  return (r < 256) ? (x0 + (size_t)r * NPTS) : (x1 + (size_t)(r - 256) * NPTS);
}
__device__ __forceinline__ unsigned short f2bf(float f){
  __hip_bfloat16 h = __float2bfloat16(f);
  return *reinterpret_cast<unsigned short*>(&h);
}
__device__ __forceinline__ float bf2f(unsigned short u){
  return __uint_as_float(((unsigned int)u) << 16);
}
__device__ __forceinline__ void gload16(const void* g, void* l){
  __builtin_amdgcn_global_load_lds((const __attribute__((address_space(1))) void*)g,
                                   (__attribute__((address_space(3))) void*)l, 16, 0, 0);
}

// ---------------- row means of X (512 rows x 4096) ----------------
__global__ void k_rowmean(const float* __restrict__ x0, const float* __restrict__ x1,
                          float* __restrict__ mu){
  int r = blockIdx.x;
  const float4* row4 = (const float4*)xrow(x0, x1, r);
  float s = 0.f;
  for (int c = threadIdx.x; c < NPTS/4; c += 256){
    float4 v = row4[c];
    s += v.x + v.y + v.z + v.w;
  }
  __shared__ float red[256];
  red[threadIdx.x] = s; __syncthreads();
  for (int off = 128; off > 0; off >>= 1){
    if (threadIdx.x < off) red[threadIdx.x] += red[threadIdx.x + off];
    __syncthreads();
  }
  if (threadIdx.x == 0) mu[r] = red[0] * (1.0f / NPTS);
}

// ------- prep: centered X in bf16 hi/lo, both layouts -------
__global__ __launch_bounds__(256) void k_prep(const float* __restrict__ x0, const float* __restrict__ x1,
      const float* __restrict__ mu,
      unsigned short* __restrict__ Xch, unsigned short* __restrict__ Xcl,
      unsigned short* __restrict__ Xth, unsigned short* __restrict__ Xtl){
  __shared__ float tile[64][65];
  int i0 = blockIdx.x * 64, a0 = blockIdx.y * 64;
  int t = threadIdx.x;
  int r = t >> 2, cg = (t & 3) * 16;
  const float* row = xrow(x0, x1, a0 + r);
  float m = mu[a0 + r];
  unsigned short h16[16] __attribute__((aligned(16)));
  unsigned short l16[16] __attribute__((aligned(16)));
  #pragma unroll
  for (int e = 0; e < 16; e += 4){
    float4 v = *(const float4*)(row + i0 + cg + e);
    v.x -= m; v.y -= m; v.z -= m; v.w -= m;
    tile[r][cg+e] = v.x; tile[r][cg+e+1] = v.y; tile[r][cg+e+2] = v.z; tile[r][cg+e+3] = v.w;
    h16[e]   = f2bf(v.x); l16[e]   = f2bf(v.x - bf2f(h16[e]));
    h16[e+1] = f2bf(v.y); l16[e+1] = f2bf(v.y - bf2f(h16[e+1]));
    h16[e+2] = f2bf(v.z); l16[e+2] = f2bf(v.z - bf2f(h16[e+2]));
    h16[e+3] = f2bf(v.w); l16[e+3] = f2bf(v.w - bf2f(h16[e+3]));
  }
  unsigned short* dst = Xch + (size_t)(a0+r)*NPTS + i0 + cg;
  *(uint4*)dst = *(uint4*)&h16[0]; *(uint4*)(dst+8) = *(uint4*)&h16[8];
  dst = Xcl + (size_t)(a0+r)*NPTS + i0 + cg;
  *(uint4*)dst = *(uint4*)&l16[0]; *(uint4*)(dst+8) = *(uint4*)&l16[8];
  __syncthreads();
  unsigned short th[16] __attribute__((aligned(16)));
  unsigned short tl[16] __attribute__((aligned(16)));
  #pragma unroll
  for (int e = 0; e < 16; e++){
    float v = tile[cg+e][r];
    th[e] = f2bf(v); tl[e] = f2bf(v - bf2f(th[e]));
  }
  unsigned short* d2 = Xth + (size_t)(i0 + r)*NDIM + a0 + cg;
  *(uint4*)d2 = *(uint4*)&th[0]; *(uint4*)(d2+8) = *(uint4*)&th[8];
  d2 = Xtl + (size_t)(i0 + r)*NDIM + a0 + cg;
  *(uint4*)d2 = *(uint4*)&tl[0]; *(uint4*)(d2+8) = *(uint4*)&tl[8];
}

// ------- V2: 16-wave blocks, 128x128 tri-tiles x 16 K-slices, 3-buf DMA pipeline -------
__global__ __launch_bounds__(1024) void k_V2(const unsigned short* __restrict__ Xch,
        const unsigned short* __restrict__ Xcl, float* __restrict__ Vp){
  int b = blockIdx.x;                  // 0..9 upper-tri tile of 4x4
  int ti = 0, rem = b;
  while (rem >= 4 - ti){ rem -= 4 - ti; ti++; }
  int tj = ti + rem;
  int i0 = ti*128, j0 = tj*128;
  int z = blockIdx.y;                  // 0..15
  size_t kbase = (size_t)z * (NPTS/VZ);  // 256-wide K slice

  __shared__ __align__(16) unsigned short SM[3][4][128*32];
  int t = threadIdx.x, lane = t & 63, wave = t >> 6;
  int wr = wave >> 2, wc = wave & 3;
  f32x4 acc[2][2];
  #pragma unroll
  for (int a = 0; a < 2; a++)
    #pragma unroll
    for (int c = 0; c < 2; c++) acc[a][c] = (f32x4){0.f,0.f,0.f,0.f};

  int srow = lane >> 2;
  int sgk  = (lane & 3) ^ ((srow >> 1) & 3);
  int lrow = lane & 15, glog = lane >> 4;

  int sl0 = wave*2, sl1 = wave*2 + 1;
  int m0 = sl0 >> 3, g0 = sl0 & 7;
  int m1 = sl1 >> 3, g1 = sl1 & 7;
  const unsigned short* b0 = (m0 & 1) ? Xcl : Xch;
  const unsigned short* b1 = (m1 & 1) ? Xcl : Xch;
  int r0 = ((m0 < 2) ? i0 : j0) + g0*16 + srow;
  int r1 = ((m1 < 2) ? i0 : j0) + g1*16 + srow;
  const unsigned short* src0 = b0 + (size_t)r0*NPTS + kbase + sgk*8;
  const unsigned short* src1 = b1 + (size_t)r1*NPTS + kbase + sgk*8;

  #define VISSUE(batch) { int kb = (batch)*32; int bf = (batch)%3; \
    gload16(src0 + kb, &SM[bf][m0][g0*512]); \
    gload16(src1 + kb, &SM[bf][m1][g1*512]); }

  VISSUE(0); VISSUE(1);
  for (int kt = 0; kt < 8; kt++){
    int bf = kt % 3;
    if (kt + 2 < 8) VISSUE(kt + 2);
    if (kt < 6)       { asm volatile("s_waitcnt vmcnt(4)" ::: "memory"); }
    else if (kt == 6) { asm volatile("s_waitcnt vmcnt(2)" ::: "memory"); }
    else              { asm volatile("s_waitcnt vmcnt(0)" ::: "memory"); }
    __builtin_amdgcn_sched_barrier(0);
    __builtin_amdgcn_s_barrier();
    __builtin_amdgcn_sched_barrier(0);

    short8 ah[2], al[2], bh[2], bl[2];
    #pragma unroll
    for (int f = 0; f < 2; f++){
      int fra = wr*32 + f*16 + lrow;
      int offa = fra*32 + ((glog ^ ((fra>>1)&3))<<3);
      ah[f] = *(const short8*)&SM[bf][0][offa];
      al[f] = *(const short8*)&SM[bf][1][offa];
      int frb = wc*32 + f*16 + lrow;
      int offb = frb*32 + ((glog ^ ((frb>>1)&3))<<3);
      bh[f] = *(const short8*)&SM[bf][2][offb];
      bl[f] = *(const short8*)&SM[bf][3][offb];
    }
    #pragma unroll
    for (int fi = 0; fi < 2; fi++)
      #pragma unroll
      for (int fj = 0; fj < 2; fj++){
        acc[fi][fj] = __builtin_amdgcn_mfma_f32_16x16x32_bf16(ah[fi], bh[fj], acc[fi][fj], 0,0,0);
        acc[fi][fj] = __builtin_amdgcn_mfma_f32_16x16x32_bf16(ah[fi], bl[fj], acc[fi][fj], 0,0,0);
        acc[fi][fj] = __builtin_amdgcn_mfma_f32_16x16x32_bf16(al[fi], bh[fj], acc[fi][fj], 0,0,0);
      }
    __builtin_amdgcn_sched_barrier(0);
    __builtin_amdgcn_s_barrier();
  }
  #undef VISSUE

  float* dst = Vp + (size_t)z*NDIM*NDIM;
  #pragma unroll
  for (int fi = 0; fi < 2; fi++)
    #pragma unroll
    for (int fj = 0; fj < 2; fj++)
      #pragma unroll
      for (int e = 0; e < 4; e++){
        int gi = i0 + wr*32 + fi*16 + (lane>>4)*4 + e;
        int gj = j0 + wc*32 + fj*16 + lrow;
        dst[(size_t)gi*NDIM + gj] = acc[fi][fj][e];
        if (ti != tj) dst[(size_t)gj*NDIM + gi] = acc[fi][fj][e];
      }
}

// ------- finVinit: V=sum(Vp)/4095; write Vh/Vl, E0=I-cV, P0=cI -------
__global__ void k_finVinit(const float* __restrict__ Vp,
      unsigned short* __restrict__ Vh, unsigned short* __restrict__ Vl,
      unsigned short* __restrict__ E0, unsigned short* __restrict__ P0){
  const float c = 0.869565217f;
  int r = blockIdx.x, lane = threadIdx.x; // 64 threads
  const size_t S = (size_t)NDIM*NDIM;
  float a[8] = {0,0,0,0,0,0,0,0};
  #pragma unroll
  for (int z = 0; z < VZ; z++){
    const float* p = Vp + z*S + (size_t)r*NDIM + lane*8;
    float4 u = *(const float4*)p;
    float4 v = *(const float4*)(p+4);
    a[0]+=u.x; a[1]+=u.y; a[2]+=u.z; a[3]+=u.w;
    a[4]+=v.x; a[5]+=v.y; a[6]+=v.z; a[7]+=v.w;
  }
  const float s = 1.0f/4095.0f;
  unsigned short vh[8] __attribute__((aligned(16))), vl[8] __attribute__((aligned(16)));
  unsigned short e8[8] __attribute__((aligned(16))), p8[8] __attribute__((aligned(16)));
  #pragma unroll
  for (int e = 0; e < 8; e++){
    float v = a[e]*s;
    vh[e] = f2bf(v); vl[e] = f2bf(v - bf2f(vh[e]));
    int col = lane*8 + e;
    e8[e] = f2bf(((col==r)?1.f:0.f) - c*v);
    p8[e] = f2bf((col==r)?c:0.f);
  }
  size_t o = (size_t)r*NDIM + lane*8;
  *(uint4*)&Vh[o] = *(uint4*)vh; *(uint4*)&Vl[o] = *(uint4*)vl;
  *(uint4*)&E0[o] = *(uint4*)e8; *(uint4*)&P0[o] = *(uint4*)p8;
}

// ------- fused NS iteration: blocks 0-63: En = E*E ; 64-127: Pn = P + P*E -------
__global__ __launch_bounds__(256) void k_ns(const unsigned short* __restrict__ E,
      const unsigned short* __restrict__ P,
      unsigned short* __restrict__ En, unsigned short* __restrict__ Pn){
  int b = blockIdx.x;
  int half = b >> 6, tile = b & 63;
  int i0 = (tile>>3)*64, j0 = (tile&7)*64;
  const unsigned short* Asrc = half ? P : E;
  __shared__ __align__(16) unsigned short Ah[64*40], Bh[64*40];
  int t = threadIdx.x, lane = t&63, wave = t>>6;
  int wr = wave>>1, wc = wave&1;
  int lrow = lane & 15, kc = (lane>>4)*8;
  f32x4 acc[2][2];
  #pragma unroll
  for (int a = 0; a < 2; a++)
    #pragma unroll
    for (int c = 0; c < 2; c++) acc[a][c] = (f32x4){0.f,0.f,0.f,0.f};
  int r = t>>2, c8 = (t&3)*8;
  const unsigned short* pA = Asrc + (size_t)(i0+r)*NDIM + c8;
  const unsigned short* pB = E + (size_t)(j0+r)*NDIM + c8;
  uint4 ra = *(const uint4*)pA, rb = *(const uint4*)pB;
  for (int kt = 0; kt < 16; kt++){
    *(uint4*)&Ah[r*40 + c8] = ra;
    *(uint4*)&Bh[r*40 + c8] = rb;
    __syncthreads();
    if (kt < 15){
      pA += 32; pB += 32;
      ra = *(const uint4*)pA; rb = *(const uint4*)pB;
    }
    short8 fa[2], fb[2];
    #pragma unroll
    for (int f = 0; f < 2; f++){
      fa[f] = *(const short8*)&Ah[(wr*32 + f*16 + lrow)*40 + kc];
      fb[f] = *(const short8*)&Bh[(wc*32 + f*16 + lrow)*40 + kc];
    }
    #pragma unroll
    for (int fi = 0; fi < 2; fi++)
      #pragma unroll
      for (int fj = 0; fj < 2; fj++)
        acc[fi][fj] = __builtin_amdgcn_mfma_f32_16x16x32_bf16(fa[fi], fb[fj], acc[fi][fj], 0,0,0);
    __syncthreads();
  }
  #pragma unroll
  for (int fi = 0; fi < 2; fi++)
    #pragma unroll
    for (int fj = 0; fj < 2; fj++)
      #pragma unroll
      for (int e = 0; e < 4; e++){
        int gi = i0 + wr*32 + fi*16 + (lane>>4)*4 + e;
        int gj = j0 + wc*32 + fj*16 + lrow;
        size_t o = (size_t)gi*NDIM + gj;
        if (half) Pn[o] = f2bf(bf2f(P[o]) + acc[fi][fj][e]);
        else      En[o] = f2bf(acc[fi][fj][e]);
      }
}

// ------- resid: R = I - (Vh+Vl)*P, stored TRANSPOSED as hi/lo bf16 -------
__global__ __launch_bounds__(256) void k_resid(const unsigned short* __restrict__ Vh,
      const unsigned short* __restrict__ Vl, const unsigned short* __restrict__ P,
      unsigned short* __restrict__ Rh, unsigned short* __restrict__ Rl){
  int b = blockIdx.x;
  int i0 = (b>>3)*64, j0 = (b&7)*64;
  __shared__ __align__(16) unsigned short Ah[64*40], Al[64*40], Bh[64*40];
  int t = threadIdx.x, lane = t&63, wave = t>>6;
  int wr = wave>>1, wc = wave&1;
  int lrow = lane & 15, kc = (lane>>4)*8;
  f32x4 acc[2][2];
  #pragma unroll
  for (int a = 0; a < 2; a++)
    #pragma unroll
    for (int c = 0; c < 2; c++) acc[a][c] = (f32x4){0.f,0.f,0.f,0.f};
  int r = t>>2, c8 = (t&3)*8;
  const unsigned short* pAh = Vh + (size_t)(i0+r)*NDIM + c8;
  const unsigned short* pAl = Vl + (size_t)(i0+r)*NDIM + c8;
  const unsigned short* pB  = P  + (size_t)(j0+r)*NDIM + c8;
  uint4 rah = *(const uint4*)pAh, ral = *(const uint4*)pAl, rb = *(const uint4*)pB;
  for (int kt = 0; kt < 16; kt++){
    *(uint4*)&Ah[r*40 + c8] = rah;
    *(uint4*)&Al[r*40 + c8] = ral;
    *(uint4*)&Bh[r*40 + c8] = rb;
    __syncthreads();
    if (kt < 15){
      pAh += 32; pAl += 32; pB += 32;
      rah = *(const uint4*)pAh; ral = *(const uint4*)pAl; rb = *(const uint4*)pB;
    }
    short8 fah[2], fal[2], fb[2];
    #pragma unroll
    for (int f = 0; f < 2; f++){
      fah[f] = *(const short8*)&Ah[(wr*32 + f*16 + lrow)*40 + kc];
      fal[f] = *(const short8*)&Al[(wr*32 + f*16 + lrow)*40 + kc];
      fb[f]  = *(const short8*)&Bh[(wc*32 + f*16 + lrow)*40 + kc];
    }
    #pragma unroll
    for (int fi = 0; fi < 2; fi++)
      #pragma unroll
      for (int fj = 0; fj < 2; fj++){
        acc[fi][fj] = __builtin_amdgcn_mfma_f32_16x16x32_bf16(fah[fi], fb[fj], acc[fi][fj], 0,0,0);
        acc[fi][fj] = __builtin_amdgcn_mfma_f32_16x16x32_bf16(fal[fi], fb[fj], acc[fi][fj], 0,0,0);
      }
    __syncthreads();
  }
  #pragma unroll
  for (int fi = 0; fi < 2; fi++)
    #pragma unroll
    for (int fj = 0; fj < 2; fj++)
      #pragma unroll
      for (int e = 0; e < 4; e++){
        int gi = i0 + wr*32 + fi*16 + (lane>>4)*4 + e;
        int gj = j0 + wc*32 + fj*16 + lrow;
        float rv = ((gi==gj)?1.f:0.f) - acc[fi][fj][e];
        unsigned short hi = f2bf(rv);
        size_t o = (size_t)gj*NDIM + gi;   // transposed store
        Rh[o] = hi; Rl[o] = f2bf(rv - bf2f(hi));
      }
}

// ------- final: VI = P + P*R -> VIh/VIl -------
__global__ __launch_bounds__(256) void k_final(const unsigned short* __restrict__ P,
      const unsigned short* __restrict__ Rh, const unsigned short* __restrict__ Rl,
      unsigned short* __restrict__ VIh, unsigned short* __restrict__ VIl){
  int b = blockIdx.x;
  int i0 = (b>>3)*64, j0 = (b&7)*64;
  __shared__ __align__(16) unsigned short Ah[64*40], Bh[64*40], Bl[64*40];
  int t = threadIdx.x, lane = t&63, wave = t>>6;
  int wr = wave>>1, wc = wave&1;
  int lrow = lane & 15, kc = (lane>>4)*8;
  f32x4 acc[2][2];
  #pragma unroll
  for (int a = 0; a < 2; a++)
    #pragma unroll
    for (int c = 0; c < 2; c++) acc[a][c] = (f32x4){0.f,0.f,0.f,0.f};
  int r = t>>2, c8 = (t&3)*8;
  const unsigned short* pA  = P  + (size_t)(i0+r)*NDIM + c8;
  const unsigned short* pBh = Rh + (size_t)(j0+r)*NDIM + c8;
  const unsigned short* pBl = Rl + (size_t)(j0+r)*NDIM + c8;
  uint4 ra = *(const uint4*)pA, rbh = *(const uint4*)pBh, rbl = *(const uint4*)pBl;
  for (int kt = 0; kt < 16; kt++){
    *(uint4*)&Ah[r*40 + c8] = ra;
    *(uint4*)&Bh[r*40 + c8] = rbh;
    *(uint4*)&Bl[r*40 + c8] = rbl;
    __syncthreads();
    if (kt < 15){
      pA += 32; pBh += 32; pBl += 32;
      ra = *(const uint4*)pA; rbh = *(const uint4*)pBh; rbl = *(const uint4*)pBl;
    }
    short8 fa[2], fbh[2], fbl[2];
    #pragma unroll
    for (int f = 0; f < 2; f++){
      fa[f]  = *(const short8*)&Ah[(wr*32 + f*16 + lrow)*40 + kc];
      fbh[f] = *(const short8*)&Bh[(wc*32 + f*16 + lrow)*40 + kc];
      fbl[f] = *(const short8*)&Bl[(wc*32 + f*16 + lrow)*40 + kc];
    }
    #pragma unroll
    for (int fi = 0; fi < 2; fi++)
      #pragma unroll
      for (int fj = 0; fj < 2; fj++){
        acc[fi][fj] = __builtin_amdgcn_mfma_f32_16x16x32_bf16(fa[fi], fbh[fj], acc[fi][fj], 0,0,0);
        acc[fi][fj] = __builtin_amdgcn_mfma_f32_16x16x32_bf16(fa[fi], fbl[fj], acc[fi][fj], 0,0,0);
      }
    __syncthreads();
  }
  #pragma unroll
  for (int fi = 0; fi < 2; fi++)
    #pragma unroll
    for (int fj = 0; fj < 2; fj++)
      #pragma unroll
      for (int e = 0; e < 4; e++){
        int gi = i0 + wr*32 + fi*16 + (lane>>4)*4 + e;
        int gj = j0 + wc*32 + fj*16 + lrow;
        size_t o = (size_t)gi*NDIM + gj;
        float vi = bf2f(P[o]) + acc[fi][fj][e];
        unsigned short hi = f2bf(vi);
        VIh[o] = hi; VIl[o] = f2bf(vi - bf2f(hi));
      }
}

// ------- Z2: 16-wave, tile 128(i) x 64(a), 3-buf DMA pipeline -------
__global__ __launch_bounds__(1024) void k_gemmZ2(const unsigned short* __restrict__ Xth,
    const unsigned short* __restrict__ Xtl, const unsigned short* __restrict__ VIh,
    const unsigned short* __restrict__ VIl, unsigned short* __restrict__ Zt){
  int i0 = blockIdx.x * 128, j0 = blockIdx.y * 64;
  __shared__ __align__(16) unsigned short SMA[3][2][128*32];
  __shared__ __align__(16) unsigned short SMB[3][2][64*32];
  int t = threadIdx.x, lane = t & 63, wave = t >> 6;
  int wr = wave >> 2, wc = wave & 3;
  f32x4 acc[2];
  acc[0] = (f32x4){0.f,0.f,0.f,0.f}; acc[1] = (f32x4){0.f,0.f,0.f,0.f};

  int srow = lane >> 2;
  int sgk  = (lane & 3) ^ ((srow >> 1) & 3);
  int lrow = lane & 15, glog = lane >> 4;

  const unsigned short* srcA0 = Xth + (size_t)(i0 + (wave&7)*16 + srow)*NDIM + sgk*8;
  const unsigned short* srcA1 = Xtl + (size_t)(i0 + (wave&7)*16 + srow)*NDIM + sgk*8;
  int gB = wave & 3;
  const unsigned short* srcB = ((wave < 12) ? VIh : VIl) + (size_t)(j0 + gB*16 + srow)*NDIM + sgk*8;
  int mB = (wave < 12) ? 0 : 1;
  int gA = wave & 7;

  #define ZISSUE(batch) { int kb = (batch)*32; int bf = (batch)%3; \
    if (wave < 8){ gload16(srcA0 + kb, &SMA[bf][0][gA*512]); \
                   gload16(srcA1 + kb, &SMA[bf][1][gA*512]); } \
    else         { gload16(srcB  + kb, &SMB[bf][mB][gB*512]); } }

  ZISSUE(0); ZISSUE(1);
  for (int kt = 0; kt < 16; kt++){
    int bf = kt % 3;
    if (kt + 2 < 16) ZISSUE(kt + 2);
    if (wave < 8){
      if (kt < 14)       { asm volatile("s_waitcnt vmcnt(4)" ::: "memory"); }
      else if (kt == 14) { asm volatile("s_waitcnt vmcnt(2)" ::: "memory"); }
      else               { asm volatile("s_waitcnt vmcnt(0)" ::: "memory"); }
    } else {
      if (kt < 14)       { asm volatile("s_waitcnt vmcnt(2)" ::: "memory"); }
      else if (kt == 14) { asm volatile("s_waitcnt vmcnt(1)" ::: "memory"); }
      else               { asm volatile("s_waitcnt vmcnt(0)" ::: "memory"); }
    }
    __builtin_amdgcn_sched_barrier(0);
    __builtin_amdgcn_s_barrier();
    __builtin_amdgcn_sched_barrier(0);

    short8 ah[2], al[2], bh, bl;
    #pragma unroll
    for (int f = 0; f < 2; f++){
      int fra = wr*32 + f*16 + lrow;
      int offa = fra*32 + ((glog ^ ((fra>>1)&3))<<3);
      ah[f] = *(const short8*)&SMA[bf][0][offa];
      al[f] = *(const short8*)&SMA[bf][1][offa];
    }
    {
      int frb = wc*16 + lrow;
      int offb = frb*32 + ((glog ^ ((frb>>1)&3))<<3);
      bh = *(const short8*)&SMB[bf][0][offb];
      bl = *(const short8*)&SMB[bf][1][offb];
    }
    #pragma unroll
    for (int fi = 0; fi < 2; fi++){
      acc[fi] = __builtin_amdgcn_mfma_f32_16x16x32_bf16(ah[fi], bh, acc[fi], 0,0,0);
      acc[fi] = __builtin_amdgcn_mfma_f32_16x16x32_bf16(ah[fi], bl, acc[fi], 0,0,0);
      acc[fi] = __builtin_amdgcn_mfma_f32_16x16x32_bf16(al[fi], bh, acc[fi], 0,0,0);
    }
    __builtin_amdgcn_sched_barrier(0);
    __builtin_amdgcn_s_barrier();
  }
  #undef ZISSUE

  #pragma unroll
  for (int fi = 0; fi < 2; fi++)
    #pragma unroll
    for (int e = 0; e < 4; e++){
      int gi = i0 + wr*32 + fi*16 + (lane>>4)*4 + e;
      int gj = j0 + wc*16 + lrow;
      Zt[(size_t)gi*NDIM + gj] = f2bf(acc[fi][e]);
    }
}

// ---------------- q[i] = dot(Xth[i,:], Zt[i,:]) ----------------
__global__ void k_q(const unsigned short* __restrict__ Xt, const unsigned short* __restrict__ Zt,
                    float* __restrict__ q){
  int wave = threadIdx.x >> 6, lane = threadIdx.x & 63;
  int i = blockIdx.x * 4 + wave;
  uint4 xv = *(const uint4*)(Xt + (size_t)i*NDIM + lane*8);
  uint4 zv = *(const uint4*)(Zt + (size_t)i*NDIM + lane*8);
  const unsigned short* xs = (const unsigned short*)&xv;
  const unsigned short* zs = (const unsigned short*)&zv;
  float s = 0.f;
  #pragma unroll
  for (int e = 0; e < 8; e++) s += bf2f(xs[e]) * bf2f(zs[e]);
  #pragma unroll
  for (int off = 32; off > 0; off >>= 1) s += __shfl_down(s, off, 64);
  if (lane == 0) q[i] = s;
}

// ------- G3: 256x128 tiles (272 = 8*34 blocks), 16 waves, acc[4][2], 4-buf depth-3 -------
__global__ __launch_bounds__(1024) void k_G3(const unsigned short* __restrict__ Xt,
        const unsigned short* __restrict__ Zt, const float* __restrict__ q,
        float* __restrict__ out){
  int b = (int)blockIdx.x;
  b = (b & 7) * 34 + (b >> 3);          // XCD-bijective chunking (272 = 8*34)
  // tiles: I in 0..15 (256 rows), J in 0..31 (128 cols), J >= 2I; count per I = 32-2I
  int I = 0, rem = b;
  while (rem >= 32 - 2*I){ rem -= 32 - 2*I; I++; }
  int J = 2*I + rem;
  int i0 = I*256, j0 = J*128;

  // per buffer: A 256x32 (16KB) + B 128x32 (8KB); 4 buffers = 96KB
  __shared__ __align__(16) unsigned short SMEM[4*(256*32 + 128*32)];
  float* fsm = (float*)SMEM;            // epilogue: f32[128][128] (64KB)

  int t = threadIdx.x, lane = t & 63, wave = t >> 6;   // wave 0..15
  int wr = wave >> 2, wc = wave & 3;                   // 64-row x 32-col sub-tile
  f32x4 acc[4][2];
  #pragma unroll
  for (int a = 0; a < 4; a++)
    #pragma unroll
    for (int c = 0; c < 2; c++) acc[a][c] = (f32x4){0.f,0.f,0.f,0.f};

  int srow = lane >> 2;
  int sgk  = (lane & 3) ^ ((srow >> 1) & 3);
  int lrow = lane & 15;
  int glog = lane >> 4;

  // staging: A groups 0..15 (wave w), B groups 0..7 (waves 0..7)
  const unsigned short* srcA = Xt + (size_t)(i0 + wave*16 + srow)*NDIM + sgk*8;
  const unsigned short* srcB = Zt + (size_t)(j0 + (wave&7)*16 + srow)*NDIM + sgk*8;
  int gA = wave, gB = wave & 7;

  #define ISSUE(batch) { int kb = (batch)*32; int bf = (batch)&3; \
    unsigned short* base = SMEM + bf*(256*32 + 128*32); \
    gload16(srcA + kb, base + gA*512 + lane*0 + (lane*8 - lane*8) + gA*0 + 0 + ( (size_t)0 ) + ( lane*8 ) ); \
    if (wave < 8) gload16(srcB + kb, base + 256*32 + gB*512 + lane*8); }
  // NOTE: dest addr = wave-uniform base + lane*16B handled by HW; pointer passed is the group base
  #undef ISSUE
  #define ISSUE(batch) { int kb = (batch)*32; int bf = (batch)&3; \
    unsigned short* base = SMEM + bf*(256*32 + 128*32); \
    gload16(srcA + kb, base + gA*512); \
    if (wave < 8) gload16(srcB + kb, base + 256*32 + gB*512); }

  ISSUE(0); ISSUE(1); ISSUE(2);

  for (int kt = 0; kt < 16; kt++){
    int cur = kt & 3;
    if (kt + 3 < 16) ISSUE(kt + 3);
    if (wave < 8){
      if (kt <= 12)      { asm volatile("s_waitcnt vmcnt(6)" ::: "memory"); }
      else if (kt == 13) { asm volatile("s_waitcnt vmcnt(4)" ::: "memory"); }
      else if (kt == 14) { asm volatile("s_waitcnt vmcnt(2)" ::: "memory"); }
      else               { asm volatile("s_waitcnt vmcnt(0)" ::: "memory"); }
    } else {
      if (kt <= 12)      { asm volatile("s_waitcnt vmcnt(3)" ::: "memory"); }
      else if (kt == 13) { asm volatile("s_waitcnt vmcnt(2)" ::: "memory"); }
      else if (kt == 14) { asm volatile("s_waitcnt vmcnt(1)" ::: "memory"); }
      else               { asm volatile("s_waitcnt vmcnt(0)" ::: "memory"); }
    }
    __builtin_amdgcn_sched_barrier(0);
    __builtin_amdgcn_s_barrier();          // batch kt landed for all waves
    __builtin_amdgcn_sched_barrier(0);

    const unsigned short* Ab = SMEM + cur*(256*32 + 128*32);
    const unsigned short* Bb = Ab + 256*32;
    short8 af[4], bfr[2];
    #pragma unroll
    for (int f = 0; f < 4; f++){
      int fra = wr*64 + f*16 + lrow;
      af[f] = *(const short8*)&Ab[fra*32 + ((glog ^ ((fra>>1)&3))<<3)];
    }
    #pragma unroll
    for (int f = 0; f < 2; f++){
      int frb = wc*32 + f*16 + lrow;
      bfr[f] = *(const short8*)&Bb[frb*32 + ((glog ^ ((frb>>1)&3))<<3)];
    }
    #pragma unroll
    for (int fi = 0; fi < 4; fi++)
      #pragma unroll
      for (int fj = 0; fj < 2; fj++)
        acc[fi][fj] = __builtin_amdgcn_mfma_f32_16x16x32_bf16(af[fi], bfr[fj], acc[fi][fj], 0, 0, 0);

    __builtin_amdgcn_sched_barrier(0);
    __builtin_amdgcn_s_barrier();          // done reading buf[cur]
  }
  #undef ISSUE

  // ---- epilogue: two half-tiles (rows 0-127, 128-255) via LDS transpose ----
  #pragma unroll
  for (int h = 0; h < 2; h++){
    if ((wr >> 1) == h){
      #pragma unroll
      for (int fi = 0; fi < 4; fi++)
        #pragma unroll
        for (int fj = 0; fj < 2; fj++)
          #pragma unroll
          for (int e = 0; e < 4; e++){
            int r = wr*64 + fi*16 + (lane >> 4)*4 + e - h*128;
            int c = wc*32 + fj*16 + lrow;
            fsm[r*128 + c] = acc[fi][fj][e];
          }
    }
    __syncthreads();
    #pragma unroll
    for (int i = 0; i < 8; i++){
      int row = wave*8 + i;
      int gi = i0 + h*128 + row;
      float qi = q[gi];
      size_t rowbase = (size_t)gi*NPTS - ((size_t)gi*(gi+1))/2 - (size_t)gi - 1;
      float2 vv = *(float2*)&fsm[row*128 + lane*2];
      int gj0 = j0 + lane*2, gj1 = gj0 + 1;
      if (gi < gj0) out[rowbase + gj0] = sqrtf(fmaxf(qi + q[gj0] - 2.0f*vv.x, 1e-12f));
      if (gi < gj1) out[rowbase + gj1] = sqrtf(fmaxf(qi + q[gj1] - 2.0f*vv.y, 1e-12f));
    }
    __syncthreads();
  }
}

extern "C" void kernel_launch(void* const* d_in, const int* in_sizes, int n_in,
                              void* d_out, int out_size, void* d_ws, size_t ws_size,
                              hipStream_t stream) {
  (void)in_sizes; (void)n_in; (void)out_size; (void)ws_size;
  const float* x0 = (const float*)d_in[0];
  const float* x1 = (const float*)d_in[1];
  float* out = (float*)d_out;

  char* w = (char*)d_ws;
  float* mu     = (float*)w; w += 4096;
  float* q      = (float*)w; w += NPTS*4;
  unsigned short* Vh = (unsigned short*)w; w += (size_t)NDIM*NDIM*2;
  unsigned short* Vl = (unsigned short*)w; w += (size_t)NDIM*NDIM*2;
  unsigned short* E0 = (unsigned short*)w; w += (size_t)NDIM*NDIM*2;
  unsigned short* E1 = (unsigned short*)w; w += (size_t)NDIM*NDIM*2;
  unsigned short* P0 = (unsigned short*)w; w += (size_t)NDIM*NDIM*2;
  unsigned short* P1 = (unsigned short*)w; w += (size_t)NDIM*NDIM*2;
  unsigned short* Xch = (unsigned short*)w; w += (size_t)NDIM*NPTS*2;
  unsigned short* Xcl = (unsigned short*)w; w += (size_t)NDIM*NPTS*2;
  unsigned short* Xth = (unsigned short*)w; w += (size_t)NDIM*NPTS*2;
  unsigned short* Xtl = (unsigned short*)w; w += (size_t)NDIM*NPTS*2;
  char* uspan = w;
  unsigned short* Rh  = (unsigned short*)uspan;
  unsigned short* Rl  = Rh + (size_t)NDIM*NDIM;
  unsigned short* VIh = Rl + (size_t)NDIM*NDIM;
  unsigned short* VIl = VIh + (size_t)NDIM*NDIM;
  unsigned short* Zt  = VIl + (size_t)NDIM*NDIM;
  float* Vp = (float*)uspan;  // VZ x 1MB partials, dead after k_finVinit

  k_rowmean<<<dim3(512), dim3(256), 0, stream>>>(x0, x1, mu);
  k_prep<<<dim3(64,8), dim3(256), 0, stream>>>(x0, x1, mu, Xch, Xcl, Xth, Xtl);
  k_V2<<<dim3(10, VZ), dim3(1024), 0, stream>>>(Xch, Xcl, Vp);
  k_finVinit<<<dim3(512), dim3(64), 0, stream>>>(Vp, Vh, Vl, E0, P0);

  unsigned short *Ec = E0, *En = E1, *Pc = P0, *Pn = P1;
  for (int it = 0; it < 3; ++it){
    k_ns<<<dim3(128), dim3(256), 0, stream>>>(Ec, Pc, En, Pn);
    unsigned short* tmp;
    tmp = Ec; Ec = En; En = tmp;
    tmp = Pc; Pc = Pn; Pn = tmp;
  }
  k_resid<<<dim3(64), dim3(256), 0, stream>>>(Vh, Vl, Pc, Rh, Rl);
  k_final<<<dim3(64), dim3(256), 0, stream>>>(Pc, Rh, Rl, VIh, VIl);
  k_gemmZ2<<<dim3(32,8), dim3(1024), 0, stream>>>(Xth, Xtl, VIh, VIl, Zt);
  k_q<<<dim3(1024), dim3(256), 0, stream>>>(Xth, Zt, q);
  k_G3<<<dim3(272), dim3(1024), 0, stream>>>(Xth, Zt, q, out);
}

// Round 14
// 128.563 us; speedup vs baseline: 1.3981x; 1.1383x over previous
//
#include <hip/hip_runtime.h>
#include <hip/hip_bf16.h>
#include <math.h>

#define NDIM 512
#define NPTS 4096
#define VZ 16

typedef __attribute__((ext_vector_type(4))) float f32x4;
typedef __attribute__((ext_vector_type(8))) short short8;

__device__ __forceinline__ const float* xrow(const float* x0, const float* x1, int r){
  return (r < 256) ? (x0 + (size_t)r * NPTS) : (x1 + (size_t)(r - 256) * NPTS);
}
__device__ __forceinline__ unsigned short f2bf(float f){
  __hip_bfloat16 h = __float2bfloat16(f);
  return *reinterpret_cast<unsigned short*>(&h);
}
__device__ __forceinline__ float bf2f(unsigned short u){
  return __uint_as_float(((unsigned int)u) << 16);
}
__device__ __forceinline__ void gload16(const void* g, void* l){
  __builtin_amdgcn_global_load_lds((const __attribute__((address_space(1))) void*)g,
                                   (__attribute__((address_space(3))) void*)l, 16, 0, 0);
}

// ---------------- row means of X (512 rows x 4096) ----------------
__global__ void k_rowmean(const float* __restrict__ x0, const float* __restrict__ x1,
                          float* __restrict__ mu){
  int r = blockIdx.x;
  const float4* row4 = (const float4*)xrow(x0, x1, r);
  float s = 0.f;
  for (int c = threadIdx.x; c < NPTS/4; c += 256){
    float4 v = row4[c];
    s += v.x + v.y + v.z + v.w;
  }
  __shared__ float red[256];
  red[threadIdx.x] = s; __syncthreads();
  for (int off = 128; off > 0; off >>= 1){
    if (threadIdx.x < off) red[threadIdx.x] += red[threadIdx.x + off];
    __syncthreads();
  }
  if (threadIdx.x == 0) mu[r] = red[0] * (1.0f / NPTS);
}

// ------- prep: centered X in bf16 hi/lo, both layouts -------
__global__ __launch_bounds__(256) void k_prep(const float* __restrict__ x0, const float* __restrict__ x1,
      const float* __restrict__ mu,
      unsigned short* __restrict__ Xch, unsigned short* __restrict__ Xcl,
      unsigned short* __restrict__ Xth, unsigned short* __restrict__ Xtl){
  __shared__ float tile[64][65];
  int i0 = blockIdx.x * 64, a0 = blockIdx.y * 64;
  int t = threadIdx.x;
  int r = t >> 2, cg = (t & 3) * 16;
  const float* row = xrow(x0, x1, a0 + r);
  float m = mu[a0 + r];
  unsigned short h16[16] __attribute__((aligned(16)));
  unsigned short l16[16] __attribute__((aligned(16)));
  #pragma unroll
  for (int e = 0; e < 16; e += 4){
    float4 v = *(const float4*)(row + i0 + cg + e);
    v.x -= m; v.y -= m; v.z -= m; v.w -= m;
    tile[r][cg+e] = v.x; tile[r][cg+e+1] = v.y; tile[r][cg+e+2] = v.z; tile[r][cg+e+3] = v.w;
    h16[e]   = f2bf(v.x); l16[e]   = f2bf(v.x - bf2f(h16[e]));
    h16[e+1] = f2bf(v.y); l16[e+1] = f2bf(v.y - bf2f(h16[e+1]));
    h16[e+2] = f2bf(v.z); l16[e+2] = f2bf(v.z - bf2f(h16[e+2]));
    h16[e+3] = f2bf(v.w); l16[e+3] = f2bf(v.w - bf2f(h16[e+3]));
  }
  unsigned short* dst = Xch + (size_t)(a0+r)*NPTS + i0 + cg;
  *(uint4*)dst = *(uint4*)&h16[0]; *(uint4*)(dst+8) = *(uint4*)&h16[8];
  dst = Xcl + (size_t)(a0+r)*NPTS + i0 + cg;
  *(uint4*)dst = *(uint4*)&l16[0]; *(uint4*)(dst+8) = *(uint4*)&l16[8];
  __syncthreads();
  unsigned short th[16] __attribute__((aligned(16)));
  unsigned short tl[16] __attribute__((aligned(16)));
  #pragma unroll
  for (int e = 0; e < 16; e++){
    float v = tile[cg+e][r];
    th[e] = f2bf(v); tl[e] = f2bf(v - bf2f(th[e]));
  }
  unsigned short* d2 = Xth + (size_t)(i0 + r)*NDIM + a0 + cg;
  *(uint4*)d2 = *(uint4*)&th[0]; *(uint4*)(d2+8) = *(uint4*)&th[8];
  d2 = Xtl + (size_t)(i0 + r)*NDIM + a0 + cg;
  *(uint4*)d2 = *(uint4*)&tl[0]; *(uint4*)(d2+8) = *(uint4*)&tl[8];
}

// ------- V2: 16-wave blocks, 128x128 tri-tiles x 16 K-slices, 3-buf DMA pipeline -------
__global__ __launch_bounds__(1024) void k_V2(const unsigned short* __restrict__ Xch,
        const unsigned short* __restrict__ Xcl, float* __restrict__ Vp){
  int b = blockIdx.x;                  // 0..9 upper-tri tile of 4x4
  int ti = 0, rem = b;
  while (rem >= 4 - ti){ rem -= 4 - ti; ti++; }
  int tj = ti + rem;
  int i0 = ti*128, j0 = tj*128;
  int z = blockIdx.y;                  // 0..15
  size_t kbase = (size_t)z * (NPTS/VZ);  // 256-wide K slice

  __shared__ __align__(16) unsigned short SM[3][4][128*32];
  int t = threadIdx.x, lane = t & 63, wave = t >> 6;
  int wr = wave >> 2, wc = wave & 3;
  f32x4 acc[2][2];
  #pragma unroll
  for (int a = 0; a < 2; a++)
    #pragma unroll
    for (int c = 0; c < 2; c++) acc[a][c] = (f32x4){0.f,0.f,0.f,0.f};

  int srow = lane >> 2;
  int sgk  = (lane & 3) ^ ((srow >> 1) & 3);
  int lrow = lane & 15, glog = lane >> 4;

  int sl0 = wave*2, sl1 = wave*2 + 1;
  int m0 = sl0 >> 3, g0 = sl0 & 7;
  int m1 = sl1 >> 3, g1 = sl1 & 7;
  const unsigned short* b0 = (m0 & 1) ? Xcl : Xch;
  const unsigned short* b1 = (m1 & 1) ? Xcl : Xch;
  int r0 = ((m0 < 2) ? i0 : j0) + g0*16 + srow;
  int r1 = ((m1 < 2) ? i0 : j0) + g1*16 + srow;
  const unsigned short* src0 = b0 + (size_t)r0*NPTS + kbase + sgk*8;
  const unsigned short* src1 = b1 + (size_t)r1*NPTS + kbase + sgk*8;

  #define VISSUE(batch) { int kb = (batch)*32; int bf = (batch)%3; \
    gload16(src0 + kb, &SM[bf][m0][g0*512]); \
    gload16(src1 + kb, &SM[bf][m1][g1*512]); }

  VISSUE(0); VISSUE(1);
  for (int kt = 0; kt < 8; kt++){
    int bf = kt % 3;
    if (kt + 2 < 8) VISSUE(kt + 2);
    if (kt < 6)       { asm volatile("s_waitcnt vmcnt(4)" ::: "memory"); }
    else if (kt == 6) { asm volatile("s_waitcnt vmcnt(2)" ::: "memory"); }
    else              { asm volatile("s_waitcnt vmcnt(0)" ::: "memory"); }
    __builtin_amdgcn_sched_barrier(0);
    __builtin_amdgcn_s_barrier();
    __builtin_amdgcn_sched_barrier(0);

    short8 ah[2], al[2], bh[2], bl[2];
    #pragma unroll
    for (int f = 0; f < 2; f++){
      int fra = wr*32 + f*16 + lrow;
      int offa = fra*32 + ((glog ^ ((fra>>1)&3))<<3);
      ah[f] = *(const short8*)&SM[bf][0][offa];
      al[f] = *(const short8*)&SM[bf][1][offa];
      int frb = wc*32 + f*16 + lrow;
      int offb = frb*32 + ((glog ^ ((frb>>1)&3))<<3);
      bh[f] = *(const short8*)&SM[bf][2][offb];
      bl[f] = *(const short8*)&SM[bf][3][offb];
    }
    #pragma unroll
    for (int fi = 0; fi < 2; fi++)
      #pragma unroll
      for (int fj = 0; fj < 2; fj++){
        acc[fi][fj] = __builtin_amdgcn_mfma_f32_16x16x32_bf16(ah[fi], bh[fj], acc[fi][fj], 0,0,0);
        acc[fi][fj] = __builtin_amdgcn_mfma_f32_16x16x32_bf16(ah[fi], bl[fj], acc[fi][fj], 0,0,0);
        acc[fi][fj] = __builtin_amdgcn_mfma_f32_16x16x32_bf16(al[fi], bh[fj], acc[fi][fj], 0,0,0);
      }
    __builtin_amdgcn_sched_barrier(0);
    __builtin_amdgcn_s_barrier();
  }
  #undef VISSUE

  float* dst = Vp + (size_t)z*NDIM*NDIM;
  #pragma unroll
  for (int fi = 0; fi < 2; fi++)
    #pragma unroll
    for (int fj = 0; fj < 2; fj++)
      #pragma unroll
      for (int e = 0; e < 4; e++){
        int gi = i0 + wr*32 + fi*16 + (lane>>4)*4 + e;
        int gj = j0 + wc*32 + fj*16 + lrow;
        dst[(size_t)gi*NDIM + gj] = acc[fi][fj][e];
        if (ti != tj) dst[(size_t)gj*NDIM + gi] = acc[fi][fj][e];
      }
}

// ------- finVinit: V=sum(Vp)/4095; write Vh/Vl, E0=I-cV, P0=cI -------
__global__ void k_finVinit(const float* __restrict__ Vp,
      unsigned short* __restrict__ Vh, unsigned short* __restrict__ Vl,
      unsigned short* __restrict__ E0, unsigned short* __restrict__ P0){
  const float c = 0.869565217f;
  int r = blockIdx.x, lane = threadIdx.x; // 64 threads
  const size_t S = (size_t)NDIM*NDIM;
  float a[8] = {0,0,0,0,0,0,0,0};
  #pragma unroll
  for (int z = 0; z < VZ; z++){
    const float* p = Vp + z*S + (size_t)r*NDIM + lane*8;
    float4 u = *(const float4*)p;
    float4 v = *(const float4*)(p+4);
    a[0]+=u.x; a[1]+=u.y; a[2]+=u.z; a[3]+=u.w;
    a[4]+=v.x; a[5]+=v.y; a[6]+=v.z; a[7]+=v.w;
  }
  const float s = 1.0f/4095.0f;
  unsigned short vh[8] __attribute__((aligned(16))), vl[8] __attribute__((aligned(16)));
  unsigned short e8[8] __attribute__((aligned(16))), p8[8] __attribute__((aligned(16)));
  #pragma unroll
  for (int e = 0; e < 8; e++){
    float v = a[e]*s;
    vh[e] = f2bf(v); vl[e] = f2bf(v - bf2f(vh[e]));
    int col = lane*8 + e;
    e8[e] = f2bf(((col==r)?1.f:0.f) - c*v);
    p8[e] = f2bf((col==r)?c:0.f);
  }
  size_t o = (size_t)r*NDIM + lane*8;
  *(uint4*)&Vh[o] = *(uint4*)vh; *(uint4*)&Vl[o] = *(uint4*)vl;
  *(uint4*)&E0[o] = *(uint4*)e8; *(uint4*)&P0[o] = *(uint4*)p8;
}

// ------- fused NS iteration: blocks 0-63: En = E*E ; 64-127: Pn = P + P*E -------
__global__ __launch_bounds__(256) void k_ns(const unsigned short* __restrict__ E,
      const unsigned short* __restrict__ P,
      unsigned short* __restrict__ En, unsigned short* __restrict__ Pn){
  int b = blockIdx.x;
  int half = b >> 6, tile = b & 63;
  int i0 = (tile>>3)*64, j0 = (tile&7)*64;
  const unsigned short* Asrc = half ? P : E;
  __shared__ __align__(16) unsigned short Ah[64*40], Bh[64*40];
  int t = threadIdx.x, lane = t&63, wave = t>>6;
  int wr = wave>>1, wc = wave&1;
  int lrow = lane & 15, kc = (lane>>4)*8;
  f32x4 acc[2][2];
  #pragma unroll
  for (int a = 0; a < 2; a++)
    #pragma unroll
    for (int c = 0; c < 2; c++) acc[a][c] = (f32x4){0.f,0.f,0.f,0.f};
  int r = t>>2, c8 = (t&3)*8;
  const unsigned short* pA = Asrc + (size_t)(i0+r)*NDIM + c8;
  const unsigned short* pB = E + (size_t)(j0+r)*NDIM + c8;
  uint4 ra = *(const uint4*)pA, rb = *(const uint4*)pB;
  for (int kt = 0; kt < 16; kt++){
    *(uint4*)&Ah[r*40 + c8] = ra;
    *(uint4*)&Bh[r*40 + c8] = rb;
    __syncthreads();
    if (kt < 15){
      pA += 32; pB += 32;
      ra = *(const uint4*)pA; rb = *(const uint4*)pB;
    }
    short8 fa[2], fb[2];
    #pragma unroll
    for (int f = 0; f < 2; f++){
      fa[f] = *(const short8*)&Ah[(wr*32 + f*16 + lrow)*40 + kc];
      fb[f] = *(const short8*)&Bh[(wc*32 + f*16 + lrow)*40 + kc];
    }
    #pragma unroll
    for (int fi = 0; fi < 2; fi++)
      #pragma unroll
      for (int fj = 0; fj < 2; fj++)
        acc[fi][fj] = __builtin_amdgcn_mfma_f32_16x16x32_bf16(fa[fi], fb[fj], acc[fi][fj], 0,0,0);
    __syncthreads();
  }
  #pragma unroll
  for (int fi = 0; fi < 2; fi++)
    #pragma unroll
    for (int fj = 0; fj < 2; fj++)
      #pragma unroll
      for (int e = 0; e < 4; e++){
        int gi = i0 + wr*32 + fi*16 + (lane>>4)*4 + e;
        int gj = j0 + wc*32 + fj*16 + lrow;
        size_t o = (size_t)gi*NDIM + gj;
        if (half) Pn[o] = f2bf(bf2f(P[o]) + acc[fi][fj][e]);
        else      En[o] = f2bf(acc[fi][fj][e]);
      }
}

// ------- resid: R = I - (Vh+Vl)*P, stored TRANSPOSED as hi/lo bf16 -------
__global__ __launch_bounds__(256) void k_resid(const unsigned short* __restrict__ Vh,
      const unsigned short* __restrict__ Vl, const unsigned short* __restrict__ P,
      unsigned short* __restrict__ Rh, unsigned short* __restrict__ Rl){
  int b = blockIdx.x;
  int i0 = (b>>3)*64, j0 = (b&7)*64;
  __shared__ __align__(16) unsigned short Ah[64*40], Al[64*40], Bh[64*40];
  int t = threadIdx.x, lane = t&63, wave = t>>6;
  int wr = wave>>1, wc = wave&1;
  int lrow = lane & 15, kc = (lane>>4)*8;
  f32x4 acc[2][2];
  #pragma unroll
  for (int a = 0; a < 2; a++)
    #pragma unroll
    for (int c = 0; c < 2; c++) acc[a][c] = (f32x4){0.f,0.f,0.f,0.f};
  int r = t>>2, c8 = (t&3)*8;
  const unsigned short* pAh = Vh + (size_t)(i0+r)*NDIM + c8;
  const unsigned short* pAl = Vl + (size_t)(i0+r)*NDIM + c8;
  const unsigned short* pB  = P  + (size_t)(j0+r)*NDIM + c8;
  uint4 rah = *(const uint4*)pAh, ral = *(const uint4*)pAl, rb = *(const uint4*)pB;
  for (int kt = 0; kt < 16; kt++){
    *(uint4*)&Ah[r*40 + c8] = rah;
    *(uint4*)&Al[r*40 + c8] = ral;
    *(uint4*)&Bh[r*40 + c8] = rb;
    __syncthreads();
    if (kt < 15){
      pAh += 32; pAl += 32; pB += 32;
      rah = *(const uint4*)pAh; ral = *(const uint4*)pAl; rb = *(const uint4*)pB;
    }
    short8 fah[2], fal[2], fb[2];
    #pragma unroll
    for (int f = 0; f < 2; f++){
      fah[f] = *(const short8*)&Ah[(wr*32 + f*16 + lrow)*40 + kc];
      fal[f] = *(const short8*)&Al[(wr*32 + f*16 + lrow)*40 + kc];
      fb[f]  = *(const short8*)&Bh[(wc*32 + f*16 + lrow)*40 + kc];
    }
    #pragma unroll
    for (int fi = 0; fi < 2; fi++)
      #pragma unroll
      for (int fj = 0; fj < 2; fj++){
        acc[fi][fj] = __builtin_amdgcn_mfma_f32_16x16x32_bf16(fah[fi], fb[fj], acc[fi][fj], 0,0,0);
        acc[fi][fj] = __builtin_amdgcn_mfma_f32_16x16x32_bf16(fal[fi], fb[fj], acc[fi][fj], 0,0,0);
      }
    __syncthreads();
  }
  #pragma unroll
  for (int fi = 0; fi < 2; fi++)
    #pragma unroll
    for (int fj = 0; fj < 2; fj++)
      #pragma unroll
      for (int e = 0; e < 4; e++){
        int gi = i0 + wr*32 + fi*16 + (lane>>4)*4 + e;
        int gj = j0 + wc*32 + fj*16 + lrow;
        float rv = ((gi==gj)?1.f:0.f) - acc[fi][fj][e];
        unsigned short hi = f2bf(rv);
        size_t o = (size_t)gj*NDIM + gi;   // transposed store
        Rh[o] = hi; Rl[o] = f2bf(rv - bf2f(hi));
      }
}

// ------- final: VI = P + P*R -> VIh/VIl -------
__global__ __launch_bounds__(256) void k_final(const unsigned short* __restrict__ P,
      const unsigned short* __restrict__ Rh, const unsigned short* __restrict__ Rl,
      unsigned short* __restrict__ VIh, unsigned short* __restrict__ VIl){
  int b = blockIdx.x;
  int i0 = (b>>3)*64, j0 = (b&7)*64;
  __shared__ __align__(16) unsigned short Ah[64*40], Bh[64*40], Bl[64*40];
  int t = threadIdx.x, lane = t&63, wave = t>>6;
  int wr = wave>>1, wc = wave&1;
  int lrow = lane & 15, kc = (lane>>4)*8;
  f32x4 acc[2][2];
  #pragma unroll
  for (int a = 0; a < 2; a++)
    #pragma unroll
    for (int c = 0; c < 2; c++) acc[a][c] = (f32x4){0.f,0.f,0.f,0.f};
  int r = t>>2, c8 = (t&3)*8;
  const unsigned short* pA  = P  + (size_t)(i0+r)*NDIM + c8;
  const unsigned short* pBh = Rh + (size_t)(j0+r)*NDIM + c8;
  const unsigned short* pBl = Rl + (size_t)(j0+r)*NDIM + c8;
  uint4 ra = *(const uint4*)pA, rbh = *(const uint4*)pBh, rbl = *(const uint4*)pBl;
  for (int kt = 0; kt < 16; kt++){
    *(uint4*)&Ah[r*40 + c8] = ra;
    *(uint4*)&Bh[r*40 + c8] = rbh;
    *(uint4*)&Bl[r*40 + c8] = rbl;
    __syncthreads();
    if (kt < 15){
      pA += 32; pBh += 32; pBl += 32;
      ra = *(const uint4*)pA; rbh = *(const uint4*)pBh; rbl = *(const uint4*)pBl;
    }
    short8 fa[2], fbh[2], fbl[2];
    #pragma unroll
    for (int f = 0; f < 2; f++){
      fa[f]  = *(const short8*)&Ah[(wr*32 + f*16 + lrow)*40 + kc];
      fbh[f] = *(const short8*)&Bh[(wc*32 + f*16 + lrow)*40 + kc];
      fbl[f] = *(const short8*)&Bl[(wc*32 + f*16 + lrow)*40 + kc];
    }
    #pragma unroll
    for (int fi = 0; fi < 2; fi++)
      #pragma unroll
      for (int fj = 0; fj < 2; fj++){
        acc[fi][fj] = __builtin_amdgcn_mfma_f32_16x16x32_bf16(fa[fi], fbh[fj], acc[fi][fj], 0,0,0);
        acc[fi][fj] = __builtin_amdgcn_mfma_f32_16x16x32_bf16(fa[fi], fbl[fj], acc[fi][fj], 0,0,0);
      }
    __syncthreads();
  }
  #pragma unroll
  for (int fi = 0; fi < 2; fi++)
    #pragma unroll
    for (int fj = 0; fj < 2; fj++)
      #pragma unroll
      for (int e = 0; e < 4; e++){
        int gi = i0 + wr*32 + fi*16 + (lane>>4)*4 + e;
        int gj = j0 + wc*32 + fj*16 + lrow;
        size_t o = (size_t)gi*NDIM + gj;
        float vi = bf2f(P[o]) + acc[fi][fj][e];
        unsigned short hi = f2bf(vi);
        VIh[o] = hi; VIl[o] = f2bf(vi - bf2f(hi));
      }
}

// ------- Z2: 16-wave, tile 128(i) x 64(a), 3-buf DMA pipeline -------
__global__ __launch_bounds__(1024) void k_gemmZ2(const unsigned short* __restrict__ Xth,
    const unsigned short* __restrict__ Xtl, const unsigned short* __restrict__ VIh,
    const unsigned short* __restrict__ VIl, unsigned short* __restrict__ Zt){
  int i0 = blockIdx.x * 128, j0 = blockIdx.y * 64;
  __shared__ __align__(16) unsigned short SMA[3][2][128*32];
  __shared__ __align__(16) unsigned short SMB[3][2][64*32];
  int t = threadIdx.x, lane = t & 63, wave = t >> 6;
  int wr = wave >> 2, wc = wave & 3;
  f32x4 acc[2];
  acc[0] = (f32x4){0.f,0.f,0.f,0.f}; acc[1] = (f32x4){0.f,0.f,0.f,0.f};

  int srow = lane >> 2;
  int sgk  = (lane & 3) ^ ((srow >> 1) & 3);
  int lrow = lane & 15, glog = lane >> 4;

  const unsigned short* srcA0 = Xth + (size_t)(i0 + (wave&7)*16 + srow)*NDIM + sgk*8;
  const unsigned short* srcA1 = Xtl + (size_t)(i0 + (wave&7)*16 + srow)*NDIM + sgk*8;
  int gB = wave & 3;
  const unsigned short* srcB = ((wave < 12) ? VIh : VIl) + (size_t)(j0 + gB*16 + srow)*NDIM + sgk*8;
  int mB = (wave < 12) ? 0 : 1;
  int gA = wave & 7;

  #define ZISSUE(batch) { int kb = (batch)*32; int bf = (batch)%3; \
    if (wave < 8){ gload16(srcA0 + kb, &SMA[bf][0][gA*512]); \
                   gload16(srcA1 + kb, &SMA[bf][1][gA*512]); } \
    else         { gload16(srcB  + kb, &SMB[bf][mB][gB*512]); } }

  ZISSUE(0); ZISSUE(1);
  for (int kt = 0; kt < 16; kt++){
    int bf = kt % 3;
    if (kt + 2 < 16) ZISSUE(kt + 2);
    if (wave < 8){
      if (kt < 14)       { asm volatile("s_waitcnt vmcnt(4)" ::: "memory"); }
      else if (kt == 14) { asm volatile("s_waitcnt vmcnt(2)" ::: "memory"); }
      else               { asm volatile("s_waitcnt vmcnt(0)" ::: "memory"); }
    } else {
      if (kt < 14)       { asm volatile("s_waitcnt vmcnt(2)" ::: "memory"); }
      else if (kt == 14) { asm volatile("s_waitcnt vmcnt(1)" ::: "memory"); }
      else               { asm volatile("s_waitcnt vmcnt(0)" ::: "memory"); }
    }
    __builtin_amdgcn_sched_barrier(0);
    __builtin_amdgcn_s_barrier();
    __builtin_amdgcn_sched_barrier(0);

    short8 ah[2], al[2], bh, bl;
    #pragma unroll
    for (int f = 0; f < 2; f++){
      int fra = wr*32 + f*16 + lrow;
      int offa = fra*32 + ((glog ^ ((fra>>1)&3))<<3);
      ah[f] = *(const short8*)&SMA[bf][0][offa];
      al[f] = *(const short8*)&SMA[bf][1][offa];
    }
    {
      int frb = wc*16 + lrow;
      int offb = frb*32 + ((glog ^ ((frb>>1)&3))<<3);
      bh = *(const short8*)&SMB[bf][0][offb];
      bl = *(const short8*)&SMB[bf][1][offb];
    }
    #pragma unroll
    for (int fi = 0; fi < 2; fi++){
      acc[fi] = __builtin_amdgcn_mfma_f32_16x16x32_bf16(ah[fi], bh, acc[fi], 0,0,0);
      acc[fi] = __builtin_amdgcn_mfma_f32_16x16x32_bf16(ah[fi], bl, acc[fi], 0,0,0);
      acc[fi] = __builtin_amdgcn_mfma_f32_16x16x32_bf16(al[fi], bh, acc[fi], 0,0,0);
    }
    __builtin_amdgcn_sched_barrier(0);
    __builtin_amdgcn_s_barrier();
  }
  #undef ZISSUE

  #pragma unroll
  for (int fi = 0; fi < 2; fi++)
    #pragma unroll
    for (int e = 0; e < 4; e++){
      int gi = i0 + wr*32 + fi*16 + (lane>>4)*4 + e;
      int gj = j0 + wc*16 + lrow;
      Zt[(size_t)gi*NDIM + gj] = f2bf(acc[fi][e]);
    }
}

// ---------------- q[i] = dot(Xth[i,:], Zt[i,:]) ----------------
__global__ void k_q(const unsigned short* __restrict__ Xt, const unsigned short* __restrict__ Zt,
                    float* __restrict__ q){
  int wave = threadIdx.x >> 6, lane = threadIdx.x & 63;
  int i = blockIdx.x * 4 + wave;
  uint4 xv = *(const uint4*)(Xt + (size_t)i*NDIM + lane*8);
  uint4 zv = *(const uint4*)(Zt + (size_t)i*NDIM + lane*8);
  const unsigned short* xs = (const unsigned short*)&xv;
  const unsigned short* zs = (const unsigned short*)&zv;
  float s = 0.f;
  #pragma unroll
  for (int e = 0; e < 8; e++) s += bf2f(xs[e]) * bf2f(zs[e]);
  #pragma unroll
  for (int off = 32; off > 0; off >>= 1) s += __shfl_down(s, off, 64);
  if (lane == 0) q[i] = s;
}

// ------- G: 16-wave blocks, BK=32, 4-buffer DEPTH-2, SINGLE barrier per step -------
__global__ __launch_bounds__(1024) void k_G(const unsigned short* __restrict__ Xt,
        const unsigned short* __restrict__ Zt, const float* __restrict__ q,
        float* __restrict__ out){
  const int NT = NPTS/128; // 32
  int b = (int)blockIdx.x;
  b = (b & 7) * 66 + (b >> 3);     // XCD-bijective chunking (528 = 8*66)
  int ti = 0, rem = b;
  while (rem >= NT - ti){ rem -= NT - ti; ti++; }
  int tj = ti + rem;
  int i0 = ti*128, j0 = tj*128;

  __shared__ __align__(16) unsigned short SMEM[2*4*128*32];
  unsigned short (*At)[128*32] = (unsigned short (*)[128*32])SMEM;
  unsigned short (*Bt)[128*32] = (unsigned short (*)[128*32])(SMEM + 4*128*32);
  float* fsm = (float*)SMEM;

  int t = threadIdx.x, lane = t & 63, wave = t >> 6;   // wave 0..15
  int wr = wave >> 2, wc = wave & 3;                   // 4x4 wave grid, 32x32 sub-tile each
  f32x4 acc[2][2];
  #pragma unroll
  for (int a = 0; a < 2; a++)
    #pragma unroll
    for (int c = 0; c < 2; c++) acc[a][c] = (f32x4){0.f,0.f,0.f,0.f};

  int srow = lane >> 2;
  int sgk  = (lane & 3) ^ ((srow >> 1) & 3);
  int lrow = lane & 15;
  int glog = lane >> 4;

  int sg = wave & 7;
  int srcrow = sg*16 + srow;
  const unsigned short* src = (wave < 8)
      ? (Xt + (size_t)(i0 + srcrow)*NDIM + sgk*8)
      : (Zt + (size_t)(j0 + srcrow)*NDIM + sgk*8);
  unsigned short (*dstb)[128*32] = (wave < 8) ? At : Bt;

  #define ISSUE(batch) { int kb = (batch)*32; int bf = (batch)&3; \
    gload16(src + kb, &dstb[bf][sg*512]); }

  // depth-2: with 4 buffers, write target buf[(kt+2)&3] was last read at step kt-2,
  // and the single barrier at step kt-1 already proves those reads completed.
  ISSUE(0); ISSUE(1);

  for (int kt = 0; kt < 16; kt++){
    int cur = kt & 3;
    if (kt + 2 < 16) ISSUE(kt + 2);
    if (kt <= 13)      { asm volatile("s_waitcnt vmcnt(2)" ::: "memory"); }
    else if (kt == 14) { asm volatile("s_waitcnt vmcnt(1)" ::: "memory"); }
    else               { asm volatile("s_waitcnt vmcnt(0)" ::: "memory"); }
    __builtin_amdgcn_sched_barrier(0);
    __builtin_amdgcn_s_barrier();          // all waves' batch-kt loads landed; reads of
    __builtin_amdgcn_sched_barrier(0);     // buf[(kt+2)&3] finished at step kt-2 (see above)

    short8 af[2], bfr[2];
    #pragma unroll
    for (int f = 0; f < 2; f++){
      int fra = wr*32 + f*16 + lrow;
      int frb = wc*32 + f*16 + lrow;
      af[f]  = *(const short8*)&At[cur][fra*32 + ((glog ^ ((fra>>1)&3))<<3)];
      bfr[f] = *(const short8*)&Bt[cur][frb*32 + ((glog ^ ((frb>>1)&3))<<3)];
    }
    #pragma unroll
    for (int fi = 0; fi < 2; fi++)
      #pragma unroll
      for (int fj = 0; fj < 2; fj++)
        acc[fi][fj] = __builtin_amdgcn_mfma_f32_16x16x32_bf16(af[fi], bfr[fj], acc[fi][fj], 0, 0, 0);
  }
  #undef ISSUE
  __syncthreads();   // all reads done before epilogue overwrites SMEM

  #pragma unroll
  for (int fi = 0; fi < 2; fi++)
    #pragma unroll
    for (int fj = 0; fj < 2; fj++)
      #pragma unroll
      for (int e = 0; e < 4; e++){
        int r = wr*32 + fi*16 + (lane >> 4)*4 + e;
        int c = wc*32 + fj*16 + lrow;
        fsm[r*128 + c] = acc[fi][fj][e];
      }
  __syncthreads();

  #pragma unroll
  for (int i = 0; i < 8; i++){
    int row = wave*8 + i;
    int gi = i0 + row;
    float qi = q[gi];
    size_t rowbase = (size_t)gi*NPTS - ((size_t)gi*(gi+1))/2 - (size_t)gi - 1;
    float2 vv = *(float2*)&fsm[row*128 + lane*2];
    int gj0 = j0 + lane*2, gj1 = gj0 + 1;
    if (gi < gj0) out[rowbase + gj0] = sqrtf(fmaxf(qi + q[gj0] - 2.0f*vv.x, 1e-12f));
    if (gi < gj1) out[rowbase + gj1] = sqrtf(fmaxf(qi + q[gj1] - 2.0f*vv.y, 1e-12f));
  }
}

extern "C" void kernel_launch(void* const* d_in, const int* in_sizes, int n_in,
                              void* d_out, int out_size, void* d_ws, size_t ws_size,
                              hipStream_t stream) {
  (void)in_sizes; (void)n_in; (void)out_size; (void)ws_size;
  const float* x0 = (const float*)d_in[0];
  const float* x1 = (const float*)d_in[1];
  float* out = (float*)d_out;

  char* w = (char*)d_ws;
  float* mu     = (float*)w; w += 4096;
  float* q      = (float*)w; w += NPTS*4;
  unsigned short* Vh = (unsigned short*)w; w += (size_t)NDIM*NDIM*2;
  unsigned short* Vl = (unsigned short*)w; w += (size_t)NDIM*NDIM*2;
  unsigned short* E0 = (unsigned short*)w; w += (size_t)NDIM*NDIM*2;
  unsigned short* E1 = (unsigned short*)w; w += (size_t)NDIM*NDIM*2;
  unsigned short* P0 = (unsigned short*)w; w += (size_t)NDIM*NDIM*2;
  unsigned short* P1 = (unsigned short*)w; w += (size_t)NDIM*NDIM*2;
  unsigned short* Xch = (unsigned short*)w; w += (size_t)NDIM*NPTS*2;
  unsigned short* Xcl = (unsigned short*)w; w += (size_t)NDIM*NPTS*2;
  unsigned short* Xth = (unsigned short*)w; w += (size_t)NDIM*NPTS*2;
  unsigned short* Xtl = (unsigned short*)w; w += (size_t)NDIM*NPTS*2;
  char* uspan = w;
  unsigned short* Rh  = (unsigned short*)uspan;
  unsigned short* Rl  = Rh + (size_t)NDIM*NDIM;
  unsigned short* VIh = Rl + (size_t)NDIM*NDIM;
  unsigned short* VIl = VIh + (size_t)NDIM*NDIM;
  unsigned short* Zt  = VIl + (size_t)NDIM*NDIM;
  float* Vp = (float*)uspan;  // VZ x 1MB partials, dead after k_finVinit

  k_rowmean<<<dim3(512), dim3(256), 0, stream>>>(x0, x1, mu);
  k_prep<<<dim3(64,8), dim3(256), 0, stream>>>(x0, x1, mu, Xch, Xcl, Xth, Xtl);
  k_V2<<<dim3(10, VZ), dim3(1024), 0, stream>>>(Xch, Xcl, Vp);
  k_finVinit<<<dim3(512), dim3(64), 0, stream>>>(Vp, Vh, Vl, E0, P0);

  unsigned short *Ec = E0, *En = E1, *Pc = P0, *Pn = P1;
  for (int it = 0; it < 3; ++it){
    k_ns<<<dim3(128), dim3(256), 0, stream>>>(Ec, Pc, En, Pn);
    unsigned short* tmp;
    tmp = Ec; Ec = En; En = tmp;
    tmp = Pc; Pc = Pn; Pn = tmp;
  }
  k_resid<<<dim3(64), dim3(256), 0, stream>>>(Vh, Vl, Pc, Rh, Rl);
  k_final<<<dim3(64), dim3(256), 0, stream>>>(Pc, Rh, Rl, VIh, VIl);
  k_gemmZ2<<<dim3(32,8), dim3(1024), 0, stream>>>(Xth, Xtl, VIh, VIl, Zt);
  k_q<<<dim3(1024), dim3(256), 0, stream>>>(Xth, Zt, q);
  k_G<<<dim3(528), dim3(1024), 0, stream>>>(Xth, Zt, q, out);
}

// Round 15
// 113.785 us; speedup vs baseline: 1.5797x; 1.1299x over previous
//
#include <hip/hip_runtime.h>
#include <hip/hip_bf16.h>
#include <math.h>

#define NDIM 512
#define NPTS 4096
#define VZ 16

typedef __attribute__((ext_vector_type(4))) float f32x4;
typedef __attribute__((ext_vector_type(8))) short short8;

__device__ __forceinline__ const float* xrow(const float* x0, const float* x1, int r){
  return (r < 256) ? (x0 + (size_t)r * NPTS) : (x1 + (size_t)(r - 256) * NPTS);
}
__device__ __forceinline__ unsigned short f2bf(float f){
  __hip_bfloat16 h = __float2bfloat16(f);
  return *reinterpret_cast<unsigned short*>(&h);
}
__device__ __forceinline__ float bf2f(unsigned short u){
  return __uint_as_float(((unsigned int)u) << 16);
}
__device__ __forceinline__ void gload16(const void* g, void* l){
  __builtin_amdgcn_global_load_lds((const __attribute__((address_space(1))) void*)g,
                                   (__attribute__((address_space(3))) void*)l, 16, 0, 0);
}

// ---------------- row means of X (512 rows x 4096) ----------------
__global__ void k_rowmean(const float* __restrict__ x0, const float* __restrict__ x1,
                          float* __restrict__ mu){
  int r = blockIdx.x;
  const float4* row4 = (const float4*)xrow(x0, x1, r);
  float s = 0.f;
  for (int c = threadIdx.x; c < NPTS/4; c += 256){
    float4 v = row4[c];
    s += v.x + v.y + v.z + v.w;
  }
  __shared__ float red[256];
  red[threadIdx.x] = s; __syncthreads();
  for (int off = 128; off > 0; off >>= 1){
    if (threadIdx.x < off) red[threadIdx.x] += red[threadIdx.x + off];
    __syncthreads();
  }
  if (threadIdx.x == 0) mu[r] = red[0] * (1.0f / NPTS);
}

// ------- prep: centered X in bf16 hi/lo, both layouts -------
__global__ __launch_bounds__(256) void k_prep(const float* __restrict__ x0, const float* __restrict__ x1,
      const float* __restrict__ mu,
      unsigned short* __restrict__ Xch, unsigned short* __restrict__ Xcl,
      unsigned short* __restrict__ Xth, unsigned short* __restrict__ Xtl){
  __shared__ float tile[64][65];
  int i0 = blockIdx.x * 64, a0 = blockIdx.y * 64;
  int t = threadIdx.x;
  int r = t >> 2, cg = (t & 3) * 16;
  const float* row = xrow(x0, x1, a0 + r);
  float m = mu[a0 + r];
  unsigned short h16[16] __attribute__((aligned(16)));
  unsigned short l16[16] __attribute__((aligned(16)));
  #pragma unroll
  for (int e = 0; e < 16; e += 4){
    float4 v = *(const float4*)(row + i0 + cg + e);
    v.x -= m; v.y -= m; v.z -= m; v.w -= m;
    tile[r][cg+e] = v.x; tile[r][cg+e+1] = v.y; tile[r][cg+e+2] = v.z; tile[r][cg+e+3] = v.w;
    h16[e]   = f2bf(v.x); l16[e]   = f2bf(v.x - bf2f(h16[e]));
    h16[e+1] = f2bf(v.y); l16[e+1] = f2bf(v.y - bf2f(h16[e+1]));
    h16[e+2] = f2bf(v.z); l16[e+2] = f2bf(v.z - bf2f(h16[e+2]));
    h16[e+3] = f2bf(v.w); l16[e+3] = f2bf(v.w - bf2f(h16[e+3]));
  }
  unsigned short* dst = Xch + (size_t)(a0+r)*NPTS + i0 + cg;
  *(uint4*)dst = *(uint4*)&h16[0]; *(uint4*)(dst+8) = *(uint4*)&h16[8];
  dst = Xcl + (size_t)(a0+r)*NPTS + i0 + cg;
  *(uint4*)dst = *(uint4*)&l16[0]; *(uint4*)(dst+8) = *(uint4*)&l16[8];
  __syncthreads();
  unsigned short th[16] __attribute__((aligned(16)));
  unsigned short tl[16] __attribute__((aligned(16)));
  #pragma unroll
  for (int e = 0; e < 16; e++){
    float v = tile[cg+e][r];
    th[e] = f2bf(v); tl[e] = f2bf(v - bf2f(th[e]));
  }
  unsigned short* d2 = Xth + (size_t)(i0 + r)*NDIM + a0 + cg;
  *(uint4*)d2 = *(uint4*)&th[0]; *(uint4*)(d2+8) = *(uint4*)&th[8];
  d2 = Xtl + (size_t)(i0 + r)*NDIM + a0 + cg;
  *(uint4*)d2 = *(uint4*)&tl[0]; *(uint4*)(d2+8) = *(uint4*)&tl[8];
}

// ------- V2: 16-wave blocks, 128x128 tri-tiles x 16 K-slices, 3-buf DMA pipeline -------
__global__ __launch_bounds__(1024) void k_V2(const unsigned short* __restrict__ Xch,
        const unsigned short* __restrict__ Xcl, float* __restrict__ Vp){
  int b = blockIdx.x;                  // 0..9 upper-tri tile of 4x4
  int ti = 0, rem = b;
  while (rem >= 4 - ti){ rem -= 4 - ti; ti++; }
  int tj = ti + rem;
  int i0 = ti*128, j0 = tj*128;
  int z = blockIdx.y;                  // 0..15
  size_t kbase = (size_t)z * (NPTS/VZ);  // 256-wide K slice

  __shared__ __align__(16) unsigned short SM[3][4][128*32];
  int t = threadIdx.x, lane = t & 63, wave = t >> 6;
  int wr = wave >> 2, wc = wave & 3;
  f32x4 acc[2][2];
  #pragma unroll
  for (int a = 0; a < 2; a++)
    #pragma unroll
    for (int c = 0; c < 2; c++) acc[a][c] = (f32x4){0.f,0.f,0.f,0.f};

  int srow = lane >> 2;
  int sgk  = (lane & 3) ^ ((srow >> 1) & 3);
  int lrow = lane & 15, glog = lane >> 4;

  int sl0 = wave*2, sl1 = wave*2 + 1;
  int m0 = sl0 >> 3, g0 = sl0 & 7;
  int m1 = sl1 >> 3, g1 = sl1 & 7;
  const unsigned short* b0 = (m0 & 1) ? Xcl : Xch;
  const unsigned short* b1 = (m1 & 1) ? Xcl : Xch;
  int r0 = ((m0 < 2) ? i0 : j0) + g0*16 + srow;
  int r1 = ((m1 < 2) ? i0 : j0) + g1*16 + srow;
  const unsigned short* src0 = b0 + (size_t)r0*NPTS + kbase + sgk*8;
  const unsigned short* src1 = b1 + (size_t)r1*NPTS + kbase + sgk*8;

  #define VISSUE(batch) { int kb = (batch)*32; int bf = (batch)%3; \
    gload16(src0 + kb, &SM[bf][m0][g0*512]); \
    gload16(src1 + kb, &SM[bf][m1][g1*512]); }

  VISSUE(0); VISSUE(1);
  for (int kt = 0; kt < 8; kt++){
    int bf = kt % 3;
    if (kt + 2 < 8) VISSUE(kt + 2);
    if (kt < 6)       { asm volatile("s_waitcnt vmcnt(4)" ::: "memory"); }
    else if (kt == 6) { asm volatile("s_waitcnt vmcnt(2)" ::: "memory"); }
    else              { asm volatile("s_waitcnt vmcnt(0)" ::: "memory"); }
    __builtin_amdgcn_sched_barrier(0);
    __builtin_amdgcn_s_barrier();
    __builtin_amdgcn_sched_barrier(0);

    short8 ah[2], al[2], bh[2], bl[2];
    #pragma unroll
    for (int f = 0; f < 2; f++){
      int fra = wr*32 + f*16 + lrow;
      int offa = fra*32 + ((glog ^ ((fra>>1)&3))<<3);
      ah[f] = *(const short8*)&SM[bf][0][offa];
      al[f] = *(const short8*)&SM[bf][1][offa];
      int frb = wc*32 + f*16 + lrow;
      int offb = frb*32 + ((glog ^ ((frb>>1)&3))<<3);
      bh[f] = *(const short8*)&SM[bf][2][offb];
      bl[f] = *(const short8*)&SM[bf][3][offb];
    }
    #pragma unroll
    for (int fi = 0; fi < 2; fi++)
      #pragma unroll
      for (int fj = 0; fj < 2; fj++){
        acc[fi][fj] = __builtin_amdgcn_mfma_f32_16x16x32_bf16(ah[fi], bh[fj], acc[fi][fj], 0,0,0);
        acc[fi][fj] = __builtin_amdgcn_mfma_f32_16x16x32_bf16(ah[fi], bl[fj], acc[fi][fj], 0,0,0);
        acc[fi][fj] = __builtin_amdgcn_mfma_f32_16x16x32_bf16(al[fi], bh[fj], acc[fi][fj], 0,0,0);
      }
    __builtin_amdgcn_sched_barrier(0);
    __builtin_amdgcn_s_barrier();
  }
  #undef VISSUE

  float* dst = Vp + (size_t)z*NDIM*NDIM;
  #pragma unroll
  for (int fi = 0; fi < 2; fi++)
    #pragma unroll
    for (int fj = 0; fj < 2; fj++)
      #pragma unroll
      for (int e = 0; e < 4; e++){
        int gi = i0 + wr*32 + fi*16 + (lane>>4)*4 + e;
        int gj = j0 + wc*32 + fj*16 + lrow;
        dst[(size_t)gi*NDIM + gj] = acc[fi][fj][e];
        if (ti != tj) dst[(size_t)gj*NDIM + gi] = acc[fi][fj][e];
      }
}

// ------- finVinit: V=sum(Vp)/4095; write Vh/Vl, E0=I-cV, P0=cI -------
__global__ void k_finVinit(const float* __restrict__ Vp,
      unsigned short* __restrict__ Vh, unsigned short* __restrict__ Vl,
      unsigned short* __restrict__ E0, unsigned short* __restrict__ P0){
  const float c = 0.869565217f;
  int r = blockIdx.x, lane = threadIdx.x; // 64 threads
  const size_t S = (size_t)NDIM*NDIM;
  float a[8] = {0,0,0,0,0,0,0,0};
  #pragma unroll
  for (int z = 0; z < VZ; z++){
    const float* p = Vp + z*S + (size_t)r*NDIM + lane*8;
    float4 u = *(const float4*)p;
    float4 v = *(const float4*)(p+4);
    a[0]+=u.x; a[1]+=u.y; a[2]+=u.z; a[3]+=u.w;
    a[4]+=v.x; a[5]+=v.y; a[6]+=v.z; a[7]+=v.w;
  }
  const float s = 1.0f/4095.0f;
  unsigned short vh[8] __attribute__((aligned(16))), vl[8] __attribute__((aligned(16)));
  unsigned short e8[8] __attribute__((aligned(16))), p8[8] __attribute__((aligned(16)));
  #pragma unroll
  for (int e = 0; e < 8; e++){
    float v = a[e]*s;
    vh[e] = f2bf(v); vl[e] = f2bf(v - bf2f(vh[e]));
    int col = lane*8 + e;
    e8[e] = f2bf(((col==r)?1.f:0.f) - c*v);
    p8[e] = f2bf((col==r)?c:0.f);
  }
  size_t o = (size_t)r*NDIM + lane*8;
  *(uint4*)&Vh[o] = *(uint4*)vh; *(uint4*)&Vl[o] = *(uint4*)vl;
  *(uint4*)&E0[o] = *(uint4*)e8; *(uint4*)&P0[o] = *(uint4*)p8;
}

// ------- ns2: DMA-pipelined fused NS iter. blocks 0-63: En=E*E ; 64-127: Pn=P+P*E
//         BK=64, 8 steps, 4 bufs x 16KB = 64KB, depth-2, single barrier/step -------
__global__ __launch_bounds__(256) void k_ns2(const unsigned short* __restrict__ E,
      const unsigned short* __restrict__ P,
      unsigned short* __restrict__ En, unsigned short* __restrict__ Pn){
  int b = blockIdx.x;
  int half = b >> 6, tile = b & 63;
  int i0 = (tile>>3)*64, j0 = (tile&7)*64;
  const unsigned short* Asrc = half ? P : E;
  __shared__ __align__(16) unsigned short SM[4][2][64*64];
  int t = threadIdx.x, lane = t & 63, wave = t >> 6;
  int wr = wave >> 1, wc = wave & 1;
  int lrow = lane & 15, glog = lane >> 4;
  f32x4 acc[2][2];
  #pragma unroll
  for (int a = 0; a < 2; a++)
    #pragma unroll
    for (int c = 0; c < 2; c++) acc[a][c] = (f32x4){0.f,0.f,0.f,0.f};

  // staging: gload = 8 rows x 128B; 8 groups per matrix; wave w stages groups {2w,2w+1} of A and B
  int srow = lane >> 3;                 // 0..7 row within group
  int sg8  = (lane & 7) ^ (srow & 7);   // pre-swizzled source granule (16B)
  int gA0 = wave*2, gA1 = wave*2 + 1;
  const unsigned short* srcA0 = Asrc + (size_t)(i0 + gA0*8 + srow)*NDIM + sg8*8;
  const unsigned short* srcA1 = Asrc + (size_t)(i0 + gA1*8 + srow)*NDIM + sg8*8;
  const unsigned short* srcB0 = E + (size_t)(j0 + gA0*8 + srow)*NDIM + sg8*8;
  const unsigned short* srcB1 = E + (size_t)(j0 + gA1*8 + srow)*NDIM + sg8*8;

  #define NISSUE(batch) { int kb = (batch)*64; int bf = (batch)&3; \
    gload16(srcA0 + kb, &SM[bf][0][gA0*512]); \
    gload16(srcA1 + kb, &SM[bf][0][gA1*512]); \
    gload16(srcB0 + kb, &SM[bf][1][gA0*512]); \
    gload16(srcB1 + kb, &SM[bf][1][gA1*512]); }

  NISSUE(0); NISSUE(1);
  for (int kt = 0; kt < 8; kt++){
    int bf = kt & 3;
    if (kt + 2 < 8) NISSUE(kt + 2);
    if (kt <= 5)      { asm volatile("s_waitcnt vmcnt(8)" ::: "memory"); }
    else if (kt == 6) { asm volatile("s_waitcnt vmcnt(4)" ::: "memory"); }
    else              { asm volatile("s_waitcnt vmcnt(0)" ::: "memory"); }
    __builtin_amdgcn_sched_barrier(0);
    __builtin_amdgcn_s_barrier();
    __builtin_amdgcn_sched_barrier(0);

    #pragma unroll
    for (int c = 0; c < 2; c++){
      short8 fa[2], fb[2];
      #pragma unroll
      for (int f = 0; f < 2; f++){
        int fra = wr*32 + f*16 + lrow;
        fa[f] = *(const short8*)&SM[bf][0][fra*64 + (((c*4+glog) ^ (fra&7))<<3)];
        int frb = wc*32 + f*16 + lrow;
        fb[f] = *(const short8*)&SM[bf][1][frb*64 + (((c*4+glog) ^ (frb&7))<<3)];
      }
      #pragma unroll
      for (int fi = 0; fi < 2; fi++)
        #pragma unroll
        for (int fj = 0; fj < 2; fj++)
          acc[fi][fj] = __builtin_amdgcn_mfma_f32_16x16x32_bf16(fa[fi], fb[fj], acc[fi][fj], 0,0,0);
    }
  }
  #undef NISSUE

  #pragma unroll
  for (int fi = 0; fi < 2; fi++)
    #pragma unroll
    for (int fj = 0; fj < 2; fj++)
      #pragma unroll
      for (int e = 0; e < 4; e++){
        int gi = i0 + wr*32 + fi*16 + (lane>>4)*4 + e;
        int gj = j0 + wc*32 + fj*16 + lrow;
        size_t o = (size_t)gi*NDIM + gj;
        if (half) Pn[o] = f2bf(bf2f(P[o]) + acc[fi][fj][e]);
        else      En[o] = f2bf(acc[fi][fj][e]);
      }
}

// ------- resid2: R = I - (Vh+Vl)*P transposed hi/lo; BK=32, 48KB, depth-2 single barrier -------
__global__ __launch_bounds__(256) void k_resid2(const unsigned short* __restrict__ Vh,
      const unsigned short* __restrict__ Vl, const unsigned short* __restrict__ P,
      unsigned short* __restrict__ Rh, unsigned short* __restrict__ Rl){
  int b = blockIdx.x;
  int i0 = (b>>3)*64, j0 = (b&7)*64;
  __shared__ __align__(16) unsigned short SM[4][3][64*32];
  int t = threadIdx.x, lane = t & 63, wave = t >> 6;
  int wr = wave >> 1, wc = wave & 1;
  int lrow = lane & 15, glog = lane >> 4;
  f32x4 acc[2][2];
  #pragma unroll
  for (int a = 0; a < 2; a++)
    #pragma unroll
    for (int c = 0; c < 2; c++) acc[a][c] = (f32x4){0.f,0.f,0.f,0.f};

  int srow = lane >> 2;                       // 0..15
  int sg4  = (lane & 3) ^ ((srow >> 1) & 3);  // pre-swizzled granule (16B)
  const unsigned short* s0 = Vh + (size_t)(i0 + wave*16 + srow)*NDIM + sg4*8;
  const unsigned short* s1 = Vl + (size_t)(i0 + wave*16 + srow)*NDIM + sg4*8;
  const unsigned short* s2 = P  + (size_t)(j0 + wave*16 + srow)*NDIM + sg4*8;

  #define RISSUE(batch) { int kb = (batch)*32; int bf = (batch)&3; \
    gload16(s0 + kb, &SM[bf][0][wave*512]); \
    gload16(s1 + kb, &SM[bf][1][wave*512]); \
    gload16(s2 + kb, &SM[bf][2][wave*512]); }

  RISSUE(0); RISSUE(1);
  for (int kt = 0; kt < 16; kt++){
    int bf = kt & 3;
    if (kt + 2 < 16) RISSUE(kt + 2);
    if (kt <= 13)      { asm volatile("s_waitcnt vmcnt(6)" ::: "memory"); }
    else if (kt == 14) { asm volatile("s_waitcnt vmcnt(3)" ::: "memory"); }
    else               { asm volatile("s_waitcnt vmcnt(0)" ::: "memory"); }
    __builtin_amdgcn_sched_barrier(0);
    __builtin_amdgcn_s_barrier();
    __builtin_amdgcn_sched_barrier(0);

    short8 fah[2], fal[2], fb[2];
    #pragma unroll
    for (int f = 0; f < 2; f++){
      int fra = wr*32 + f*16 + lrow;
      int offa = fra*32 + ((glog ^ ((fra>>1)&3))<<3);
      fah[f] = *(const short8*)&SM[bf][0][offa];
      fal[f] = *(const short8*)&SM[bf][1][offa];
      int frb = wc*32 + f*16 + lrow;
      fb[f]  = *(const short8*)&SM[bf][2][frb*32 + ((glog ^ ((frb>>1)&3))<<3)];
    }
    #pragma unroll
    for (int fi = 0; fi < 2; fi++)
      #pragma unroll
      for (int fj = 0; fj < 2; fj++){
        acc[fi][fj] = __builtin_amdgcn_mfma_f32_16x16x32_bf16(fah[fi], fb[fj], acc[fi][fj], 0,0,0);
        acc[fi][fj] = __builtin_amdgcn_mfma_f32_16x16x32_bf16(fal[fi], fb[fj], acc[fi][fj], 0,0,0);
      }
  }
  #undef RISSUE

  #pragma unroll
  for (int fi = 0; fi < 2; fi++)
    #pragma unroll
    for (int fj = 0; fj < 2; fj++)
      #pragma unroll
      for (int e = 0; e < 4; e++){
        int gi = i0 + wr*32 + fi*16 + (lane>>4)*4 + e;
        int gj = j0 + wc*32 + fj*16 + lrow;
        float rv = ((gi==gj)?1.f:0.f) - acc[fi][fj][e];
        unsigned short hi = f2bf(rv);
        size_t o = (size_t)gj*NDIM + gi;   // transposed store
        Rh[o] = hi; Rl[o] = f2bf(rv - bf2f(hi));
      }
}

// ------- final2: VI = P + P*(Rh+Rl); same skeleton as resid2 -------
__global__ __launch_bounds__(256) void k_final2(const unsigned short* __restrict__ P,
      const unsigned short* __restrict__ Rh, const unsigned short* __restrict__ Rl,
      unsigned short* __restrict__ VIh, unsigned short* __restrict__ VIl){
  int b = blockIdx.x;
  int i0 = (b>>3)*64, j0 = (b&7)*64;
  __shared__ __align__(16) unsigned short SM[4][3][64*32];
  int t = threadIdx.x, lane = t & 63, wave = t >> 6;
  int wr = wave >> 1, wc = wave & 1;
  int lrow = lane & 15, glog = lane >> 4;
  f32x4 acc[2][2];
  #pragma unroll
  for (int a = 0; a < 2; a++)
    #pragma unroll
    for (int c = 0; c < 2; c++) acc[a][c] = (f32x4){0.f,0.f,0.f,0.f};

  int srow = lane >> 2;
  int sg4  = (lane & 3) ^ ((srow >> 1) & 3);
  const unsigned short* s0 = P  + (size_t)(i0 + wave*16 + srow)*NDIM + sg4*8;
  const unsigned short* s1 = Rh + (size_t)(j0 + wave*16 + srow)*NDIM + sg4*8;
  const unsigned short* s2 = Rl + (size_t)(j0 + wave*16 + srow)*NDIM + sg4*8;

  #define FISSUE(batch) { int kb = (batch)*32; int bf = (batch)&3; \
    gload16(s0 + kb, &SM[bf][0][wave*512]); \
    gload16(s1 + kb, &SM[bf][1][wave*512]); \
    gload16(s2 + kb, &SM[bf][2][wave*512]); }

  FISSUE(0); FISSUE(1);
  for (int kt = 0; kt < 16; kt++){
    int bf = kt & 3;
    if (kt + 2 < 16) FISSUE(kt + 2);
    if (kt <= 13)      { asm volatile("s_waitcnt vmcnt(6)" ::: "memory"); }
    else if (kt == 14) { asm volatile("s_waitcnt vmcnt(3)" ::: "memory"); }
    else               { asm volatile("s_waitcnt vmcnt(0)" ::: "memory"); }
    __builtin_amdgcn_sched_barrier(0);
    __builtin_amdgcn_s_barrier();
    __builtin_amdgcn_sched_barrier(0);

    short8 fa[2], fbh[2], fbl[2];
    #pragma unroll
    for (int f = 0; f < 2; f++){
      int fra = wr*32 + f*16 + lrow;
      fa[f] = *(const short8*)&SM[bf][0][fra*32 + ((glog ^ ((fra>>1)&3))<<3)];
      int frb = wc*32 + f*16 + lrow;
      int offb = frb*32 + ((glog ^ ((frb>>1)&3))<<3);
      fbh[f] = *(const short8*)&SM[bf][1][offb];
      fbl[f] = *(const short8*)&SM[bf][2][offb];
    }
    #pragma unroll
    for (int fi = 0; fi < 2; fi++)
      #pragma unroll
      for (int fj = 0; fj < 2; fj++){
        acc[fi][fj] = __builtin_amdgcn_mfma_f32_16x16x32_bf16(fa[fi], fbh[fj], acc[fi][fj], 0,0,0);
        acc[fi][fj] = __builtin_amdgcn_mfma_f32_16x16x32_bf16(fa[fi], fbl[fj], acc[fi][fj], 0,0,0);
      }
  }
  #undef FISSUE

  #pragma unroll
  for (int fi = 0; fi < 2; fi++)
    #pragma unroll
    for (int fj = 0; fj < 2; fj++)
      #pragma unroll
      for (int e = 0; e < 4; e++){
        int gi = i0 + wr*32 + fi*16 + (lane>>4)*4 + e;
        int gj = j0 + wc*32 + fj*16 + lrow;
        size_t o = (size_t)gi*NDIM + gj;
        float vi = bf2f(P[o]) + acc[fi][fj][e];
        unsigned short hi = f2bf(vi);
        VIh[o] = hi; VIl[o] = f2bf(vi - bf2f(hi));
      }
}

// ------- Z2: 16-wave, tile 128(i) x 64(a), 3-buf DMA pipeline -------
__global__ __launch_bounds__(1024) void k_gemmZ2(const unsigned short* __restrict__ Xth,
    const unsigned short* __restrict__ Xtl, const unsigned short* __restrict__ VIh,
    const unsigned short* __restrict__ VIl, unsigned short* __restrict__ Zt){
  int i0 = blockIdx.x * 128, j0 = blockIdx.y * 64;
  __shared__ __align__(16) unsigned short SMA[3][2][128*32];
  __shared__ __align__(16) unsigned short SMB[3][2][64*32];
  int t = threadIdx.x, lane = t & 63, wave = t >> 6;
  int wr = wave >> 2, wc = wave & 3;
  f32x4 acc[2];
  acc[0] = (f32x4){0.f,0.f,0.f,0.f}; acc[1] = (f32x4){0.f,0.f,0.f,0.f};

  int srow = lane >> 2;
  int sgk  = (lane & 3) ^ ((srow >> 1) & 3);
  int lrow = lane & 15, glog = lane >> 4;

  const unsigned short* srcA0 = Xth + (size_t)(i0 + (wave&7)*16 + srow)*NDIM + sgk*8;
  const unsigned short* srcA1 = Xtl + (size_t)(i0 + (wave&7)*16 + srow)*NDIM + sgk*8;
  int gB = wave & 3;
  const unsigned short* srcB = ((wave < 12) ? VIh : VIl) + (size_t)(j0 + gB*16 + srow)*NDIM + sgk*8;
  int mB = (wave < 12) ? 0 : 1;
  int gA = wave & 7;

  #define ZISSUE(batch) { int kb = (batch)*32; int bf = (batch)%3; \
    if (wave < 8){ gload16(srcA0 + kb, &SMA[bf][0][gA*512]); \
                   gload16(srcA1 + kb, &SMA[bf][1][gA*512]); } \
    else         { gload16(srcB  + kb, &SMB[bf][mB][gB*512]); } }

  ZISSUE(0); ZISSUE(1);
  for (int kt = 0; kt < 16; kt++){
    int bf = kt % 3;
    if (kt + 2 < 16) ZISSUE(kt + 2);
    if (wave < 8){
      if (kt < 14)       { asm volatile("s_waitcnt vmcnt(4)" ::: "memory"); }
      else if (kt == 14) { asm volatile("s_waitcnt vmcnt(2)" ::: "memory"); }
      else               { asm volatile("s_waitcnt vmcnt(0)" ::: "memory"); }
    } else {
      if (kt < 14)       { asm volatile("s_waitcnt vmcnt(2)" ::: "memory"); }
      else if (kt == 14) { asm volatile("s_waitcnt vmcnt(1)" ::: "memory"); }
      else               { asm volatile("s_waitcnt vmcnt(0)" ::: "memory"); }
    }
    __builtin_amdgcn_sched_barrier(0);
    __builtin_amdgcn_s_barrier();
    __builtin_amdgcn_sched_barrier(0);

    short8 ah[2], al[2], bh, bl;
    #pragma unroll
    for (int f = 0; f < 2; f++){
      int fra = wr*32 + f*16 + lrow;
      int offa = fra*32 + ((glog ^ ((fra>>1)&3))<<3);
      ah[f] = *(const short8*)&SMA[bf][0][offa];
      al[f] = *(const short8*)&SMA[bf][1][offa];
    }
    {
      int frb = wc*16 + lrow;
      int offb = frb*32 + ((glog ^ ((frb>>1)&3))<<3);
      bh = *(const short8*)&SMB[bf][0][offb];
      bl = *(const short8*)&SMB[bf][1][offb];
    }
    #pragma unroll
    for (int fi = 0; fi < 2; fi++){
      acc[fi] = __builtin_amdgcn_mfma_f32_16x16x32_bf16(ah[fi], bh, acc[fi], 0,0,0);
      acc[fi] = __builtin_amdgcn_mfma_f32_16x16x32_bf16(ah[fi], bl, acc[fi], 0,0,0);
      acc[fi] = __builtin_amdgcn_mfma_f32_16x16x32_bf16(al[fi], bh, acc[fi], 0,0,0);
    }
    __builtin_amdgcn_sched_barrier(0);
    __builtin_amdgcn_s_barrier();
  }
  #undef ZISSUE

  #pragma unroll
  for (int fi = 0; fi < 2; fi++)
    #pragma unroll
    for (int e = 0; e < 4; e++){
      int gi = i0 + wr*32 + fi*16 + (lane>>4)*4 + e;
      int gj = j0 + wc*16 + lrow;
      Zt[(size_t)gi*NDIM + gj] = f2bf(acc[fi][e]);
    }
}

// ---------------- q[i] = dot(Xth[i,:], Zt[i,:]) ----------------
__global__ void k_q(const unsigned short* __restrict__ Xt, const unsigned short* __restrict__ Zt,
                    float* __restrict__ q){
  int wave = threadIdx.x >> 6, lane = threadIdx.x & 63;
  int i = blockIdx.x * 4 + wave;
  uint4 xv = *(const uint4*)(Xt + (size_t)i*NDIM + lane*8);
  uint4 zv = *(const uint4*)(Zt + (size_t)i*NDIM + lane*8);
  const unsigned short* xs = (const unsigned short*)&xv;
  const unsigned short* zs = (const unsigned short*)&zv;
  float s = 0.f;
  #pragma unroll
  for (int e = 0; e < 8; e++) s += bf2f(xs[e]) * bf2f(zs[e]);
  #pragma unroll
  for (int off = 32; off > 0; off >>= 1) s += __shfl_down(s, off, 64);
  if (lane == 0) q[i] = s;
}

// ------- G: 16-wave blocks, BK=32, 4-buffer DEPTH-2, SINGLE barrier per step -------
__global__ __launch_bounds__(1024) void k_G(const unsigned short* __restrict__ Xt,
        const unsigned short* __restrict__ Zt, const float* __restrict__ q,
        float* __restrict__ out){
  const int NT = NPTS/128; // 32
  int b = (int)blockIdx.x;
  b = (b & 7) * 66 + (b >> 3);     // XCD-bijective chunking (528 = 8*66)
  int ti = 0, rem = b;
  while (rem >= NT - ti){ rem -= NT - ti; ti++; }
  int tj = ti + rem;
  int i0 = ti*128, j0 = tj*128;

  __shared__ __align__(16) unsigned short SMEM[2*4*128*32];
  unsigned short (*At)[128*32] = (unsigned short (*)[128*32])SMEM;
  unsigned short (*Bt)[128*32] = (unsigned short (*)[128*32])(SMEM + 4*128*32);
  float* fsm = (float*)SMEM;

  int t = threadIdx.x, lane = t & 63, wave = t >> 6;   // wave 0..15
  int wr = wave >> 2, wc = wave & 3;                   // 4x4 wave grid, 32x32 sub-tile each
  f32x4 acc[2][2];
  #pragma unroll
  for (int a = 0; a < 2; a++)
    #pragma unroll
    for (int c = 0; c < 2; c++) acc[a][c] = (f32x4){0.f,0.f,0.f,0.f};

  int srow = lane >> 2;
  int sgk  = (lane & 3) ^ ((srow >> 1) & 3);
  int lrow = lane & 15;
  int glog = lane >> 4;

  int sg = wave & 7;
  int srcrow = sg*16 + srow;
  const unsigned short* src = (wave < 8)
      ? (Xt + (size_t)(i0 + srcrow)*NDIM + sgk*8)
      : (Zt + (size_t)(j0 + srcrow)*NDIM + sgk*8);
  unsigned short (*dstb)[128*32] = (wave < 8) ? At : Bt;

  #define ISSUE(batch) { int kb = (batch)*32; int bf = (batch)&3; \
    gload16(src + kb, &dstb[bf][sg*512]); }

  ISSUE(0); ISSUE(1);

  for (int kt = 0; kt < 16; kt++){
    int cur = kt & 3;
    if (kt + 2 < 16) ISSUE(kt + 2);
    if (kt <= 13)      { asm volatile("s_waitcnt vmcnt(2)" ::: "memory"); }
    else if (kt == 14) { asm volatile("s_waitcnt vmcnt(1)" ::: "memory"); }
    else               { asm volatile("s_waitcnt vmcnt(0)" ::: "memory"); }
    __builtin_amdgcn_sched_barrier(0);
    __builtin_amdgcn_s_barrier();
    __builtin_amdgcn_sched_barrier(0);

    short8 af[2], bfr[2];
    #pragma unroll
    for (int f = 0; f < 2; f++){
      int fra = wr*32 + f*16 + lrow;
      int frb = wc*32 + f*16 + lrow;
      af[f]  = *(const short8*)&At[cur][fra*32 + ((glog ^ ((fra>>1)&3))<<3)];
      bfr[f] = *(const short8*)&Bt[cur][frb*32 + ((glog ^ ((frb>>1)&3))<<3)];
    }
    #pragma unroll
    for (int fi = 0; fi < 2; fi++)
      #pragma unroll
      for (int fj = 0; fj < 2; fj++)
        acc[fi][fj] = __builtin_amdgcn_mfma_f32_16x16x32_bf16(af[fi], bfr[fj], acc[fi][fj], 0, 0, 0);
  }
  #undef ISSUE
  __syncthreads();   // all reads done before epilogue overwrites SMEM

  #pragma unroll
  for (int fi = 0; fi < 2; fi++)
    #pragma unroll
    for (int fj = 0; fj < 2; fj++)
      #pragma unroll
      for (int e = 0; e < 4; e++){
        int r = wr*32 + fi*16 + (lane >> 4)*4 + e;
        int c = wc*32 + fj*16 + lrow;
        fsm[r*128 + c] = acc[fi][fj][e];
      }
  __syncthreads();

  #pragma unroll
  for (int i = 0; i < 8; i++){
    int row = wave*8 + i;
    int gi = i0 + row;
    float qi = q[gi];
    size_t rowbase = (size_t)gi*NPTS - ((size_t)gi*(gi+1))/2 - (size_t)gi - 1;
    float2 vv = *(float2*)&fsm[row*128 + lane*2];
    int gj0 = j0 + lane*2, gj1 = gj0 + 1;
    if (gi < gj0) out[rowbase + gj0] = sqrtf(fmaxf(qi + q[gj0] - 2.0f*vv.x, 1e-12f));
    if (gi < gj1) out[rowbase + gj1] = sqrtf(fmaxf(qi + q[gj1] - 2.0f*vv.y, 1e-12f));
  }
}

extern "C" void kernel_launch(void* const* d_in, const int* in_sizes, int n_in,
                              void* d_out, int out_size, void* d_ws, size_t ws_size,
                              hipStream_t stream) {
  (void)in_sizes; (void)n_in; (void)out_size; (void)ws_size;
  const float* x0 = (const float*)d_in[0];
  const float* x1 = (const float*)d_in[1];
  float* out = (float*)d_out;

  char* w = (char*)d_ws;
  float* mu     = (float*)w; w += 4096;
  float* q      = (float*)w; w += NPTS*4;
  unsigned short* Vh = (unsigned short*)w; w += (size_t)NDIM*NDIM*2;
  unsigned short* Vl = (unsigned short*)w; w += (size_t)NDIM*NDIM*2;
  unsigned short* E0 = (unsigned short*)w; w += (size_t)NDIM*NDIM*2;
  unsigned short* E1 = (unsigned short*)w; w += (size_t)NDIM*NDIM*2;
  unsigned short* P0 = (unsigned short*)w; w += (size_t)NDIM*NDIM*2;
  unsigned short* P1 = (unsigned short*)w; w += (size_t)NDIM*NDIM*2;
  unsigned short* Xch = (unsigned short*)w; w += (size_t)NDIM*NPTS*2;
  unsigned short* Xcl = (unsigned short*)w; w += (size_t)NDIM*NPTS*2;
  unsigned short* Xth = (unsigned short*)w; w += (size_t)NDIM*NPTS*2;
  unsigned short* Xtl = (unsigned short*)w; w += (size_t)NDIM*NPTS*2;
  char* uspan = w;
  unsigned short* Rh  = (unsigned short*)uspan;
  unsigned short* Rl  = Rh + (size_t)NDIM*NDIM;
  unsigned short* VIh = Rl + (size_t)NDIM*NDIM;
  unsigned short* VIl = VIh + (size_t)NDIM*NDIM;
  unsigned short* Zt  = VIl + (size_t)NDIM*NDIM;
  float* Vp = (float*)uspan;  // VZ x 1MB partials, dead after k_finVinit

  k_rowmean<<<dim3(512), dim3(256), 0, stream>>>(x0, x1, mu);
  k_prep<<<dim3(64,8), dim3(256), 0, stream>>>(x0, x1, mu, Xch, Xcl, Xth, Xtl);
  k_V2<<<dim3(10, VZ), dim3(1024), 0, stream>>>(Xch, Xcl, Vp);
  k_finVinit<<<dim3(512), dim3(64), 0, stream>>>(Vp, Vh, Vl, E0, P0);

  unsigned short *Ec = E0, *En = E1, *Pc = P0, *Pn = P1;
  for (int it = 0; it < 3; ++it){
    k_ns2<<<dim3(128), dim3(256), 0, stream>>>(Ec, Pc, En, Pn);
    unsigned short* tmp;
    tmp = Ec; Ec = En; En = tmp;
    tmp = Pc; Pc = Pn; Pn = tmp;
  }
  k_resid2<<<dim3(64), dim3(256), 0, stream>>>(Vh, Vl, Pc, Rh, Rl);
  k_final2<<<dim3(64), dim3(256), 0, stream>>>(Pc, Rh, Rl, VIh, VIl);
  k_gemmZ2<<<dim3(32,8), dim3(1024), 0, stream>>>(Xth, Xtl, VIh, VIl, Zt);
  k_q<<<dim3(1024), dim3(256), 0, stream>>>(Xth, Zt, q);
  k_G<<<dim3(528), dim3(1024), 0, stream>>>(Xth, Zt, q, out);
}

// Round 16
// 113.393 us; speedup vs baseline: 1.5852x; 1.0035x over previous
//
#include <hip/hip_runtime.h>
#include <hip/hip_bf16.h>
#include <math.h>

#define NDIM 512
#define NPTS 4096
#define VZ 16

typedef __attribute__((ext_vector_type(4))) float f32x4;
typedef __attribute__((ext_vector_type(8))) short short8;

__device__ __forceinline__ const float* xrow(const float* x0, const float* x1, int r){
  return (r < 256) ? (x0 + (size_t)r * NPTS) : (x1 + (size_t)(r - 256) * NPTS);
}
__device__ __forceinline__ unsigned short f2bf(float f){
  __hip_bfloat16 h = __float2bfloat16(f);
  return *reinterpret_cast<unsigned short*>(&h);
}
__device__ __forceinline__ float bf2f(unsigned short u){
  return __uint_as_float(((unsigned int)u) << 16);
}
__device__ __forceinline__ void gload16(const void* g, void* l){
  __builtin_amdgcn_global_load_lds((const __attribute__((address_space(1))) void*)g,
                                   (__attribute__((address_space(3))) void*)l, 16, 0, 0);
}

// ---------------- row means of X (512 rows x 4096) ----------------
__global__ void k_rowmean(const float* __restrict__ x0, const float* __restrict__ x1,
                          float* __restrict__ mu){
  int r = blockIdx.x;
  const float4* row4 = (const float4*)xrow(x0, x1, r);
  float s = 0.f;
  for (int c = threadIdx.x; c < NPTS/4; c += 256){
    float4 v = row4[c];
    s += v.x + v.y + v.z + v.w;
  }
  __shared__ float red[256];
  red[threadIdx.x] = s; __syncthreads();
  for (int off = 128; off > 0; off >>= 1){
    if (threadIdx.x < off) red[threadIdx.x] += red[threadIdx.x + off];
    __syncthreads();
  }
  if (threadIdx.x == 0) mu[r] = red[0] * (1.0f / NPTS);
}

// ------- prep: centered X in bf16 hi/lo, both layouts -------
__global__ __launch_bounds__(256) void k_prep(const float* __restrict__ x0, const float* __restrict__ x1,
      const float* __restrict__ mu,
      unsigned short* __restrict__ Xch, unsigned short* __restrict__ Xcl,
      unsigned short* __restrict__ Xth, unsigned short* __restrict__ Xtl){
  __shared__ float tile[64][65];
  int i0 = blockIdx.x * 64, a0 = blockIdx.y * 64;
  int t = threadIdx.x;
  int r = t >> 2, cg = (t & 3) * 16;
  const float* row = xrow(x0, x1, a0 + r);
  float m = mu[a0 + r];
  unsigned short h16[16] __attribute__((aligned(16)));
  unsigned short l16[16] __attribute__((aligned(16)));
  #pragma unroll
  for (int e = 0; e < 16; e += 4){
    float4 v = *(const float4*)(row + i0 + cg + e);
    v.x -= m; v.y -= m; v.z -= m; v.w -= m;
    tile[r][cg+e] = v.x; tile[r][cg+e+1] = v.y; tile[r][cg+e+2] = v.z; tile[r][cg+e+3] = v.w;
    h16[e]   = f2bf(v.x); l16[e]   = f2bf(v.x - bf2f(h16[e]));
    h16[e+1] = f2bf(v.y); l16[e+1] = f2bf(v.y - bf2f(h16[e+1]));
    h16[e+2] = f2bf(v.z); l16[e+2] = f2bf(v.z - bf2f(h16[e+2]));
    h16[e+3] = f2bf(v.w); l16[e+3] = f2bf(v.w - bf2f(h16[e+3]));
  }
  unsigned short* dst = Xch + (size_t)(a0+r)*NPTS + i0 + cg;
  *(uint4*)dst = *(uint4*)&h16[0]; *(uint4*)(dst+8) = *(uint4*)&h16[8];
  dst = Xcl + (size_t)(a0+r)*NPTS + i0 + cg;
  *(uint4*)dst = *(uint4*)&l16[0]; *(uint4*)(dst+8) = *(uint4*)&l16[8];
  __syncthreads();
  unsigned short th[16] __attribute__((aligned(16)));
  unsigned short tl[16] __attribute__((aligned(16)));
  #pragma unroll
  for (int e = 0; e < 16; e++){
    float v = tile[cg+e][r];
    th[e] = f2bf(v); tl[e] = f2bf(v - bf2f(th[e]));
  }
  unsigned short* d2 = Xth + (size_t)(i0 + r)*NDIM + a0 + cg;
  *(uint4*)d2 = *(uint4*)&th[0]; *(uint4*)(d2+8) = *(uint4*)&th[8];
  d2 = Xtl + (size_t)(i0 + r)*NDIM + a0 + cg;
  *(uint4*)d2 = *(uint4*)&tl[0]; *(uint4*)(d2+8) = *(uint4*)&tl[8];
}

// ------- V2: 16-wave blocks, 128x128 tri-tiles x 16 K-slices, 3-buf DMA pipeline -------
__global__ __launch_bounds__(1024) void k_V2(const unsigned short* __restrict__ Xch,
        const unsigned short* __restrict__ Xcl, float* __restrict__ Vp){
  int b = blockIdx.x;                  // 0..9 upper-tri tile of 4x4
  int ti = 0, rem = b;
  while (rem >= 4 - ti){ rem -= 4 - ti; ti++; }
  int tj = ti + rem;
  int i0 = ti*128, j0 = tj*128;
  int z = blockIdx.y;                  // 0..15
  size_t kbase = (size_t)z * (NPTS/VZ);  // 256-wide K slice

  __shared__ __align__(16) unsigned short SM[3][4][128*32];
  int t = threadIdx.x, lane = t & 63, wave = t >> 6;
  int wr = wave >> 2, wc = wave & 3;
  f32x4 acc[2][2];
  #pragma unroll
  for (int a = 0; a < 2; a++)
    #pragma unroll
    for (int c = 0; c < 2; c++) acc[a][c] = (f32x4){0.f,0.f,0.f,0.f};

  int srow = lane >> 2;
  int sgk  = (lane & 3) ^ ((srow >> 1) & 3);
  int lrow = lane & 15, glog = lane >> 4;

  int sl0 = wave*2, sl1 = wave*2 + 1;
  int m0 = sl0 >> 3, g0 = sl0 & 7;
  int m1 = sl1 >> 3, g1 = sl1 & 7;
  const unsigned short* b0 = (m0 & 1) ? Xcl : Xch;
  const unsigned short* b1 = (m1 & 1) ? Xcl : Xch;
  int r0 = ((m0 < 2) ? i0 : j0) + g0*16 + srow;
  int r1 = ((m1 < 2) ? i0 : j0) + g1*16 + srow;
  const unsigned short* src0 = b0 + (size_t)r0*NPTS + kbase + sgk*8;
  const unsigned short* src1 = b1 + (size_t)r1*NPTS + kbase + sgk*8;

  #define VISSUE(batch) { int kb = (batch)*32; int bf = (batch)%3; \
    gload16(src0 + kb, &SM[bf][m0][g0*512]); \
    gload16(src1 + kb, &SM[bf][m1][g1*512]); }

  VISSUE(0); VISSUE(1);
  for (int kt = 0; kt < 8; kt++){
    int bf = kt % 3;
    if (kt + 2 < 8) VISSUE(kt + 2);
    if (kt < 6)       { asm volatile("s_waitcnt vmcnt(4)" ::: "memory"); }
    else if (kt == 6) { asm volatile("s_waitcnt vmcnt(2)" ::: "memory"); }
    else              { asm volatile("s_waitcnt vmcnt(0)" ::: "memory"); }
    __builtin_amdgcn_sched_barrier(0);
    __builtin_amdgcn_s_barrier();
    __builtin_amdgcn_sched_barrier(0);

    short8 ah[2], al[2], bh[2], bl[2];
    #pragma unroll
    for (int f = 0; f < 2; f++){
      int fra = wr*32 + f*16 + lrow;
      int offa = fra*32 + ((glog ^ ((fra>>1)&3))<<3);
      ah[f] = *(const short8*)&SM[bf][0][offa];
      al[f] = *(const short8*)&SM[bf][1][offa];
      int frb = wc*32 + f*16 + lrow;
      int offb = frb*32 + ((glog ^ ((frb>>1)&3))<<3);
      bh[f] = *(const short8*)&SM[bf][2][offb];
      bl[f] = *(const short8*)&SM[bf][3][offb];
    }
    #pragma unroll
    for (int fi = 0; fi < 2; fi++)
      #pragma unroll
      for (int fj = 0; fj < 2; fj++){
        acc[fi][fj] = __builtin_amdgcn_mfma_f32_16x16x32_bf16(ah[fi], bh[fj], acc[fi][fj], 0,0,0);
        acc[fi][fj] = __builtin_amdgcn_mfma_f32_16x16x32_bf16(ah[fi], bl[fj], acc[fi][fj], 0,0,0);
        acc[fi][fj] = __builtin_amdgcn_mfma_f32_16x16x32_bf16(al[fi], bh[fj], acc[fi][fj], 0,0,0);
      }
    __builtin_amdgcn_sched_barrier(0);
    __builtin_amdgcn_s_barrier();
  }
  #undef VISSUE

  float* dst = Vp + (size_t)z*NDIM*NDIM;
  #pragma unroll
  for (int fi = 0; fi < 2; fi++)
    #pragma unroll
    for (int fj = 0; fj < 2; fj++)
      #pragma unroll
      for (int e = 0; e < 4; e++){
        int gi = i0 + wr*32 + fi*16 + (lane>>4)*4 + e;
        int gj = j0 + wc*32 + fj*16 + lrow;
        dst[(size_t)gi*NDIM + gj] = acc[fi][fj][e];
        if (ti != tj) dst[(size_t)gj*NDIM + gi] = acc[fi][fj][e];
      }
}

// ------- finVinit: V=sum(Vp)/4095; write Vh/Vl, E0=I-cV, P0=cI -------
__global__ void k_finVinit(const float* __restrict__ Vp,
      unsigned short* __restrict__ Vh, unsigned short* __restrict__ Vl,
      unsigned short* __restrict__ E0, unsigned short* __restrict__ P0){
  const float c = 0.869565217f;
  int r = blockIdx.x, lane = threadIdx.x; // 64 threads
  const size_t S = (size_t)NDIM*NDIM;
  float a[8] = {0,0,0,0,0,0,0,0};
  #pragma unroll
  for (int z = 0; z < VZ; z++){
    const float* p = Vp + z*S + (size_t)r*NDIM + lane*8;
    float4 u = *(const float4*)p;
    float4 v = *(const float4*)(p+4);
    a[0]+=u.x; a[1]+=u.y; a[2]+=u.z; a[3]+=u.w;
    a[4]+=v.x; a[5]+=v.y; a[6]+=v.z; a[7]+=v.w;
  }
  const float s = 1.0f/4095.0f;
  unsigned short vh[8] __attribute__((aligned(16))), vl[8] __attribute__((aligned(16)));
  unsigned short e8[8] __attribute__((aligned(16))), p8[8] __attribute__((aligned(16)));
  #pragma unroll
  for (int e = 0; e < 8; e++){
    float v = a[e]*s;
    vh[e] = f2bf(v); vl[e] = f2bf(v - bf2f(vh[e]));
    int col = lane*8 + e;
    e8[e] = f2bf(((col==r)?1.f:0.f) - c*v);
    p8[e] = f2bf((col==r)?c:0.f);
  }
  size_t o = (size_t)r*NDIM + lane*8;
  *(uint4*)&Vh[o] = *(uint4*)vh; *(uint4*)&Vl[o] = *(uint4*)vl;
  *(uint4*)&E0[o] = *(uint4*)e8; *(uint4*)&P0[o] = *(uint4*)p8;
}

// ------- ns2: DMA-pipelined fused NS iter. blocks 0-63: En=E*E ; 64-127: Pn=P+P*E -------
__global__ __launch_bounds__(256) void k_ns2(const unsigned short* __restrict__ E,
      const unsigned short* __restrict__ P,
      unsigned short* __restrict__ En, unsigned short* __restrict__ Pn){
  int b = blockIdx.x;
  int half = b >> 6, tile = b & 63;
  int i0 = (tile>>3)*64, j0 = (tile&7)*64;
  const unsigned short* Asrc = half ? P : E;
  __shared__ __align__(16) unsigned short SM[4][2][64*64];
  int t = threadIdx.x, lane = t & 63, wave = t >> 6;
  int wr = wave >> 1, wc = wave & 1;
  int lrow = lane & 15, glog = lane >> 4;
  f32x4 acc[2][2];
  #pragma unroll
  for (int a = 0; a < 2; a++)
    #pragma unroll
    for (int c = 0; c < 2; c++) acc[a][c] = (f32x4){0.f,0.f,0.f,0.f};

  int srow = lane >> 3;                 // 0..7 row within group
  int sg8  = (lane & 7) ^ (srow & 7);   // pre-swizzled source granule (16B)
  int gA0 = wave*2, gA1 = wave*2 + 1;
  const unsigned short* srcA0 = Asrc + (size_t)(i0 + gA0*8 + srow)*NDIM + sg8*8;
  const unsigned short* srcA1 = Asrc + (size_t)(i0 + gA1*8 + srow)*NDIM + sg8*8;
  const unsigned short* srcB0 = E + (size_t)(j0 + gA0*8 + srow)*NDIM + sg8*8;
  const unsigned short* srcB1 = E + (size_t)(j0 + gA1*8 + srow)*NDIM + sg8*8;

  #define NISSUE(batch) { int kb = (batch)*64; int bf = (batch)&3; \
    gload16(srcA0 + kb, &SM[bf][0][gA0*512]); \
    gload16(srcA1 + kb, &SM[bf][0][gA1*512]); \
    gload16(srcB0 + kb, &SM[bf][1][gA0*512]); \
    gload16(srcB1 + kb, &SM[bf][1][gA1*512]); }

  NISSUE(0); NISSUE(1);
  for (int kt = 0; kt < 8; kt++){
    int bf = kt & 3;
    if (kt + 2 < 8) NISSUE(kt + 2);
    if (kt <= 5)      { asm volatile("s_waitcnt vmcnt(8)" ::: "memory"); }
    else if (kt == 6) { asm volatile("s_waitcnt vmcnt(4)" ::: "memory"); }
    else              { asm volatile("s_waitcnt vmcnt(0)" ::: "memory"); }
    __builtin_amdgcn_sched_barrier(0);
    __builtin_amdgcn_s_barrier();
    __builtin_amdgcn_sched_barrier(0);

    #pragma unroll
    for (int c = 0; c < 2; c++){
      short8 fa[2], fb[2];
      #pragma unroll
      for (int f = 0; f < 2; f++){
        int fra = wr*32 + f*16 + lrow;
        fa[f] = *(const short8*)&SM[bf][0][fra*64 + (((c*4+glog) ^ (fra&7))<<3)];
        int frb = wc*32 + f*16 + lrow;
        fb[f] = *(const short8*)&SM[bf][1][frb*64 + (((c*4+glog) ^ (frb&7))<<3)];
      }
      #pragma unroll
      for (int fi = 0; fi < 2; fi++)
        #pragma unroll
        for (int fj = 0; fj < 2; fj++)
          acc[fi][fj] = __builtin_amdgcn_mfma_f32_16x16x32_bf16(fa[fi], fb[fj], acc[fi][fj], 0,0,0);
    }
  }
  #undef NISSUE

  #pragma unroll
  for (int fi = 0; fi < 2; fi++)
    #pragma unroll
    for (int fj = 0; fj < 2; fj++)
      #pragma unroll
      for (int e = 0; e < 4; e++){
        int gi = i0 + wr*32 + fi*16 + (lane>>4)*4 + e;
        int gj = j0 + wc*32 + fj*16 + lrow;
        size_t o = (size_t)gi*NDIM + gj;
        if (half) Pn[o] = f2bf(bf2f(P[o]) + acc[fi][fj][e]);
        else      En[o] = f2bf(acc[fi][fj][e]);
      }
}

// ------- resid2: R = I - (Vh+Vl)*P transposed hi/lo; BK=32, 48KB, depth-2 single barrier -------
__global__ __launch_bounds__(256) void k_resid2(const unsigned short* __restrict__ Vh,
      const unsigned short* __restrict__ Vl, const unsigned short* __restrict__ P,
      unsigned short* __restrict__ Rh, unsigned short* __restrict__ Rl){
  int b = blockIdx.x;
  int i0 = (b>>3)*64, j0 = (b&7)*64;
  __shared__ __align__(16) unsigned short SM[4][3][64*32];
  int t = threadIdx.x, lane = t & 63, wave = t >> 6;
  int wr = wave >> 1, wc = wave & 1;
  int lrow = lane & 15, glog = lane >> 4;
  f32x4 acc[2][2];
  #pragma unroll
  for (int a = 0; a < 2; a++)
    #pragma unroll
    for (int c = 0; c < 2; c++) acc[a][c] = (f32x4){0.f,0.f,0.f,0.f};

  int srow = lane >> 2;
  int sg4  = (lane & 3) ^ ((srow >> 1) & 3);
  const unsigned short* s0 = Vh + (size_t)(i0 + wave*16 + srow)*NDIM + sg4*8;
  const unsigned short* s1 = Vl + (size_t)(i0 + wave*16 + srow)*NDIM + sg4*8;
  const unsigned short* s2 = P  + (size_t)(j0 + wave*16 + srow)*NDIM + sg4*8;

  #define RISSUE(batch) { int kb = (batch)*32; int bf = (batch)&3; \
    gload16(s0 + kb, &SM[bf][0][wave*512]); \
    gload16(s1 + kb, &SM[bf][1][wave*512]); \
    gload16(s2 + kb, &SM[bf][2][wave*512]); }

  RISSUE(0); RISSUE(1);
  for (int kt = 0; kt < 16; kt++){
    int bf = kt & 3;
    if (kt + 2 < 16) RISSUE(kt + 2);
    if (kt <= 13)      { asm volatile("s_waitcnt vmcnt(6)" ::: "memory"); }
    else if (kt == 14) { asm volatile("s_waitcnt vmcnt(3)" ::: "memory"); }
    else               { asm volatile("s_waitcnt vmcnt(0)" ::: "memory"); }
    __builtin_amdgcn_sched_barrier(0);
    __builtin_amdgcn_s_barrier();
    __builtin_amdgcn_sched_barrier(0);

    short8 fah[2], fal[2], fb[2];
    #pragma unroll
    for (int f = 0; f < 2; f++){
      int fra = wr*32 + f*16 + lrow;
      int offa = fra*32 + ((glog ^ ((fra>>1)&3))<<3);
      fah[f] = *(const short8*)&SM[bf][0][offa];
      fal[f] = *(const short8*)&SM[bf][1][offa];
      int frb = wc*32 + f*16 + lrow;
      fb[f]  = *(const short8*)&SM[bf][2][frb*32 + ((glog ^ ((frb>>1)&3))<<3)];
    }
    #pragma unroll
    for (int fi = 0; fi < 2; fi++)
      #pragma unroll
      for (int fj = 0; fj < 2; fj++){
        acc[fi][fj] = __builtin_amdgcn_mfma_f32_16x16x32_bf16(fah[fi], fb[fj], acc[fi][fj], 0,0,0);
        acc[fi][fj] = __builtin_amdgcn_mfma_f32_16x16x32_bf16(fal[fi], fb[fj], acc[fi][fj], 0,0,0);
      }
  }
  #undef RISSUE

  #pragma unroll
  for (int fi = 0; fi < 2; fi++)
    #pragma unroll
    for (int fj = 0; fj < 2; fj++)
      #pragma unroll
      for (int e = 0; e < 4; e++){
        int gi = i0 + wr*32 + fi*16 + (lane>>4)*4 + e;
        int gj = j0 + wc*32 + fj*16 + lrow;
        float rv = ((gi==gj)?1.f:0.f) - acc[fi][fj][e];
        unsigned short hi = f2bf(rv);
        size_t o = (size_t)gj*NDIM + gi;   // transposed store
        Rh[o] = hi; Rl[o] = f2bf(rv - bf2f(hi));
      }
}

// ------- final2: VI = P + P*(Rh+Rl); same skeleton as resid2 -------
__global__ __launch_bounds__(256) void k_final2(const unsigned short* __restrict__ P,
      const unsigned short* __restrict__ Rh, const unsigned short* __restrict__ Rl,
      unsigned short* __restrict__ VIh, unsigned short* __restrict__ VIl){
  int b = blockIdx.x;
  int i0 = (b>>3)*64, j0 = (b&7)*64;
  __shared__ __align__(16) unsigned short SM[4][3][64*32];
  int t = threadIdx.x, lane = t & 63, wave = t >> 6;
  int wr = wave >> 1, wc = wave & 1;
  int lrow = lane & 15, glog = lane >> 4;
  f32x4 acc[2][2];
  #pragma unroll
  for (int a = 0; a < 2; a++)
    #pragma unroll
    for (int c = 0; c < 2; c++) acc[a][c] = (f32x4){0.f,0.f,0.f,0.f};

  int srow = lane >> 2;
  int sg4  = (lane & 3) ^ ((srow >> 1) & 3);
  const unsigned short* s0 = P  + (size_t)(i0 + wave*16 + srow)*NDIM + sg4*8;
  const unsigned short* s1 = Rh + (size_t)(j0 + wave*16 + srow)*NDIM + sg4*8;
  const unsigned short* s2 = Rl + (size_t)(j0 + wave*16 + srow)*NDIM + sg4*8;

  #define FISSUE(batch) { int kb = (batch)*32; int bf = (batch)&3; \
    gload16(s0 + kb, &SM[bf][0][wave*512]); \
    gload16(s1 + kb, &SM[bf][1][wave*512]); \
    gload16(s2 + kb, &SM[bf][2][wave*512]); }

  FISSUE(0); FISSUE(1);
  for (int kt = 0; kt < 16; kt++){
    int bf = kt & 3;
    if (kt + 2 < 16) FISSUE(kt + 2);
    if (kt <= 13)      { asm volatile("s_waitcnt vmcnt(6)" ::: "memory"); }
    else if (kt == 14) { asm volatile("s_waitcnt vmcnt(3)" ::: "memory"); }
    else               { asm volatile("s_waitcnt vmcnt(0)" ::: "memory"); }
    __builtin_amdgcn_sched_barrier(0);
    __builtin_amdgcn_s_barrier();
    __builtin_amdgcn_sched_barrier(0);

    short8 fa[2], fbh[2], fbl[2];
    #pragma unroll
    for (int f = 0; f < 2; f++){
      int fra = wr*32 + f*16 + lrow;
      fa[f] = *(const short8*)&SM[bf][0][fra*32 + ((glog ^ ((fra>>1)&3))<<3)];
      int frb = wc*32 + f*16 + lrow;
      int offb = frb*32 + ((glog ^ ((frb>>1)&3))<<3);
      fbh[f] = *(const short8*)&SM[bf][1][offb];
      fbl[f] = *(const short8*)&SM[bf][2][offb];
    }
    #pragma unroll
    for (int fi = 0; fi < 2; fi++)
      #pragma unroll
      for (int fj = 0; fj < 2; fj++){
        acc[fi][fj] = __builtin_amdgcn_mfma_f32_16x16x32_bf16(fa[fi], fbh[fj], acc[fi][fj], 0,0,0);
        acc[fi][fj] = __builtin_amdgcn_mfma_f32_16x16x32_bf16(fa[fi], fbl[fj], acc[fi][fj], 0,0,0);
      }
  }
  #undef FISSUE

  #pragma unroll
  for (int fi = 0; fi < 2; fi++)
    #pragma unroll
    for (int fj = 0; fj < 2; fj++)
      #pragma unroll
      for (int e = 0; e < 4; e++){
        int gi = i0 + wr*32 + fi*16 + (lane>>4)*4 + e;
        int gj = j0 + wc*32 + fj*16 + lrow;
        size_t o = (size_t)gi*NDIM + gj;
        float vi = bf2f(P[o]) + acc[fi][fj][e];
        unsigned short hi = f2bf(vi);
        VIh[o] = hi; VIl[o] = f2bf(vi - bf2f(hi));
      }
}

// ------- Z2: 16-wave, tile 128(i) x 64(a), 3-buf DMA pipeline -------
__global__ __launch_bounds__(1024) void k_gemmZ2(const unsigned short* __restrict__ Xth,
    const unsigned short* __restrict__ Xtl, const unsigned short* __restrict__ VIh,
    const unsigned short* __restrict__ VIl, unsigned short* __restrict__ Zt){
  int i0 = blockIdx.x * 128, j0 = blockIdx.y * 64;
  __shared__ __align__(16) unsigned short SMA[3][2][128*32];
  __shared__ __align__(16) unsigned short SMB[3][2][64*32];
  int t = threadIdx.x, lane = t & 63, wave = t >> 6;
  int wr = wave >> 2, wc = wave & 3;
  f32x4 acc[2];
  acc[0] = (f32x4){0.f,0.f,0.f,0.f}; acc[1] = (f32x4){0.f,0.f,0.f,0.f};

  int srow = lane >> 2;
  int sgk  = (lane & 3) ^ ((srow >> 1) & 3);
  int lrow = lane & 15, glog = lane >> 4;

  const unsigned short* srcA0 = Xth + (size_t)(i0 + (wave&7)*16 + srow)*NDIM + sgk*8;
  const unsigned short* srcA1 = Xtl + (size_t)(i0 + (wave&7)*16 + srow)*NDIM + sgk*8;
  int gB = wave & 3;
  const unsigned short* srcB = ((wave < 12) ? VIh : VIl) + (size_t)(j0 + gB*16 + srow)*NDIM + sgk*8;
  int mB = (wave < 12) ? 0 : 1;
  int gA = wave & 7;

  #define ZISSUE(batch) { int kb = (batch)*32; int bf = (batch)%3; \
    if (wave < 8){ gload16(srcA0 + kb, &SMA[bf][0][gA*512]); \
                   gload16(srcA1 + kb, &SMA[bf][1][gA*512]); } \
    else         { gload16(srcB  + kb, &SMB[bf][mB][gB*512]); } }

  ZISSUE(0); ZISSUE(1);
  for (int kt = 0; kt < 16; kt++){
    int bf = kt % 3;
    if (kt + 2 < 16) ZISSUE(kt + 2);
    if (wave < 8){
      if (kt < 14)       { asm volatile("s_waitcnt vmcnt(4)" ::: "memory"); }
      else if (kt == 14) { asm volatile("s_waitcnt vmcnt(2)" ::: "memory"); }
      else               { asm volatile("s_waitcnt vmcnt(0)" ::: "memory"); }
    } else {
      if (kt < 14)       { asm volatile("s_waitcnt vmcnt(2)" ::: "memory"); }
      else if (kt == 14) { asm volatile("s_waitcnt vmcnt(1)" ::: "memory"); }
      else               { asm volatile("s_waitcnt vmcnt(0)" ::: "memory"); }
    }
    __builtin_amdgcn_sched_barrier(0);
    __builtin_amdgcn_s_barrier();
    __builtin_amdgcn_sched_barrier(0);

    short8 ah[2], al[2], bh, bl;
    #pragma unroll
    for (int f = 0; f < 2; f++){
      int fra = wr*32 + f*16 + lrow;
      int offa = fra*32 + ((glog ^ ((fra>>1)&3))<<3);
      ah[f] = *(const short8*)&SMA[bf][0][offa];
      al[f] = *(const short8*)&SMA[bf][1][offa];
    }
    {
      int frb = wc*16 + lrow;
      int offb = frb*32 + ((glog ^ ((frb>>1)&3))<<3);
      bh = *(const short8*)&SMB[bf][0][offb];
      bl = *(const short8*)&SMB[bf][1][offb];
    }
    #pragma unroll
    for (int fi = 0; fi < 2; fi++){
      acc[fi] = __builtin_amdgcn_mfma_f32_16x16x32_bf16(ah[fi], bh, acc[fi], 0,0,0);
      acc[fi] = __builtin_amdgcn_mfma_f32_16x16x32_bf16(ah[fi], bl, acc[fi], 0,0,0);
      acc[fi] = __builtin_amdgcn_mfma_f32_16x16x32_bf16(al[fi], bh, acc[fi], 0,0,0);
    }
    __builtin_amdgcn_sched_barrier(0);
    __builtin_amdgcn_s_barrier();
  }
  #undef ZISSUE

  #pragma unroll
  for (int fi = 0; fi < 2; fi++)
    #pragma unroll
    for (int e = 0; e < 4; e++){
      int gi = i0 + wr*32 + fi*16 + (lane>>4)*4 + e;
      int gj = j0 + wc*16 + lrow;
      Zt[(size_t)gi*NDIM + gj] = f2bf(acc[fi][e]);
    }
}

// ---------------- q[i] = dot(Xth[i,:], Zt[i,:]) ----------------
__global__ void k_q(const unsigned short* __restrict__ Xt, const unsigned short* __restrict__ Zt,
                    float* __restrict__ q){
  int wave = threadIdx.x >> 6, lane = threadIdx.x & 63;
  int i = blockIdx.x * 4 + wave;
  uint4 xv = *(const uint4*)(Xt + (size_t)i*NDIM + lane*8);
  uint4 zv = *(const uint4*)(Zt + (size_t)i*NDIM + lane*8);
  const unsigned short* xs = (const unsigned short*)&xv;
  const unsigned short* zs = (const unsigned short*)&zv;
  float s = 0.f;
  #pragma unroll
  for (int e = 0; e < 8; e++) s += bf2f(xs[e]) * bf2f(zs[e]);
  #pragma unroll
  for (int off = 32; off > 0; off >>= 1) s += __shfl_down(s, off, 64);
  if (lane == 0) q[i] = s;
}

// ------- G: 16-wave, BK=32, 4-buffer, DOUBLE-step windows, ONE barrier per window -------
// Window kt (kt even): wait own 2 prefetch loads (full window of cover) -> barrier ->
// issue batches kt+2,kt+3 (their target buffers were read in window kt-2; reads done
// before this barrier) -> compute batches kt,kt+1. 8 barriers total.
__global__ __launch_bounds__(1024) void k_G(const unsigned short* __restrict__ Xt,
        const unsigned short* __restrict__ Zt, const float* __restrict__ q,
        float* __restrict__ out){
  const int NT = NPTS/128; // 32
  int b = (int)blockIdx.x;
  b = (b & 7) * 66 + (b >> 3);     // XCD-bijective chunking (528 = 8*66)
  int ti = 0, rem = b;
  while (rem >= NT - ti){ rem -= NT - ti; ti++; }
  int tj = ti + rem;
  int i0 = ti*128, j0 = tj*128;

  __shared__ __align__(16) unsigned short SMEM[2*4*128*32];
  unsigned short (*At)[128*32] = (unsigned short (*)[128*32])SMEM;
  unsigned short (*Bt)[128*32] = (unsigned short (*)[128*32])(SMEM + 4*128*32);
  float* fsm = (float*)SMEM;

  int t = threadIdx.x, lane = t & 63, wave = t >> 6;   // wave 0..15
  int wr = wave >> 2, wc = wave & 3;                   // 4x4 wave grid, 32x32 sub-tile each
  f32x4 acc[2][2];
  #pragma unroll
  for (int a = 0; a < 2; a++)
    #pragma unroll
    for (int c = 0; c < 2; c++) acc[a][c] = (f32x4){0.f,0.f,0.f,0.f};

  int srow = lane >> 2;
  int sgk  = (lane & 3) ^ ((srow >> 1) & 3);
  int lrow = lane & 15;
  int glog = lane >> 4;

  int sg = wave & 7;
  int srcrow = sg*16 + srow;
  const unsigned short* src = (wave < 8)
      ? (Xt + (size_t)(i0 + srcrow)*NDIM + sgk*8)
      : (Zt + (size_t)(j0 + srcrow)*NDIM + sgk*8);
  unsigned short (*dstb)[128*32] = (wave < 8) ? At : Bt;

  #define ISSUE(batch) { int kb = (batch)*32; int bf = (batch)&3; \
    gload16(src + kb, &dstb[bf][sg*512]); }

  ISSUE(0); ISSUE(1);

  #pragma unroll
  for (int kt = 0; kt < 16; kt += 2){
    // own 2 prefetch loads (batches kt,kt+1) had a full window to land
    asm volatile("s_waitcnt vmcnt(0)" ::: "memory");
    __builtin_amdgcn_sched_barrier(0);
    __builtin_amdgcn_s_barrier();      // all waves: batches kt,kt+1 in LDS; reads of
    __builtin_amdgcn_sched_barrier(0); // buffers (kt+2)&3,(kt+3)&3 (window kt-2) done
    if (kt + 2 < 16){ ISSUE(kt + 2); ISSUE(kt + 3); }

    #pragma unroll
    for (int s2 = 0; s2 < 2; s2++){
      int cur = (kt + s2) & 3;
      short8 af[2], bfr[2];
      #pragma unroll
      for (int f = 0; f < 2; f++){
        int fra = wr*32 + f*16 + lrow;
        int frb = wc*32 + f*16 + lrow;
        af[f]  = *(const short8*)&At[cur][fra*32 + ((glog ^ ((fra>>1)&3))<<3)];
        bfr[f] = *(const short8*)&Bt[cur][frb*32 + ((glog ^ ((frb>>1)&3))<<3)];
      }
      #pragma unroll
      for (int fi = 0; fi < 2; fi++)
        #pragma unroll
        for (int fj = 0; fj < 2; fj++)
          acc[fi][fj] = __builtin_amdgcn_mfma_f32_16x16x32_bf16(af[fi], bfr[fj], acc[fi][fj], 0, 0, 0);
    }
  }
  #undef ISSUE
  __syncthreads();   // all reads done before epilogue overwrites SMEM

  #pragma unroll
  for (int fi = 0; fi < 2; fi++)
    #pragma unroll
    for (int fj = 0; fj < 2; fj++)
      #pragma unroll
      for (int e = 0; e < 4; e++){
        int r = wr*32 + fi*16 + (lane >> 4)*4 + e;
        int c = wc*32 + fj*16 + lrow;
        fsm[r*128 + c] = acc[fi][fj][e];
      }
  __syncthreads();

  #pragma unroll
  for (int i = 0; i < 8; i++){
    int row = wave*8 + i;
    int gi = i0 + row;
    float qi = q[gi];
    size_t rowbase = (size_t)gi*NPTS - ((size_t)gi*(gi+1))/2 - (size_t)gi - 1;
    float2 vv = *(float2*)&fsm[row*128 + lane*2];
    int gj0 = j0 + lane*2, gj1 = gj0 + 1;
    if (gi < gj0) out[rowbase + gj0] = sqrtf(fmaxf(qi + q[gj0] - 2.0f*vv.x, 1e-12f));
    if (gi < gj1) out[rowbase + gj1] = sqrtf(fmaxf(qi + q[gj1] - 2.0f*vv.y, 1e-12f));
  }
}

extern "C" void kernel_launch(void* const* d_in, const int* in_sizes, int n_in,
                              void* d_out, int out_size, void* d_ws, size_t ws_size,
                              hipStream_t stream) {
  (void)in_sizes; (void)n_in; (void)out_size; (void)ws_size;
  const float* x0 = (const float*)d_in[0];
  const float* x1 = (const float*)d_in[1];
  float* out = (float*)d_out;

  char* w = (char*)d_ws;
  float* mu     = (float*)w; w += 4096;
  float* q      = (float*)w; w += NPTS*4;
  unsigned short* Vh = (unsigned short*)w; w += (size_t)NDIM*NDIM*2;
  unsigned short* Vl = (unsigned short*)w; w += (size_t)NDIM*NDIM*2;
  unsigned short* E0 = (unsigned short*)w; w += (size_t)NDIM*NDIM*2;
  unsigned short* E1 = (unsigned short*)w; w += (size_t)NDIM*NDIM*2;
  unsigned short* P0 = (unsigned short*)w; w += (size_t)NDIM*NDIM*2;
  unsigned short* P1 = (unsigned short*)w; w += (size_t)NDIM*NDIM*2;
  unsigned short* Xch = (unsigned short*)w; w += (size_t)NDIM*NPTS*2;
  unsigned short* Xcl = (unsigned short*)w; w += (size_t)NDIM*NPTS*2;
  unsigned short* Xth = (unsigned short*)w; w += (size_t)NDIM*NPTS*2;
  unsigned short* Xtl = (unsigned short*)w; w += (size_t)NDIM*NPTS*2;
  char* uspan = w;
  unsigned short* Rh  = (unsigned short*)uspan;
  unsigned short* Rl  = Rh + (size_t)NDIM*NDIM;
  unsigned short* VIh = Rl + (size_t)NDIM*NDIM;
  unsigned short* VIl = VIh + (size_t)NDIM*NDIM;
  unsigned short* Zt  = VIl + (size_t)NDIM*NDIM;
  float* Vp = (float*)uspan;  // VZ x 1MB partials, dead after k_finVinit

  k_rowmean<<<dim3(512), dim3(256), 0, stream>>>(x0, x1, mu);
  k_prep<<<dim3(64,8), dim3(256), 0, stream>>>(x0, x1, mu, Xch, Xcl, Xth, Xtl);
  k_V2<<<dim3(10, VZ), dim3(1024), 0, stream>>>(Xch, Xcl, Vp);
  k_finVinit<<<dim3(512), dim3(64), 0, stream>>>(Vp, Vh, Vl, E0, P0);

  unsigned short *Ec = E0, *En = E1, *Pc = P0, *Pn = P1;
  for (int it = 0; it < 3; ++it){
    k_ns2<<<dim3(128), dim3(256), 0, stream>>>(Ec, Pc, En, Pn);
    unsigned short* tmp;
    tmp = Ec; Ec = En; En = tmp;
    tmp = Pc; Pc = Pn; Pn = tmp;
  }
  k_resid2<<<dim3(64), dim3(256), 0, stream>>>(Vh, Vl, Pc, Rh, Rl);
  k_final2<<<dim3(64), dim3(256), 0, stream>>>(Pc, Rh, Rl, VIh, VIl);
  k_gemmZ2<<<dim3(32,8), dim3(1024), 0, stream>>>(Xth, Xtl, VIh, VIl, Zt);
  k_q<<<dim3(1024), dim3(256), 0, stream>>>(Xth, Zt, q);
  k_G<<<dim3(528), dim3(1024), 0, stream>>>(Xth, Zt, q, out);
}

// Round 17
// 108.414 us; speedup vs baseline: 1.6580x; 1.0459x over previous
//
#include <hip/hip_runtime.h>
#include <hip/hip_bf16.h>
#include <math.h>

#define NDIM 512
#define NPTS 4096
#define VZ 16

typedef __attribute__((ext_vector_type(4))) float f32x4;
typedef __attribute__((ext_vector_type(8))) short short8;

__device__ __forceinline__ const float* xrow(const float* x0, const float* x1, int r){
  return (r < 256) ? (x0 + (size_t)r * NPTS) : (x1 + (size_t)(r - 256) * NPTS);
}
__device__ __forceinline__ unsigned short f2bf(float f){
  __hip_bfloat16 h = __float2bfloat16(f);
  return *reinterpret_cast<unsigned short*>(&h);
}
__device__ __forceinline__ float bf2f(unsigned short u){
  return __uint_as_float(((unsigned int)u) << 16);
}
__device__ __forceinline__ void gload16(const void* g, void* l){
  __builtin_amdgcn_global_load_lds((const __attribute__((address_space(1))) void*)g,
                                   (__attribute__((address_space(3))) void*)l, 16, 0, 0);
}

// ---------------- row means of X (512 rows x 4096); also zeroes q ----------------
__global__ void k_rowmean(const float* __restrict__ x0, const float* __restrict__ x1,
                          float* __restrict__ mu, float* __restrict__ q){
  int r = blockIdx.x;
  if (threadIdx.x < 8) q[r*8 + threadIdx.x] = 0.f;   // 512 blocks x 8 = 4096
  const float4* row4 = (const float4*)xrow(x0, x1, r);
  float s = 0.f;
  for (int c = threadIdx.x; c < NPTS/4; c += 256){
    float4 v = row4[c];
    s += v.x + v.y + v.z + v.w;
  }
  __shared__ float red[256];
  red[threadIdx.x] = s; __syncthreads();
  for (int off = 128; off > 0; off >>= 1){
    if (threadIdx.x < off) red[threadIdx.x] += red[threadIdx.x + off];
    __syncthreads();
  }
  if (threadIdx.x == 0) mu[r] = red[0] * (1.0f / NPTS);
}

// ------- prep: centered X in bf16 hi/lo, both layouts -------
__global__ __launch_bounds__(256) void k_prep(const float* __restrict__ x0, const float* __restrict__ x1,
      const float* __restrict__ mu,
      unsigned short* __restrict__ Xch, unsigned short* __restrict__ Xcl,
      unsigned short* __restrict__ Xth, unsigned short* __restrict__ Xtl){
  __shared__ float tile[64][65];
  int i0 = blockIdx.x * 64, a0 = blockIdx.y * 64;
  int t = threadIdx.x;
  int r = t >> 2, cg = (t & 3) * 16;
  const float* row = xrow(x0, x1, a0 + r);
  float m = mu[a0 + r];
  unsigned short h16[16] __attribute__((aligned(16)));
  unsigned short l16[16] __attribute__((aligned(16)));
  #pragma unroll
  for (int e = 0; e < 16; e += 4){
    float4 v = *(const float4*)(row + i0 + cg + e);
    v.x -= m; v.y -= m; v.z -= m; v.w -= m;
    tile[r][cg+e] = v.x; tile[r][cg+e+1] = v.y; tile[r][cg+e+2] = v.z; tile[r][cg+e+3] = v.w;
    h16[e]   = f2bf(v.x); l16[e]   = f2bf(v.x - bf2f(h16[e]));
    h16[e+1] = f2bf(v.y); l16[e+1] = f2bf(v.y - bf2f(h16[e+1]));
    h16[e+2] = f2bf(v.z); l16[e+2] = f2bf(v.z - bf2f(h16[e+2]));
    h16[e+3] = f2bf(v.w); l16[e+3] = f2bf(v.w - bf2f(h16[e+3]));
  }
  unsigned short* dst = Xch + (size_t)(a0+r)*NPTS + i0 + cg;
  *(uint4*)dst = *(uint4*)&h16[0]; *(uint4*)(dst+8) = *(uint4*)&h16[8];
  dst = Xcl + (size_t)(a0+r)*NPTS + i0 + cg;
  *(uint4*)dst = *(uint4*)&l16[0]; *(uint4*)(dst+8) = *(uint4*)&l16[8];
  __syncthreads();
  unsigned short th[16] __attribute__((aligned(16)));
  unsigned short tl[16] __attribute__((aligned(16)));
  #pragma unroll
  for (int e = 0; e < 16; e++){
    float v = tile[cg+e][r];
    th[e] = f2bf(v); tl[e] = f2bf(v - bf2f(th[e]));
  }
  unsigned short* d2 = Xth + (size_t)(i0 + r)*NDIM + a0 + cg;
  *(uint4*)d2 = *(uint4*)&th[0]; *(uint4*)(d2+8) = *(uint4*)&th[8];
  d2 = Xtl + (size_t)(i0 + r)*NDIM + a0 + cg;
  *(uint4*)d2 = *(uint4*)&tl[0]; *(uint4*)(d2+8) = *(uint4*)&tl[8];
}

// ------- V2: 16-wave blocks, 128x128 tri-tiles x 16 K-slices, 3-buf DMA pipeline -------
__global__ __launch_bounds__(1024) void k_V2(const unsigned short* __restrict__ Xch,
        const unsigned short* __restrict__ Xcl, float* __restrict__ Vp){
  int b = blockIdx.x;                  // 0..9 upper-tri tile of 4x4
  int ti = 0, rem = b;
  while (rem >= 4 - ti){ rem -= 4 - ti; ti++; }
  int tj = ti + rem;
  int i0 = ti*128, j0 = tj*128;
  int z = blockIdx.y;                  // 0..15
  size_t kbase = (size_t)z * (NPTS/VZ);  // 256-wide K slice

  __shared__ __align__(16) unsigned short SM[3][4][128*32];
  int t = threadIdx.x, lane = t & 63, wave = t >> 6;
  int wr = wave >> 2, wc = wave & 3;
  f32x4 acc[2][2];
  #pragma unroll
  for (int a = 0; a < 2; a++)
    #pragma unroll
    for (int c = 0; c < 2; c++) acc[a][c] = (f32x4){0.f,0.f,0.f,0.f};

  int srow = lane >> 2;
  int sgk  = (lane & 3) ^ ((srow >> 1) & 3);
  int lrow = lane & 15, glog = lane >> 4;

  int sl0 = wave*2, sl1 = wave*2 + 1;
  int m0 = sl0 >> 3, g0 = sl0 & 7;
  int m1 = sl1 >> 3, g1 = sl1 & 7;
  const unsigned short* b0 = (m0 & 1) ? Xcl : Xch;
  const unsigned short* b1 = (m1 & 1) ? Xcl : Xch;
  int r0 = ((m0 < 2) ? i0 : j0) + g0*16 + srow;
  int r1 = ((m1 < 2) ? i0 : j0) + g1*16 + srow;
  const unsigned short* src0 = b0 + (size_t)r0*NPTS + kbase + sgk*8;
  const unsigned short* src1 = b1 + (size_t)r1*NPTS + kbase + sgk*8;

  #define VISSUE(batch) { int kb = (batch)*32; int bf = (batch)%3; \
    gload16(src0 + kb, &SM[bf][m0][g0*512]); \
    gload16(src1 + kb, &SM[bf][m1][g1*512]); }

  VISSUE(0); VISSUE(1);
  for (int kt = 0; kt < 8; kt++){
    int bf = kt % 3;
    if (kt + 2 < 8) VISSUE(kt + 2);
    if (kt < 6)       { asm volatile("s_waitcnt vmcnt(4)" ::: "memory"); }
    else if (kt == 6) { asm volatile("s_waitcnt vmcnt(2)" ::: "memory"); }
    else              { asm volatile("s_waitcnt vmcnt(0)" ::: "memory"); }
    __builtin_amdgcn_sched_barrier(0);
    __builtin_amdgcn_s_barrier();
    __builtin_amdgcn_sched_barrier(0);

    short8 ah[2], al[2], bh[2], bl[2];
    #pragma unroll
    for (int f = 0; f < 2; f++){
      int fra = wr*32 + f*16 + lrow;
      int offa = fra*32 + ((glog ^ ((fra>>1)&3))<<3);
      ah[f] = *(const short8*)&SM[bf][0][offa];
      al[f] = *(const short8*)&SM[bf][1][offa];
      int frb = wc*32 + f*16 + lrow;
      int offb = frb*32 + ((glog ^ ((frb>>1)&3))<<3);
      bh[f] = *(const short8*)&SM[bf][2][offb];
      bl[f] = *(const short8*)&SM[bf][3][offb];
    }
    #pragma unroll
    for (int fi = 0; fi < 2; fi++)
      #pragma unroll
      for (int fj = 0; fj < 2; fj++){
        acc[fi][fj] = __builtin_amdgcn_mfma_f32_16x16x32_bf16(ah[fi], bh[fj], acc[fi][fj], 0,0,0);
        acc[fi][fj] = __builtin_amdgcn_mfma_f32_16x16x32_bf16(ah[fi], bl[fj], acc[fi][fj], 0,0,0);
        acc[fi][fj] = __builtin_amdgcn_mfma_f32_16x16x32_bf16(al[fi], bh[fj], acc[fi][fj], 0,0,0);
      }
    __builtin_amdgcn_sched_barrier(0);
    __builtin_amdgcn_s_barrier();
  }
  #undef VISSUE

  float* dst = Vp + (size_t)z*NDIM*NDIM;
  #pragma unroll
  for (int fi = 0; fi < 2; fi++)
    #pragma unroll
    for (int fj = 0; fj < 2; fj++)
      #pragma unroll
      for (int e = 0; e < 4; e++){
        int gi = i0 + wr*32 + fi*16 + (lane>>4)*4 + e;
        int gj = j0 + wc*32 + fj*16 + lrow;
        dst[(size_t)gi*NDIM + gj] = acc[fi][fj][e];
        if (ti != tj) dst[(size_t)gj*NDIM + gi] = acc[fi][fj][e];
      }
}

// ------- finVinit: V=sum(Vp)/4095 (regs only); E0 = I - cV, P0 = cI -------
__global__ void k_finVinit(const float* __restrict__ Vp,
      unsigned short* __restrict__ E0, unsigned short* __restrict__ P0){
  const float c = 0.869565217f;
  int r = blockIdx.x, lane = threadIdx.x; // 64 threads
  const size_t S = (size_t)NDIM*NDIM;
  float a[8] = {0,0,0,0,0,0,0,0};
  #pragma unroll
  for (int z = 0; z < VZ; z++){
    const float* p = Vp + z*S + (size_t)r*NDIM + lane*8;
    float4 u = *(const float4*)p;
    float4 v = *(const float4*)(p+4);
    a[0]+=u.x; a[1]+=u.y; a[2]+=u.z; a[3]+=u.w;
    a[4]+=v.x; a[5]+=v.y; a[6]+=v.z; a[7]+=v.w;
  }
  const float s = 1.0f/4095.0f;
  unsigned short e8[8] __attribute__((aligned(16))), p8[8] __attribute__((aligned(16)));
  #pragma unroll
  for (int e = 0; e < 8; e++){
    float v = a[e]*s;
    int col = lane*8 + e;
    e8[e] = f2bf(((col==r)?1.f:0.f) - c*v);
    p8[e] = f2bf((col==r)?c:0.f);
  }
  size_t o = (size_t)r*NDIM + lane*8;
  *(uint4*)&E0[o] = *(uint4*)e8; *(uint4*)&P0[o] = *(uint4*)p8;
}

// ------- ns2: DMA-pipelined fused NS iter. blocks 0-63: En=E*E ; 64-127: Pn=P+P*E -------
__global__ __launch_bounds__(256) void k_ns2(const unsigned short* __restrict__ E,
      const unsigned short* __restrict__ P,
      unsigned short* __restrict__ En, unsigned short* __restrict__ Pn){
  int b = blockIdx.x;
  int half = b >> 6, tile = b & 63;
  int i0 = (tile>>3)*64, j0 = (tile&7)*64;
  const unsigned short* Asrc = half ? P : E;
  __shared__ __align__(16) unsigned short SM[4][2][64*64];
  int t = threadIdx.x, lane = t & 63, wave = t >> 6;
  int wr = wave >> 1, wc = wave & 1;
  int lrow = lane & 15, glog = lane >> 4;
  f32x4 acc[2][2];
  #pragma unroll
  for (int a = 0; a < 2; a++)
    #pragma unroll
    for (int c = 0; c < 2; c++) acc[a][c] = (f32x4){0.f,0.f,0.f,0.f};

  int srow = lane >> 3;                 // 0..7 row within group
  int sg8  = (lane & 7) ^ (srow & 7);   // pre-swizzled source granule (16B)
  int gA0 = wave*2, gA1 = wave*2 + 1;
  const unsigned short* srcA0 = Asrc + (size_t)(i0 + gA0*8 + srow)*NDIM + sg8*8;
  const unsigned short* srcA1 = Asrc + (size_t)(i0 + gA1*8 + srow)*NDIM + sg8*8;
  const unsigned short* srcB0 = E + (size_t)(j0 + gA0*8 + srow)*NDIM + sg8*8;
  const unsigned short* srcB1 = E + (size_t)(j0 + gA1*8 + srow)*NDIM + sg8*8;

  #define NISSUE(batch) { int kb = (batch)*64; int bf = (batch)&3; \
    gload16(srcA0 + kb, &SM[bf][0][gA0*512]); \
    gload16(srcA1 + kb, &SM[bf][0][gA1*512]); \
    gload16(srcB0 + kb, &SM[bf][1][gA0*512]); \
    gload16(srcB1 + kb, &SM[bf][1][gA1*512]); }

  NISSUE(0); NISSUE(1);
  for (int kt = 0; kt < 8; kt++){
    int bf = kt & 3;
    if (kt + 2 < 8) NISSUE(kt + 2);
    if (kt <= 5)      { asm volatile("s_waitcnt vmcnt(8)" ::: "memory"); }
    else if (kt == 6) { asm volatile("s_waitcnt vmcnt(4)" ::: "memory"); }
    else              { asm volatile("s_waitcnt vmcnt(0)" ::: "memory"); }
    __builtin_amdgcn_sched_barrier(0);
    __builtin_amdgcn_s_barrier();
    __builtin_amdgcn_sched_barrier(0);

    #pragma unroll
    for (int c = 0; c < 2; c++){
      short8 fa[2], fb[2];
      #pragma unroll
      for (int f = 0; f < 2; f++){
        int fra = wr*32 + f*16 + lrow;
        fa[f] = *(const short8*)&SM[bf][0][fra*64 + (((c*4+glog) ^ (fra&7))<<3)];
        int frb = wc*32 + f*16 + lrow;
        fb[f] = *(const short8*)&SM[bf][1][frb*64 + (((c*4+glog) ^ (frb&7))<<3)];
      }
      #pragma unroll
      for (int fi = 0; fi < 2; fi++)
        #pragma unroll
        for (int fj = 0; fj < 2; fj++)
          acc[fi][fj] = __builtin_amdgcn_mfma_f32_16x16x32_bf16(fa[fi], fb[fj], acc[fi][fj], 0,0,0);
    }
  }
  #undef NISSUE

  #pragma unroll
  for (int fi = 0; fi < 2; fi++)
    #pragma unroll
    for (int fj = 0; fj < 2; fj++)
      #pragma unroll
      for (int e = 0; e < 4; e++){
        int gi = i0 + wr*32 + fi*16 + (lane>>4)*4 + e;
        int gj = j0 + wc*32 + fj*16 + lrow;
        size_t o = (size_t)gi*NDIM + gj;
        if (half) Pn[o] = f2bf(bf2f(P[o]) + acc[fi][fj][e]);
        else      En[o] = f2bf(acc[fi][fj][e]);
      }
}

// ------- final2: VI = P + P*E3  (R == E3 identity; E3,P symmetric) -> VIh/VIl -------
__global__ __launch_bounds__(256) void k_final2(const unsigned short* __restrict__ P,
      const unsigned short* __restrict__ E3,
      unsigned short* __restrict__ VIh, unsigned short* __restrict__ VIl){
  int b = blockIdx.x;
  int i0 = (b>>3)*64, j0 = (b&7)*64;
  __shared__ __align__(16) unsigned short SM[4][2][64*32];
  int t = threadIdx.x, lane = t & 63, wave = t >> 6;
  int wr = wave >> 1, wc = wave & 1;
  int lrow = lane & 15, glog = lane >> 4;
  f32x4 acc[2][2];
  #pragma unroll
  for (int a = 0; a < 2; a++)
    #pragma unroll
    for (int c = 0; c < 2; c++) acc[a][c] = (f32x4){0.f,0.f,0.f,0.f};

  int srow = lane >> 2;
  int sg4  = (lane & 3) ^ ((srow >> 1) & 3);
  const unsigned short* s0 = P  + (size_t)(i0 + wave*16 + srow)*NDIM + sg4*8;
  const unsigned short* s1 = E3 + (size_t)(j0 + wave*16 + srow)*NDIM + sg4*8;

  #define FISSUE(batch) { int kb = (batch)*32; int bf = (batch)&3; \
    gload16(s0 + kb, &SM[bf][0][wave*512]); \
    gload16(s1 + kb, &SM[bf][1][wave*512]); }

  FISSUE(0); FISSUE(1);
  for (int kt = 0; kt < 16; kt++){
    int bf = kt & 3;
    if (kt + 2 < 16) FISSUE(kt + 2);
    if (kt <= 13)      { asm volatile("s_waitcnt vmcnt(4)" ::: "memory"); }
    else if (kt == 14) { asm volatile("s_waitcnt vmcnt(2)" ::: "memory"); }
    else               { asm volatile("s_waitcnt vmcnt(0)" ::: "memory"); }
    __builtin_amdgcn_sched_barrier(0);
    __builtin_amdgcn_s_barrier();
    __builtin_amdgcn_sched_barrier(0);

    short8 fa[2], fb[2];
    #pragma unroll
    for (int f = 0; f < 2; f++){
      int fra = wr*32 + f*16 + lrow;
      fa[f] = *(const short8*)&SM[bf][0][fra*32 + ((glog ^ ((fra>>1)&3))<<3)];
      int frb = wc*32 + f*16 + lrow;
      fb[f] = *(const short8*)&SM[bf][1][frb*32 + ((glog ^ ((frb>>1)&3))<<3)];
    }
    #pragma unroll
    for (int fi = 0; fi < 2; fi++)
      #pragma unroll
      for (int fj = 0; fj < 2; fj++)
        acc[fi][fj] = __builtin_amdgcn_mfma_f32_16x16x32_bf16(fa[fi], fb[fj], acc[fi][fj], 0,0,0);
  }
  #undef FISSUE

  #pragma unroll
  for (int fi = 0; fi < 2; fi++)
    #pragma unroll
    for (int fj = 0; fj < 2; fj++)
      #pragma unroll
      for (int e = 0; e < 4; e++){
        int gi = i0 + wr*32 + fi*16 + (lane>>4)*4 + e;
        int gj = j0 + wc*32 + fj*16 + lrow;
        size_t o = (size_t)gi*NDIM + gj;
        float vi = bf2f(P[o]) + acc[fi][fj][e];
        unsigned short hi = f2bf(vi);
        VIh[o] = hi; VIl[o] = f2bf(vi - bf2f(hi));
      }
}

// ------- Z2: 16-wave, tile 128(i) x 64(a), 3-buf DMA pipeline; fused q partials -------
__global__ __launch_bounds__(1024) void k_gemmZ2(const unsigned short* __restrict__ Xth,
    const unsigned short* __restrict__ Xtl, const unsigned short* __restrict__ VIh,
    const unsigned short* __restrict__ VIl, unsigned short* __restrict__ Zt,
    float* __restrict__ q){
  int i0 = blockIdx.x * 128, j0 = blockIdx.y * 64;
  __shared__ __align__(16) unsigned short SMA[3][2][128*32];
  __shared__ __align__(16) unsigned short SMB[3][2][64*32];
  int t = threadIdx.x, lane = t & 63, wave = t >> 6;
  int wr = wave >> 2, wc = wave & 3;
  f32x4 acc[2];
  acc[0] = (f32x4){0.f,0.f,0.f,0.f}; acc[1] = (f32x4){0.f,0.f,0.f,0.f};

  int srow = lane >> 2;
  int sgk  = (lane & 3) ^ ((srow >> 1) & 3);
  int lrow = lane & 15, glog = lane >> 4;

  const unsigned short* srcA0 = Xth + (size_t)(i0 + (wave&7)*16 + srow)*NDIM + sgk*8;
  const unsigned short* srcA1 = Xtl + (size_t)(i0 + (wave&7)*16 + srow)*NDIM + sgk*8;
  int gB = wave & 3;
  const unsigned short* srcB = ((wave < 12) ? VIh : VIl) + (size_t)(j0 + gB*16 + srow)*NDIM + sgk*8;
  int mB = (wave < 12) ? 0 : 1;
  int gA = wave & 7;

  #define ZISSUE(batch) { int kb = (batch)*32; int bf = (batch)%3; \
    if (wave < 8){ gload16(srcA0 + kb, &SMA[bf][0][gA*512]); \
                   gload16(srcA1 + kb, &SMA[bf][1][gA*512]); } \
    else         { gload16(srcB  + kb, &SMB[bf][mB][gB*512]); } }

  ZISSUE(0); ZISSUE(1);
  for (int kt = 0; kt < 16; kt++){
    int bf = kt % 3;
    if (kt + 2 < 16) ZISSUE(kt + 2);
    if (wave < 8){
      if (kt < 14)       { asm volatile("s_waitcnt vmcnt(4)" ::: "memory"); }
      else if (kt == 14) { asm volatile("s_waitcnt vmcnt(2)" ::: "memory"); }
      else               { asm volatile("s_waitcnt vmcnt(0)" ::: "memory"); }
    } else {
      if (kt < 14)       { asm volatile("s_waitcnt vmcnt(2)" ::: "memory"); }
      else if (kt == 14) { asm volatile("s_waitcnt vmcnt(1)" ::: "memory"); }
      else               { asm volatile("s_waitcnt vmcnt(0)" ::: "memory"); }
    }
    __builtin_amdgcn_sched_barrier(0);
    __builtin_amdgcn_s_barrier();
    __builtin_amdgcn_sched_barrier(0);

    short8 ah[2], al[2], bh, bl;
    #pragma unroll
    for (int f = 0; f < 2; f++){
      int fra = wr*32 + f*16 + lrow;
      int offa = fra*32 + ((glog ^ ((fra>>1)&3))<<3);
      ah[f] = *(const short8*)&SMA[bf][0][offa];
      al[f] = *(const short8*)&SMA[bf][1][offa];
    }
    {
      int frb = wc*16 + lrow;
      int offb = frb*32 + ((glog ^ ((frb>>1)&3))<<3);
      bh = *(const short8*)&SMB[bf][0][offb];
      bl = *(const short8*)&SMB[bf][1][offb];
    }
    #pragma unroll
    for (int fi = 0; fi < 2; fi++){
      acc[fi] = __builtin_amdgcn_mfma_f32_16x16x32_bf16(ah[fi], bh, acc[fi], 0,0,0);
      acc[fi] = __builtin_amdgcn_mfma_f32_16x16x32_bf16(ah[fi], bl, acc[fi], 0,0,0);
      acc[fi] = __builtin_amdgcn_mfma_f32_16x16x32_bf16(al[fi], bh, acc[fi], 0,0,0);
    }
    __builtin_amdgcn_sched_barrier(0);
    __builtin_amdgcn_s_barrier();
  }
  #undef ZISSUE

  // epilogue: write Zt and accumulate q[gi] partial dot over this block's 64 columns
  #pragma unroll
  for (int fi = 0; fi < 2; fi++)
    #pragma unroll
    for (int e = 0; e < 4; e++){
      int gi = i0 + wr*32 + fi*16 + (lane>>4)*4 + e;
      int gj = j0 + wc*16 + lrow;
      size_t o = (size_t)gi*NDIM + gj;
      unsigned short zb = f2bf(acc[fi][e]);
      Zt[o] = zb;
      float p = bf2f(zb) * bf2f(Xth[o]);
      p += __shfl_xor(p, 1, 64);
      p += __shfl_xor(p, 2, 64);
      p += __shfl_xor(p, 4, 64);
      p += __shfl_xor(p, 8, 64);
      if (lrow == 0) atomicAdd(&q[gi], p);
    }
}

// ------- G: 16-wave, BK=32, 4-buffer, double-step windows, one barrier per window -------
__global__ __launch_bounds__(1024) void k_G(const unsigned short* __restrict__ Xt,
        const unsigned short* __restrict__ Zt, const float* __restrict__ q,
        float* __restrict__ out){
  const int NT = NPTS/128; // 32
  int b = (int)blockIdx.x;
  b = (b & 7) * 66 + (b >> 3);     // XCD-bijective chunking (528 = 8*66)
  int ti = 0, rem = b;
  while (rem >= NT - ti){ rem -= NT - ti; ti++; }
  int tj = ti + rem;
  int i0 = ti*128, j0 = tj*128;

  __shared__ __align__(16) unsigned short SMEM[2*4*128*32];
  unsigned short (*At)[128*32] = (unsigned short (*)[128*32])SMEM;
  unsigned short (*Bt)[128*32] = (unsigned short (*)[128*32])(SMEM + 4*128*32);
  float* fsm = (float*)SMEM;

  int t = threadIdx.x, lane = t & 63, wave = t >> 6;   // wave 0..15
  int wr = wave >> 2, wc = wave & 3;                   // 4x4 wave grid, 32x32 sub-tile each
  f32x4 acc[2][2];
  #pragma unroll
  for (int a = 0; a < 2; a++)
    #pragma unroll
    for (int c = 0; c < 2; c++) acc[a][c] = (f32x4){0.f,0.f,0.f,0.f};

  int srow = lane >> 2;
  int sgk  = (lane & 3) ^ ((srow >> 1) & 3);
  int lrow = lane & 15;
  int glog = lane >> 4;

  int sg = wave & 7;
  int srcrow = sg*16 + srow;
  const unsigned short* src = (wave < 8)
      ? (Xt + (size_t)(i0 + srcrow)*NDIM + sgk*8)
      : (Zt + (size_t)(j0 + srcrow)*NDIM + sgk*8);
  unsigned short (*dstb)[128*32] = (wave < 8) ? At : Bt;

  #define ISSUE(batch) { int kb = (batch)*32; int bf = (batch)&3; \
    gload16(src + kb, &dstb[bf][sg*512]); }

  ISSUE(0); ISSUE(1);

  #pragma unroll
  for (int kt = 0; kt < 16; kt += 2){
    asm volatile("s_waitcnt vmcnt(0)" ::: "memory");
    __builtin_amdgcn_sched_barrier(0);
    __builtin_amdgcn_s_barrier();
    __builtin_amdgcn_sched_barrier(0);
    if (kt + 2 < 16){ ISSUE(kt + 2); ISSUE(kt + 3); }

    #pragma unroll
    for (int s2 = 0; s2 < 2; s2++){
      int cur = (kt + s2) & 3;
      short8 af[2], bfr[2];
      #pragma unroll
      for (int f = 0; f < 2; f++){
        int fra = wr*32 + f*16 + lrow;
        int frb = wc*32 + f*16 + lrow;
        af[f]  = *(const short8*)&At[cur][fra*32 + ((glog ^ ((fra>>1)&3))<<3)];
        bfr[f] = *(const short8*)&Bt[cur][frb*32 + ((glog ^ ((frb>>1)&3))<<3)];
      }
      #pragma unroll
      for (int fi = 0; fi < 2; fi++)
        #pragma unroll
        for (int fj = 0; fj < 2; fj++)
          acc[fi][fj] = __builtin_amdgcn_mfma_f32_16x16x32_bf16(af[fi], bfr[fj], acc[fi][fj], 0, 0, 0);
    }
  }
  #undef ISSUE
  __syncthreads();   // all reads done before epilogue overwrites SMEM

  #pragma unroll
  for (int fi = 0; fi < 2; fi++)
    #pragma unroll
    for (int fj = 0; fj < 2; fj++)
      #pragma unroll
      for (int e = 0; e < 4; e++){
        int r = wr*32 + fi*16 + (lane >> 4)*4 + e;
        int c = wc*32 + fj*16 + lrow;
        fsm[r*128 + c] = acc[fi][fj][e];
      }
  __syncthreads();

  #pragma unroll
  for (int i = 0; i < 8; i++){
    int row = wave*8 + i;
    int gi = i0 + row;
    float qi = q[gi];
    size_t rowbase = (size_t)gi*NPTS - ((size_t)gi*(gi+1))/2 - (size_t)gi - 1;
    float2 vv = *(float2*)&fsm[row*128 + lane*2];
    int gj0 = j0 + lane*2, gj1 = gj0 + 1;
    if (gi < gj0) out[rowbase + gj0] = sqrtf(fmaxf(qi + q[gj0] - 2.0f*vv.x, 1e-12f));
    if (gi < gj1) out[rowbase + gj1] = sqrtf(fmaxf(qi + q[gj1] - 2.0f*vv.y, 1e-12f));
  }
}

extern "C" void kernel_launch(void* const* d_in, const int* in_sizes, int n_in,
                              void* d_out, int out_size, void* d_ws, size_t ws_size,
                              hipStream_t stream) {
  (void)in_sizes; (void)n_in; (void)out_size; (void)ws_size;
  const float* x0 = (const float*)d_in[0];
  const float* x1 = (const float*)d_in[1];
  float* out = (float*)d_out;

  char* w = (char*)d_ws;
  float* mu     = (float*)w; w += 4096;
  float* q      = (float*)w; w += NPTS*4;
  unsigned short* E0 = (unsigned short*)w; w += (size_t)NDIM*NDIM*2;
  unsigned short* E1 = (unsigned short*)w; w += (size_t)NDIM*NDIM*2;
  unsigned short* P0 = (unsigned short*)w; w += (size_t)NDIM*NDIM*2;
  unsigned short* P1 = (unsigned short*)w; w += (size_t)NDIM*NDIM*2;
  unsigned short* Xch = (unsigned short*)w; w += (size_t)NDIM*NPTS*2;
  unsigned short* Xcl = (unsigned short*)w; w += (size_t)NDIM*NPTS*2;
  unsigned short* Xth = (unsigned short*)w; w += (size_t)NDIM*NPTS*2;
  unsigned short* Xtl = (unsigned short*)w; w += (size_t)NDIM*NPTS*2;
  char* uspan = w;
  unsigned short* VIh = (unsigned short*)uspan;
  unsigned short* VIl = VIh + (size_t)NDIM*NDIM;
  unsigned short* Zt  = VIl + (size_t)NDIM*NDIM;
  float* Vp = (float*)uspan;  // VZ x 1MB partials, dead after k_finVinit

  k_rowmean<<<dim3(512), dim3(256), 0, stream>>>(x0, x1, mu, q);
  k_prep<<<dim3(64,8), dim3(256), 0, stream>>>(x0, x1, mu, Xch, Xcl, Xth, Xtl);
  k_V2<<<dim3(10, VZ), dim3(1024), 0, stream>>>(Xch, Xcl, Vp);
  k_finVinit<<<dim3(512), dim3(64), 0, stream>>>(Vp, E0, P0);

  unsigned short *Ec = E0, *En = E1, *Pc = P0, *Pn = P1;
  for (int it = 0; it < 3; ++it){
    k_ns2<<<dim3(128), dim3(256), 0, stream>>>(Ec, Pc, En, Pn);
    unsigned short* tmp;
    tmp = Ec; Ec = En; En = tmp;
    tmp = Pc; Pc = Pn; Pn = tmp;
  }
  // VI = P3 + P3*E3  (exact identity: I - V*P3 == E3; both symmetric)
  k_final2<<<dim3(64), dim3(256), 0, stream>>>(Pc, Ec, VIh, VIl);
  k_gemmZ2<<<dim3(32,8), dim3(1024), 0, stream>>>(Xth, Xtl, VIh, VIl, Zt, q);
  k_G<<<dim3(528), dim3(1024), 0, stream>>>(Xth, Zt, q, out);
}

// Round 18
// 103.584 us; speedup vs baseline: 1.7353x; 1.0466x over previous
//
#include <hip/hip_runtime.h>
#include <hip/hip_bf16.h>
#include <math.h>

#define NDIM 512
#define NPTS 4096
#define VZ 16

typedef __attribute__((ext_vector_type(4))) float f32x4;
typedef __attribute__((ext_vector_type(8))) short short8;

__device__ __forceinline__ const float* xrow(const float* x0, const float* x1, int r){
  return (r < 256) ? (x0 + (size_t)r * NPTS) : (x1 + (size_t)(r - 256) * NPTS);
}
__device__ __forceinline__ unsigned short f2bf(float f){
  __hip_bfloat16 h = __float2bfloat16(f);
  return *reinterpret_cast<unsigned short*>(&h);
}
__device__ __forceinline__ float bf2f(unsigned short u){
  return __uint_as_float(((unsigned int)u) << 16);
}
__device__ __forceinline__ void gload16(const void* g, void* l){
  __builtin_amdgcn_global_load_lds((const __attribute__((address_space(1))) void*)g,
                                   (__attribute__((address_space(3))) void*)l, 16, 0, 0);
}

// ---------------- row means of X (512 rows x 4096); also zeroes q ----------------
__global__ void k_rowmean(const float* __restrict__ x0, const float* __restrict__ x1,
                          float* __restrict__ mu, float* __restrict__ q){
  int r = blockIdx.x;
  if (threadIdx.x < 8) q[r*8 + threadIdx.x] = 0.f;   // 512 blocks x 8 = 4096
  const float4* row4 = (const float4*)xrow(x0, x1, r);
  float s = 0.f;
  for (int c = threadIdx.x; c < NPTS/4; c += 256){
    float4 v = row4[c];
    s += v.x + v.y + v.z + v.w;
  }
  __shared__ float red[256];
  red[threadIdx.x] = s; __syncthreads();
  for (int off = 128; off > 0; off >>= 1){
    if (threadIdx.x < off) red[threadIdx.x] += red[threadIdx.x + off];
    __syncthreads();
  }
  if (threadIdx.x == 0) mu[r] = red[0] * (1.0f / NPTS);
}

// ------- prep: centered X in bf16; row-major hi (Xch) + transposed hi/lo (Xth/Xtl) -------
__global__ __launch_bounds__(256) void k_prep(const float* __restrict__ x0, const float* __restrict__ x1,
      const float* __restrict__ mu,
      unsigned short* __restrict__ Xch,
      unsigned short* __restrict__ Xth, unsigned short* __restrict__ Xtl){
  __shared__ float tile[64][65];
  int i0 = blockIdx.x * 64, a0 = blockIdx.y * 64;
  int t = threadIdx.x;
  int r = t >> 2, cg = (t & 3) * 16;
  const float* row = xrow(x0, x1, a0 + r);
  float m = mu[a0 + r];
  unsigned short h16[16] __attribute__((aligned(16)));
  #pragma unroll
  for (int e = 0; e < 16; e += 4){
    float4 v = *(const float4*)(row + i0 + cg + e);
    v.x -= m; v.y -= m; v.z -= m; v.w -= m;
    tile[r][cg+e] = v.x; tile[r][cg+e+1] = v.y; tile[r][cg+e+2] = v.z; tile[r][cg+e+3] = v.w;
    h16[e]   = f2bf(v.x);
    h16[e+1] = f2bf(v.y);
    h16[e+2] = f2bf(v.z);
    h16[e+3] = f2bf(v.w);
  }
  unsigned short* dst = Xch + (size_t)(a0+r)*NPTS + i0 + cg;
  *(uint4*)dst = *(uint4*)&h16[0]; *(uint4*)(dst+8) = *(uint4*)&h16[8];
  __syncthreads();
  unsigned short th[16] __attribute__((aligned(16)));
  unsigned short tl[16] __attribute__((aligned(16)));
  #pragma unroll
  for (int e = 0; e < 16; e++){
    float v = tile[cg+e][r];
    th[e] = f2bf(v); tl[e] = f2bf(v - bf2f(th[e]));
  }
  unsigned short* d2 = Xth + (size_t)(i0 + r)*NDIM + a0 + cg;
  *(uint4*)d2 = *(uint4*)&th[0]; *(uint4*)(d2+8) = *(uint4*)&th[8];
  d2 = Xtl + (size_t)(i0 + r)*NDIM + a0 + cg;
  *(uint4*)d2 = *(uint4*)&tl[0]; *(uint4*)(d2+8) = *(uint4*)&tl[8];
}

// ------- V2: hi-only. 16-wave blocks, 128x128 tri-tiles x 16 K-slices, 3-buf DMA -------
__global__ __launch_bounds__(1024) void k_V2(const unsigned short* __restrict__ Xch,
        float* __restrict__ Vp){
  int b = blockIdx.x;                  // 0..9 upper-tri tile of 4x4
  int ti = 0, rem = b;
  while (rem >= 4 - ti){ rem -= 4 - ti; ti++; }
  int tj = ti + rem;
  int i0 = ti*128, j0 = tj*128;
  int z = blockIdx.y;                  // 0..15
  size_t kbase = (size_t)z * (NPTS/VZ);  // 256-wide K slice

  __shared__ __align__(16) unsigned short SM[3][2][128*32];  // {Ah,Bh} x 8KB, 3 bufs = 48KB
  int t = threadIdx.x, lane = t & 63, wave = t >> 6;
  int wr = wave >> 2, wc = wave & 3;
  f32x4 acc[2][2];
  #pragma unroll
  for (int a = 0; a < 2; a++)
    #pragma unroll
    for (int c = 0; c < 2; c++) acc[a][c] = (f32x4){0.f,0.f,0.f,0.f};

  int srow = lane >> 2;
  int sgk  = (lane & 3) ^ ((srow >> 1) & 3);
  int lrow = lane & 15, glog = lane >> 4;

  // 16 slots: m = wave>>3 (0=A,1=B), group g = wave&7; 1 load per wave per batch
  int m0 = wave >> 3, g0 = wave & 7;
  int r0 = ((m0 == 0) ? i0 : j0) + g0*16 + srow;
  const unsigned short* src0 = Xch + (size_t)r0*NPTS + kbase + sgk*8;

  #define VISSUE(batch) { int kb = (batch)*32; int bf = (batch)%3; \
    gload16(src0 + kb, &SM[bf][m0][g0*512]); }

  VISSUE(0); VISSUE(1);
  for (int kt = 0; kt < 8; kt++){
    int bf = kt % 3;
    if (kt + 2 < 8) VISSUE(kt + 2);
    if (kt < 6)       { asm volatile("s_waitcnt vmcnt(2)" ::: "memory"); }
    else if (kt == 6) { asm volatile("s_waitcnt vmcnt(1)" ::: "memory"); }
    else              { asm volatile("s_waitcnt vmcnt(0)" ::: "memory"); }
    __builtin_amdgcn_sched_barrier(0);
    __builtin_amdgcn_s_barrier();
    __builtin_amdgcn_sched_barrier(0);

    short8 ah[2], bh[2];
    #pragma unroll
    for (int f = 0; f < 2; f++){
      int fra = wr*32 + f*16 + lrow;
      ah[f] = *(const short8*)&SM[bf][0][fra*32 + ((glog ^ ((fra>>1)&3))<<3)];
      int frb = wc*32 + f*16 + lrow;
      bh[f] = *(const short8*)&SM[bf][1][frb*32 + ((glog ^ ((frb>>1)&3))<<3)];
    }
    #pragma unroll
    for (int fi = 0; fi < 2; fi++)
      #pragma unroll
      for (int fj = 0; fj < 2; fj++)
        acc[fi][fj] = __builtin_amdgcn_mfma_f32_16x16x32_bf16(ah[fi], bh[fj], acc[fi][fj], 0,0,0);
    __builtin_amdgcn_sched_barrier(0);
    __builtin_amdgcn_s_barrier();
  }
  #undef VISSUE

  float* dst = Vp + (size_t)z*NDIM*NDIM;
  #pragma unroll
  for (int fi = 0; fi < 2; fi++)
    #pragma unroll
    for (int fj = 0; fj < 2; fj++)
      #pragma unroll
      for (int e = 0; e < 4; e++){
        int gi = i0 + wr*32 + fi*16 + (lane>>4)*4 + e;
        int gj = j0 + wc*32 + fj*16 + lrow;
        dst[(size_t)gi*NDIM + gj] = acc[fi][fj][e];
        if (ti != tj) dst[(size_t)gj*NDIM + gi] = acc[fi][fj][e];
      }
}

// ------- finVinit: V=sum(Vp)/4095 (regs only); E0 = I - cV, P0 = cI -------
__global__ void k_finVinit(const float* __restrict__ Vp,
      unsigned short* __restrict__ E0, unsigned short* __restrict__ P0){
  const float c = 0.869565217f;
  int r = blockIdx.x, lane = threadIdx.x; // 64 threads
  const size_t S = (size_t)NDIM*NDIM;
  float a[8] = {0,0,0,0,0,0,0,0};
  #pragma unroll
  for (int z = 0; z < VZ; z++){
    const float* p = Vp + z*S + (size_t)r*NDIM + lane*8;
    float4 u = *(const float4*)p;
    float4 v = *(const float4*)(p+4);
    a[0]+=u.x; a[1]+=u.y; a[2]+=u.z; a[3]+=u.w;
    a[4]+=v.x; a[5]+=v.y; a[6]+=v.z; a[7]+=v.w;
  }
  const float s = 1.0f/4095.0f;
  unsigned short e8[8] __attribute__((aligned(16))), p8[8] __attribute__((aligned(16)));
  #pragma unroll
  for (int e = 0; e < 8; e++){
    float v = a[e]*s;
    int col = lane*8 + e;
    e8[e] = f2bf(((col==r)?1.f:0.f) - c*v);
    p8[e] = f2bf((col==r)?c:0.f);
  }
  size_t o = (size_t)r*NDIM + lane*8;
  *(uint4*)&E0[o] = *(uint4*)e8; *(uint4*)&P0[o] = *(uint4*)p8;
}

// ------- ns2: DMA-pipelined fused NS iter. blocks 0-63: En=E*E ; 64-127: Pn=P+P*E -------
__global__ __launch_bounds__(256) void k_ns2(const unsigned short* __restrict__ E,
      const unsigned short* __restrict__ P,
      unsigned short* __restrict__ En, unsigned short* __restrict__ Pn){
  int b = blockIdx.x;
  int half = b >> 6, tile = b & 63;
  int i0 = (tile>>3)*64, j0 = (tile&7)*64;
  const unsigned short* Asrc = half ? P : E;
  __shared__ __align__(16) unsigned short SM[4][2][64*64];
  int t = threadIdx.x, lane = t & 63, wave = t >> 6;
  int wr = wave >> 1, wc = wave & 1;
  int lrow = lane & 15, glog = lane >> 4;
  f32x4 acc[2][2];
  #pragma unroll
  for (int a = 0; a < 2; a++)
    #pragma unroll
    for (int c = 0; c < 2; c++) acc[a][c] = (f32x4){0.f,0.f,0.f,0.f};

  int srow = lane >> 3;                 // 0..7 row within group
  int sg8  = (lane & 7) ^ (srow & 7);   // pre-swizzled source granule (16B)
  int gA0 = wave*2, gA1 = wave*2 + 1;
  const unsigned short* srcA0 = Asrc + (size_t)(i0 + gA0*8 + srow)*NDIM + sg8*8;
  const unsigned short* srcA1 = Asrc + (size_t)(i0 + gA1*8 + srow)*NDIM + sg8*8;
  const unsigned short* srcB0 = E + (size_t)(j0 + gA0*8 + srow)*NDIM + sg8*8;
  const unsigned short* srcB1 = E + (size_t)(j0 + gA1*8 + srow)*NDIM + sg8*8;

  #define NISSUE(batch) { int kb = (batch)*64; int bf = (batch)&3; \
    gload16(srcA0 + kb, &SM[bf][0][gA0*512]); \
    gload16(srcA1 + kb, &SM[bf][0][gA1*512]); \
    gload16(srcB0 + kb, &SM[bf][1][gA0*512]); \
    gload16(srcB1 + kb, &SM[bf][1][gA1*512]); }

  NISSUE(0); NISSUE(1);
  for (int kt = 0; kt < 8; kt++){
    int bf = kt & 3;
    if (kt + 2 < 8) NISSUE(kt + 2);
    if (kt <= 5)      { asm volatile("s_waitcnt vmcnt(8)" ::: "memory"); }
    else if (kt == 6) { asm volatile("s_waitcnt vmcnt(4)" ::: "memory"); }
    else              { asm volatile("s_waitcnt vmcnt(0)" ::: "memory"); }
    __builtin_amdgcn_sched_barrier(0);
    __builtin_amdgcn_s_barrier();
    __builtin_amdgcn_sched_barrier(0);

    #pragma unroll
    for (int c = 0; c < 2; c++){
      short8 fa[2], fb[2];
      #pragma unroll
      for (int f = 0; f < 2; f++){
        int fra = wr*32 + f*16 + lrow;
        fa[f] = *(const short8*)&SM[bf][0][fra*64 + (((c*4+glog) ^ (fra&7))<<3)];
        int frb = wc*32 + f*16 + lrow;
        fb[f] = *(const short8*)&SM[bf][1][frb*64 + (((c*4+glog) ^ (frb&7))<<3)];
      }
      #pragma unroll
      for (int fi = 0; fi < 2; fi++)
        #pragma unroll
        for (int fj = 0; fj < 2; fj++)
          acc[fi][fj] = __builtin_amdgcn_mfma_f32_16x16x32_bf16(fa[fi], fb[fj], acc[fi][fj], 0,0,0);
    }
  }
  #undef NISSUE

  #pragma unroll
  for (int fi = 0; fi < 2; fi++)
    #pragma unroll
    for (int fj = 0; fj < 2; fj++)
      #pragma unroll
      for (int e = 0; e < 4; e++){
        int gi = i0 + wr*32 + fi*16 + (lane>>4)*4 + e;
        int gj = j0 + wc*32 + fj*16 + lrow;
        size_t o = (size_t)gi*NDIM + gj;
        if (half) Pn[o] = f2bf(bf2f(P[o]) + acc[fi][fj][e]);
        else      En[o] = f2bf(acc[fi][fj][e]);
      }
}

// ------- final2: VI = P + P*E3  (R == E3 identity; E3,P symmetric) -> VIh/VIl -------
__global__ __launch_bounds__(256) void k_final2(const unsigned short* __restrict__ P,
      const unsigned short* __restrict__ E3,
      unsigned short* __restrict__ VIh, unsigned short* __restrict__ VIl){
  int b = blockIdx.x;
  int i0 = (b>>3)*64, j0 = (b&7)*64;
  __shared__ __align__(16) unsigned short SM[4][2][64*32];
  int t = threadIdx.x, lane = t & 63, wave = t >> 6;
  int wr = wave >> 1, wc = wave & 1;
  int lrow = lane & 15, glog = lane >> 4;
  f32x4 acc[2][2];
  #pragma unroll
  for (int a = 0; a < 2; a++)
    #pragma unroll
    for (int c = 0; c < 2; c++) acc[a][c] = (f32x4){0.f,0.f,0.f,0.f};

  int srow = lane >> 2;
  int sg4  = (lane & 3) ^ ((srow >> 1) & 3);
  const unsigned short* s0 = P  + (size_t)(i0 + wave*16 + srow)*NDIM + sg4*8;
  const unsigned short* s1 = E3 + (size_t)(j0 + wave*16 + srow)*NDIM + sg4*8;

  #define FISSUE(batch) { int kb = (batch)*32; int bf = (batch)&3; \
    gload16(s0 + kb, &SM[bf][0][wave*512]); \
    gload16(s1 + kb, &SM[bf][1][wave*512]); }

  FISSUE(0); FISSUE(1);
  for (int kt = 0; kt < 16; kt++){
    int bf = kt & 3;
    if (kt + 2 < 16) FISSUE(kt + 2);
    if (kt <= 13)      { asm volatile("s_waitcnt vmcnt(4)" ::: "memory"); }
    else if (kt == 14) { asm volatile("s_waitcnt vmcnt(2)" ::: "memory"); }
    else               { asm volatile("s_waitcnt vmcnt(0)" ::: "memory"); }
    __builtin_amdgcn_sched_barrier(0);
    __builtin_amdgcn_s_barrier();
    __builtin_amdgcn_sched_barrier(0);

    short8 fa[2], fb[2];
    #pragma unroll
    for (int f = 0; f < 2; f++){
      int fra = wr*32 + f*16 + lrow;
      fa[f] = *(const short8*)&SM[bf][0][fra*32 + ((glog ^ ((fra>>1)&3))<<3)];
      int frb = wc*32 + f*16 + lrow;
      fb[f] = *(const short8*)&SM[bf][1][frb*32 + ((glog ^ ((frb>>1)&3))<<3)];
    }
    #pragma unroll
    for (int fi = 0; fi < 2; fi++)
      #pragma unroll
      for (int fj = 0; fj < 2; fj++)
        acc[fi][fj] = __builtin_amdgcn_mfma_f32_16x16x32_bf16(fa[fi], fb[fj], acc[fi][fj], 0,0,0);
  }
  #undef FISSUE

  #pragma unroll
  for (int fi = 0; fi < 2; fi++)
    #pragma unroll
    for (int fj = 0; fj < 2; fj++)
      #pragma unroll
      for (int e = 0; e < 4; e++){
        int gi = i0 + wr*32 + fi*16 + (lane>>4)*4 + e;
        int gj = j0 + wc*32 + fj*16 + lrow;
        size_t o = (size_t)gi*NDIM + gj;
        float vi = bf2f(P[o]) + acc[fi][fj][e];
        unsigned short hi = f2bf(vi);
        VIh[o] = hi; VIl[o] = f2bf(vi - bf2f(hi));
      }
}

// ------- Z2: 16-wave, tile 128(i) x 64(a), 3-buf DMA pipeline; fused q partials -------
__global__ __launch_bounds__(1024) void k_gemmZ2(const unsigned short* __restrict__ Xth,
    const unsigned short* __restrict__ Xtl, const unsigned short* __restrict__ VIh,
    const unsigned short* __restrict__ VIl, unsigned short* __restrict__ Zt,
    float* __restrict__ q){
  int i0 = blockIdx.x * 128, j0 = blockIdx.y * 64;
  __shared__ __align__(16) unsigned short SMA[3][2][128*32];
  __shared__ __align__(16) unsigned short SMB[3][2][64*32];
  int t = threadIdx.x, lane = t & 63, wave = t >> 6;
  int wr = wave >> 2, wc = wave & 3;
  f32x4 acc[2];
  acc[0] = (f32x4){0.f,0.f,0.f,0.f}; acc[1] = (f32x4){0.f,0.f,0.f,0.f};

  int srow = lane >> 2;
  int sgk  = (lane & 3) ^ ((srow >> 1) & 3);
  int lrow = lane & 15, glog = lane >> 4;

  const unsigned short* srcA0 = Xth + (size_t)(i0 + (wave&7)*16 + srow)*NDIM + sgk*8;
  const unsigned short* srcA1 = Xtl + (size_t)(i0 + (wave&7)*16 + srow)*NDIM + sgk*8;
  int gB = wave & 3;
  const unsigned short* srcB = ((wave < 12) ? VIh : VIl) + (size_t)(j0 + gB*16 + srow)*NDIM + sgk*8;
  int mB = (wave < 12) ? 0 : 1;
  int gA = wave & 7;

  #define ZISSUE(batch) { int kb = (batch)*32; int bf = (batch)%3; \
    if (wave < 8){ gload16(srcA0 + kb, &SMA[bf][0][gA*512]); \
                   gload16(srcA1 + kb, &SMA[bf][1][gA*512]); } \
    else         { gload16(srcB  + kb, &SMB[bf][mB][gB*512]); } }

  ZISSUE(0); ZISSUE(1);
  for (int kt = 0; kt < 16; kt++){
    int bf = kt % 3;
    if (kt + 2 < 16) ZISSUE(kt + 2);
    if (wave < 8){
      if (kt < 14)       { asm volatile("s_waitcnt vmcnt(4)" ::: "memory"); }
      else if (kt == 14) { asm volatile("s_waitcnt vmcnt(2)" ::: "memory"); }
      else               { asm volatile("s_waitcnt vmcnt(0)" ::: "memory"); }
    } else {
      if (kt < 14)       { asm volatile("s_waitcnt vmcnt(2)" ::: "memory"); }
      else if (kt == 14) { asm volatile("s_waitcnt vmcnt(1)" ::: "memory"); }
      else               { asm volatile("s_waitcnt vmcnt(0)" ::: "memory"); }
    }
    __builtin_amdgcn_sched_barrier(0);
    __builtin_amdgcn_s_barrier();
    __builtin_amdgcn_sched_barrier(0);

    short8 ah[2], al[2], bh, bl;
    #pragma unroll
    for (int f = 0; f < 2; f++){
      int fra = wr*32 + f*16 + lrow;
      int offa = fra*32 + ((glog ^ ((fra>>1)&3))<<3);
      ah[f] = *(const short8*)&SMA[bf][0][offa];
      al[f] = *(const short8*)&SMA[bf][1][offa];
    }
    {
      int frb = wc*16 + lrow;
      int offb = frb*32 + ((glog ^ ((frb>>1)&3))<<3);
      bh = *(const short8*)&SMB[bf][0][offb];
      bl = *(const short8*)&SMB[bf][1][offb];
    }
    #pragma unroll
    for (int fi = 0; fi < 2; fi++){
      acc[fi] = __builtin_amdgcn_mfma_f32_16x16x32_bf16(ah[fi], bh, acc[fi], 0,0,0);
      acc[fi] = __builtin_amdgcn_mfma_f32_16x16x32_bf16(ah[fi], bl, acc[fi], 0,0,0);
      acc[fi] = __builtin_amdgcn_mfma_f32_16x16x32_bf16(al[fi], bh, acc[fi], 0,0,0);
    }
    __builtin_amdgcn_sched_barrier(0);
    __builtin_amdgcn_s_barrier();
  }
  #undef ZISSUE

  // epilogue: write Zt and accumulate q[gi] partial dot over this block's 64 columns
  #pragma unroll
  for (int fi = 0; fi < 2; fi++)
    #pragma unroll
    for (int e = 0; e < 4; e++){
      int gi = i0 + wr*32 + fi*16 + (lane>>4)*4 + e;
      int gj = j0 + wc*16 + lrow;
      size_t o = (size_t)gi*NDIM + gj;
      unsigned short zb = f2bf(acc[fi][e]);
      Zt[o] = zb;
      float p = bf2f(zb) * bf2f(Xth[o]);
      p += __shfl_xor(p, 1, 64);
      p += __shfl_xor(p, 2, 64);
      p += __shfl_xor(p, 4, 64);
      p += __shfl_xor(p, 8, 64);
      if (lrow == 0) atomicAdd(&q[gi], p);
    }
}

// ------- G: 16-wave, BK=32, 4-buffer, double-step windows, one barrier per window -------
__global__ __launch_bounds__(1024) void k_G(const unsigned short* __restrict__ Xt,
        const unsigned short* __restrict__ Zt, const float* __restrict__ q,
        float* __restrict__ out){
  const int NT = NPTS/128; // 32
  int b = (int)blockIdx.x;
  b = (b & 7) * 66 + (b >> 3);     // XCD-bijective chunking (528 = 8*66)
  int ti = 0, rem = b;
  while (rem >= NT - ti){ rem -= NT - ti; ti++; }
  int tj = ti + rem;
  int i0 = ti*128, j0 = tj*128;

  __shared__ __align__(16) unsigned short SMEM[2*4*128*32];
  unsigned short (*At)[128*32] = (unsigned short (*)[128*32])SMEM;
  unsigned short (*Bt)[128*32] = (unsigned short (*)[128*32])(SMEM + 4*128*32);
  float* fsm = (float*)SMEM;

  int t = threadIdx.x, lane = t & 63, wave = t >> 6;   // wave 0..15
  int wr = wave >> 2, wc = wave & 3;                   // 4x4 wave grid, 32x32 sub-tile each
  f32x4 acc[2][2];
  #pragma unroll
  for (int a = 0; a < 2; a++)
    #pragma unroll
    for (int c = 0; c < 2; c++) acc[a][c] = (f32x4){0.f,0.f,0.f,0.f};

  int srow = lane >> 2;
  int sgk  = (lane & 3) ^ ((srow >> 1) & 3);
  int lrow = lane & 15;
  int glog = lane >> 4;

  int sg = wave & 7;
  int srcrow = sg*16 + srow;
  const unsigned short* src = (wave < 8)
      ? (Xt + (size_t)(i0 + srcrow)*NDIM + sgk*8)
      : (Zt + (size_t)(j0 + srcrow)*NDIM + sgk*8);
  unsigned short (*dstb)[128*32] = (wave < 8) ? At : Bt;

  #define ISSUE(batch) { int kb = (batch)*32; int bf = (batch)&3; \
    gload16(src + kb, &dstb[bf][sg*512]); }

  ISSUE(0); ISSUE(1);

  #pragma unroll
  for (int kt = 0; kt < 16; kt += 2){
    asm volatile("s_waitcnt vmcnt(0)" ::: "memory");
    __builtin_amdgcn_sched_barrier(0);
    __builtin_amdgcn_s_barrier();
    __builtin_amdgcn_sched_barrier(0);
    if (kt + 2 < 16){ ISSUE(kt + 2); ISSUE(kt + 3); }

    #pragma unroll
    for (int s2 = 0; s2 < 2; s2++){
      int cur = (kt + s2) & 3;
      short8 af[2], bfr[2];
      #pragma unroll
      for (int f = 0; f < 2; f++){
        int fra = wr*32 + f*16 + lrow;
        int frb = wc*32 + f*16 + lrow;
        af[f]  = *(const short8*)&At[cur][fra*32 + ((glog ^ ((fra>>1)&3))<<3)];
        bfr[f] = *(const short8*)&Bt[cur][frb*32 + ((glog ^ ((frb>>1)&3))<<3)];
      }
      #pragma unroll
      for (int fi = 0; fi < 2; fi++)
        #pragma unroll
        for (int fj = 0; fj < 2; fj++)
          acc[fi][fj] = __builtin_amdgcn_mfma_f32_16x16x32_bf16(af[fi], bfr[fj], acc[fi][fj], 0, 0, 0);
    }
  }
  #undef ISSUE
  __syncthreads();   // all reads done before epilogue overwrites SMEM

  #pragma unroll
  for (int fi = 0; fi < 2; fi++)
    #pragma unroll
    for (int fj = 0; fj < 2; fj++)
      #pragma unroll
      for (int e = 0; e < 4; e++){
        int r = wr*32 + fi*16 + (lane >> 4)*4 + e;
        int c = wc*32 + fj*16 + lrow;
        fsm[r*128 + c] = acc[fi][fj][e];
      }
  __syncthreads();

  #pragma unroll
  for (int i = 0; i < 8; i++){
    int row = wave*8 + i;
    int gi = i0 + row;
    float qi = q[gi];
    size_t rowbase = (size_t)gi*NPTS - ((size_t)gi*(gi+1))/2 - (size_t)gi - 1;
    float2 vv = *(float2*)&fsm[row*128 + lane*2];
    int gj0 = j0 + lane*2, gj1 = gj0 + 1;
    if (gi < gj0) out[rowbase + gj0] = sqrtf(fmaxf(qi + q[gj0] - 2.0f*vv.x, 1e-12f));
    if (gi < gj1) out[rowbase + gj1] = sqrtf(fmaxf(qi + q[gj1] - 2.0f*vv.y, 1e-12f));
  }
}

extern "C" void kernel_launch(void* const* d_in, const int* in_sizes, int n_in,
                              void* d_out, int out_size, void* d_ws, size_t ws_size,
                              hipStream_t stream) {
  (void)in_sizes; (void)n_in; (void)out_size; (void)ws_size;
  const float* x0 = (const float*)d_in[0];
  const float* x1 = (const float*)d_in[1];
  float* out = (float*)d_out;

  char* w = (char*)d_ws;
  float* mu     = (float*)w; w += 4096;
  float* q      = (float*)w; w += NPTS*4;
  unsigned short* E0 = (unsigned short*)w; w += (size_t)NDIM*NDIM*2;
  unsigned short* E1 = (unsigned short*)w; w += (size_t)NDIM*NDIM*2;
  unsigned short* P0 = (unsigned short*)w; w += (size_t)NDIM*NDIM*2;
  unsigned short* P1 = (unsigned short*)w; w += (size_t)NDIM*NDIM*2;
  unsigned short* Xch = (unsigned short*)w; w += (size_t)NDIM*NPTS*2;
  unsigned short* Xth = (unsigned short*)w; w += (size_t)NDIM*NPTS*2;
  unsigned short* Xtl = (unsigned short*)w; w += (size_t)NDIM*NPTS*2;
  char* uspan = w;
  unsigned short* VIh = (unsigned short*)uspan;
  unsigned short* VIl = VIh + (size_t)NDIM*NDIM;
  unsigned short* Zt  = VIl + (size_t)NDIM*NDIM;
  float* Vp = (float*)uspan;  // VZ x 1MB partials, dead after k_finVinit

  k_rowmean<<<dim3(512), dim3(256), 0, stream>>>(x0, x1, mu, q);
  k_prep<<<dim3(64,8), dim3(256), 0, stream>>>(x0, x1, mu, Xch, Xth, Xtl);
  k_V2<<<dim3(10, VZ), dim3(1024), 0, stream>>>(Xch, Vp);
  k_finVinit<<<dim3(512), dim3(64), 0, stream>>>(Vp, E0, P0);

  unsigned short *Ec = E0, *En = E1, *Pc = P0, *Pn = P1;
  for (int it = 0; it < 3; ++it){
    k_ns2<<<dim3(128), dim3(256), 0, stream>>>(Ec, Pc, En, Pn);
    unsigned short* tmp;
    tmp = Ec; Ec = En; En = tmp;
    tmp = Pc; Pc = Pn; Pn = tmp;
  }
  k_final2<<<dim3(64), dim3(256), 0, stream>>>(Pc, Ec, VIh, VIl);
  k_gemmZ2<<<dim3(32,8), dim3(1024), 0, stream>>>(Xth, Xtl, VIh, VIl, Zt, q);
  k_G<<<dim3(528), dim3(1024), 0, stream>>>(Xth, Zt, q, out);
}

// Round 19
// 103.113 us; speedup vs baseline: 1.7432x; 1.0046x over previous
//
#include <hip/hip_runtime.h>
#include <hip/hip_bf16.h>
#include <math.h>

#define NDIM 512
#define NPTS 4096
#define VZ 16

typedef __attribute__((ext_vector_type(4))) float f32x4;
typedef __attribute__((ext_vector_type(8))) short short8;

__device__ __forceinline__ const float* xrow(const float* x0, const float* x1, int r){
  return (r < 256) ? (x0 + (size_t)r * NPTS) : (x1 + (size_t)(r - 256) * NPTS);
}
__device__ __forceinline__ unsigned short f2bf(float f){
  __hip_bfloat16 h = __float2bfloat16(f);
  return *reinterpret_cast<unsigned short*>(&h);
}
__device__ __forceinline__ float bf2f(unsigned short u){
  return __uint_as_float(((unsigned int)u) << 16);
}
__device__ __forceinline__ void gload16(const void* g, void* l){
  __builtin_amdgcn_global_load_lds((const __attribute__((address_space(1))) void*)g,
                                   (__attribute__((address_space(3))) void*)l, 16, 0, 0);
}

// ---------------- row means of X (512 rows x 4096); also zeroes q ----------------
__global__ void k_rowmean(const float* __restrict__ x0, const float* __restrict__ x1,
                          float* __restrict__ mu, float* __restrict__ q){
  int r = blockIdx.x;
  if (threadIdx.x < 8) q[r*8 + threadIdx.x] = 0.f;   // 512 blocks x 8 = 4096
  const float4* row4 = (const float4*)xrow(x0, x1, r);
  float s = 0.f;
  for (int c = threadIdx.x; c < NPTS/4; c += 256){
    float4 v = row4[c];
    s += v.x + v.y + v.z + v.w;
  }
  __shared__ float red[256];
  red[threadIdx.x] = s; __syncthreads();
  for (int off = 128; off > 0; off >>= 1){
    if (threadIdx.x < off) red[threadIdx.x] += red[threadIdx.x + off];
    __syncthreads();
  }
  if (threadIdx.x == 0) mu[r] = red[0] * (1.0f / NPTS);
}

// ------- prep: centered X in bf16; row-major hi (Xch) + transposed hi/lo (Xth/Xtl) -------
__global__ __launch_bounds__(256) void k_prep(const float* __restrict__ x0, const float* __restrict__ x1,
      const float* __restrict__ mu,
      unsigned short* __restrict__ Xch,
      unsigned short* __restrict__ Xth, unsigned short* __restrict__ Xtl){
  __shared__ float tile[64][65];
  int i0 = blockIdx.x * 64, a0 = blockIdx.y * 64;
  int t = threadIdx.x;
  int r = t >> 2, cg = (t & 3) * 16;
  const float* row = xrow(x0, x1, a0 + r);
  float m = mu[a0 + r];
  unsigned short h16[16] __attribute__((aligned(16)));
  #pragma unroll
  for (int e = 0; e < 16; e += 4){
    float4 v = *(const float4*)(row + i0 + cg + e);
    v.x -= m; v.y -= m; v.z -= m; v.w -= m;
    tile[r][cg+e] = v.x; tile[r][cg+e+1] = v.y; tile[r][cg+e+2] = v.z; tile[r][cg+e+3] = v.w;
    h16[e]   = f2bf(v.x);
    h16[e+1] = f2bf(v.y);
    h16[e+2] = f2bf(v.z);
    h16[e+3] = f2bf(v.w);
  }
  unsigned short* dst = Xch + (size_t)(a0+r)*NPTS + i0 + cg;
  *(uint4*)dst = *(uint4*)&h16[0]; *(uint4*)(dst+8) = *(uint4*)&h16[8];
  __syncthreads();
  unsigned short th[16] __attribute__((aligned(16)));
  unsigned short tl[16] __attribute__((aligned(16)));
  #pragma unroll
  for (int e = 0; e < 16; e++){
    float v = tile[cg+e][r];
    th[e] = f2bf(v); tl[e] = f2bf(v - bf2f(th[e]));
  }
  unsigned short* d2 = Xth + (size_t)(i0 + r)*NDIM + a0 + cg;
  *(uint4*)d2 = *(uint4*)&th[0]; *(uint4*)(d2+8) = *(uint4*)&th[8];
  d2 = Xtl + (size_t)(i0 + r)*NDIM + a0 + cg;
  *(uint4*)d2 = *(uint4*)&tl[0]; *(uint4*)(d2+8) = *(uint4*)&tl[8];
}

// ------- V2: hi-only. 16-wave blocks, 128x128 tri-tiles x 16 K-slices, 3-buf DMA -------
__global__ __launch_bounds__(1024) void k_V2(const unsigned short* __restrict__ Xch,
        float* __restrict__ Vp){
  int b = blockIdx.x;                  // 0..9 upper-tri tile of 4x4
  int ti = 0, rem = b;
  while (rem >= 4 - ti){ rem -= 4 - ti; ti++; }
  int tj = ti + rem;
  int i0 = ti*128, j0 = tj*128;
  int z = blockIdx.y;                  // 0..15
  size_t kbase = (size_t)z * (NPTS/VZ);  // 256-wide K slice

  __shared__ __align__(16) unsigned short SM[3][2][128*32];  // {Ah,Bh} x 8KB, 3 bufs = 48KB
  int t = threadIdx.x, lane = t & 63, wave = t >> 6;
  int wr = wave >> 2, wc = wave & 3;
  f32x4 acc[2][2];
  #pragma unroll
  for (int a = 0; a < 2; a++)
    #pragma unroll
    for (int c = 0; c < 2; c++) acc[a][c] = (f32x4){0.f,0.f,0.f,0.f};

  int srow = lane >> 2;
  int sgk  = (lane & 3) ^ ((srow >> 1) & 3);
  int lrow = lane & 15, glog = lane >> 4;

  int m0 = wave >> 3, g0 = wave & 7;
  int r0 = ((m0 == 0) ? i0 : j0) + g0*16 + srow;
  const unsigned short* src0 = Xch + (size_t)r0*NPTS + kbase + sgk*8;

  #define VISSUE(batch) { int kb = (batch)*32; int bf = (batch)%3; \
    gload16(src0 + kb, &SM[bf][m0][g0*512]); }

  VISSUE(0); VISSUE(1);
  for (int kt = 0; kt < 8; kt++){
    int bf = kt % 3;
    if (kt + 2 < 8) VISSUE(kt + 2);
    if (kt < 6)       { asm volatile("s_waitcnt vmcnt(2)" ::: "memory"); }
    else if (kt == 6) { asm volatile("s_waitcnt vmcnt(1)" ::: "memory"); }
    else              { asm volatile("s_waitcnt vmcnt(0)" ::: "memory"); }
    __builtin_amdgcn_sched_barrier(0);
    __builtin_amdgcn_s_barrier();
    __builtin_amdgcn_sched_barrier(0);

    short8 ah[2], bh[2];
    #pragma unroll
    for (int f = 0; f < 2; f++){
      int fra = wr*32 + f*16 + lrow;
      ah[f] = *(const short8*)&SM[bf][0][fra*32 + ((glog ^ ((fra>>1)&3))<<3)];
      int frb = wc*32 + f*16 + lrow;
      bh[f] = *(const short8*)&SM[bf][1][frb*32 + ((glog ^ ((frb>>1)&3))<<3)];
    }
    __builtin_amdgcn_s_setprio(1);
    #pragma unroll
    for (int fi = 0; fi < 2; fi++)
      #pragma unroll
      for (int fj = 0; fj < 2; fj++)
        acc[fi][fj] = __builtin_amdgcn_mfma_f32_16x16x32_bf16(ah[fi], bh[fj], acc[fi][fj], 0,0,0);
    __builtin_amdgcn_s_setprio(0);
    __builtin_amdgcn_sched_barrier(0);
    __builtin_amdgcn_s_barrier();
  }
  #undef VISSUE

  float* dst = Vp + (size_t)z*NDIM*NDIM;
  #pragma unroll
  for (int fi = 0; fi < 2; fi++)
    #pragma unroll
    for (int fj = 0; fj < 2; fj++)
      #pragma unroll
      for (int e = 0; e < 4; e++){
        int gi = i0 + wr*32 + fi*16 + (lane>>4)*4 + e;
        int gj = j0 + wc*32 + fj*16 + lrow;
        dst[(size_t)gi*NDIM + gj] = acc[fi][fj][e];
        if (ti != tj) dst[(size_t)gj*NDIM + gi] = acc[fi][fj][e];
      }
}

// ------- finVinit: V=sum(Vp)/4095 (regs only); E0 = I - cV, P0 = cI -------
__global__ void k_finVinit(const float* __restrict__ Vp,
      unsigned short* __restrict__ E0, unsigned short* __restrict__ P0){
  const float c = 0.869565217f;
  int r = blockIdx.x, lane = threadIdx.x; // 64 threads
  const size_t S = (size_t)NDIM*NDIM;
  float a[8] = {0,0,0,0,0,0,0,0};
  #pragma unroll
  for (int z = 0; z < VZ; z++){
    const float* p = Vp + z*S + (size_t)r*NDIM + lane*8;
    float4 u = *(const float4*)p;
    float4 v = *(const float4*)(p+4);
    a[0]+=u.x; a[1]+=u.y; a[2]+=u.z; a[3]+=u.w;
    a[4]+=v.x; a[5]+=v.y; a[6]+=v.z; a[7]+=v.w;
  }
  const float s = 1.0f/4095.0f;
  unsigned short e8[8] __attribute__((aligned(16))), p8[8] __attribute__((aligned(16)));
  #pragma unroll
  for (int e = 0; e < 8; e++){
    float v = a[e]*s;
    int col = lane*8 + e;
    e8[e] = f2bf(((col==r)?1.f:0.f) - c*v);
    p8[e] = f2bf((col==r)?c:0.f);
  }
  size_t o = (size_t)r*NDIM + lane*8;
  *(uint4*)&E0[o] = *(uint4*)e8; *(uint4*)&P0[o] = *(uint4*)p8;
}

// ------- ns2: DMA-pipelined fused NS iter. blocks 0-63: En=E*E ; 64-127: Pn=P+P*E -------
__global__ __launch_bounds__(256) void k_ns2(const unsigned short* __restrict__ E,
      const unsigned short* __restrict__ P,
      unsigned short* __restrict__ En, unsigned short* __restrict__ Pn){
  int b = blockIdx.x;
  int half = b >> 6, tile = b & 63;
  int i0 = (tile>>3)*64, j0 = (tile&7)*64;
  const unsigned short* Asrc = half ? P : E;
  __shared__ __align__(16) unsigned short SM[4][2][64*64];
  int t = threadIdx.x, lane = t & 63, wave = t >> 6;
  int wr = wave >> 1, wc = wave & 1;
  int lrow = lane & 15, glog = lane >> 4;
  f32x4 acc[2][2];
  #pragma unroll
  for (int a = 0; a < 2; a++)
    #pragma unroll
    for (int c = 0; c < 2; c++) acc[a][c] = (f32x4){0.f,0.f,0.f,0.f};

  int srow = lane >> 3;                 // 0..7 row within group
  int sg8  = (lane & 7) ^ (srow & 7);   // pre-swizzled source granule (16B)
  int gA0 = wave*2, gA1 = wave*2 + 1;
  const unsigned short* srcA0 = Asrc + (size_t)(i0 + gA0*8 + srow)*NDIM + sg8*8;
  const unsigned short* srcA1 = Asrc + (size_t)(i0 + gA1*8 + srow)*NDIM + sg8*8;
  const unsigned short* srcB0 = E + (size_t)(j0 + gA0*8 + srow)*NDIM + sg8*8;
  const unsigned short* srcB1 = E + (size_t)(j0 + gA1*8 + srow)*NDIM + sg8*8;

  #define NISSUE(batch) { int kb = (batch)*64; int bf = (batch)&3; \
    gload16(srcA0 + kb, &SM[bf][0][gA0*512]); \
    gload16(srcA1 + kb, &SM[bf][0][gA1*512]); \
    gload16(srcB0 + kb, &SM[bf][1][gA0*512]); \
    gload16(srcB1 + kb, &SM[bf][1][gA1*512]); }

  NISSUE(0); NISSUE(1);
  for (int kt = 0; kt < 8; kt++){
    int bf = kt & 3;
    if (kt + 2 < 8) NISSUE(kt + 2);
    if (kt <= 5)      { asm volatile("s_waitcnt vmcnt(8)" ::: "memory"); }
    else if (kt == 6) { asm volatile("s_waitcnt vmcnt(4)" ::: "memory"); }
    else              { asm volatile("s_waitcnt vmcnt(0)" ::: "memory"); }
    __builtin_amdgcn_sched_barrier(0);
    __builtin_amdgcn_s_barrier();
    __builtin_amdgcn_sched_barrier(0);

    #pragma unroll
    for (int c = 0; c < 2; c++){
      short8 fa[2], fb[2];
      #pragma unroll
      for (int f = 0; f < 2; f++){
        int fra = wr*32 + f*16 + lrow;
        fa[f] = *(const short8*)&SM[bf][0][fra*64 + (((c*4+glog) ^ (fra&7))<<3)];
        int frb = wc*32 + f*16 + lrow;
        fb[f] = *(const short8*)&SM[bf][1][frb*64 + (((c*4+glog) ^ (frb&7))<<3)];
      }
      __builtin_amdgcn_s_setprio(1);
      #pragma unroll
      for (int fi = 0; fi < 2; fi++)
        #pragma unroll
        for (int fj = 0; fj < 2; fj++)
          acc[fi][fj] = __builtin_amdgcn_mfma_f32_16x16x32_bf16(fa[fi], fb[fj], acc[fi][fj], 0,0,0);
      __builtin_amdgcn_s_setprio(0);
    }
  }
  #undef NISSUE

  #pragma unroll
  for (int fi = 0; fi < 2; fi++)
    #pragma unroll
    for (int fj = 0; fj < 2; fj++)
      #pragma unroll
      for (int e = 0; e < 4; e++){
        int gi = i0 + wr*32 + fi*16 + (lane>>4)*4 + e;
        int gj = j0 + wc*32 + fj*16 + lrow;
        size_t o = (size_t)gi*NDIM + gj;
        if (half) Pn[o] = f2bf(bf2f(P[o]) + acc[fi][fj][e]);
        else      En[o] = f2bf(acc[fi][fj][e]);
      }
}

// ------- final2: VI = P + P*E3  (R == E3 identity; E3,P symmetric) -> VIh/VIl -------
__global__ __launch_bounds__(256) void k_final2(const unsigned short* __restrict__ P,
      const unsigned short* __restrict__ E3,
      unsigned short* __restrict__ VIh, unsigned short* __restrict__ VIl){
  int b = blockIdx.x;
  int i0 = (b>>3)*64, j0 = (b&7)*64;
  __shared__ __align__(16) unsigned short SM[4][2][64*32];
  int t = threadIdx.x, lane = t & 63, wave = t >> 6;
  int wr = wave >> 1, wc = wave & 1;
  int lrow = lane & 15, glog = lane >> 4;
  f32x4 acc[2][2];
  #pragma unroll
  for (int a = 0; a < 2; a++)
    #pragma unroll
    for (int c = 0; c < 2; c++) acc[a][c] = (f32x4){0.f,0.f,0.f,0.f};

  int srow = lane >> 2;
  int sg4  = (lane & 3) ^ ((srow >> 1) & 3);
  const unsigned short* s0 = P  + (size_t)(i0 + wave*16 + srow)*NDIM + sg4*8;
  const unsigned short* s1 = E3 + (size_t)(j0 + wave*16 + srow)*NDIM + sg4*8;

  #define FISSUE(batch) { int kb = (batch)*32; int bf = (batch)&3; \
    gload16(s0 + kb, &SM[bf][0][wave*512]); \
    gload16(s1 + kb, &SM[bf][1][wave*512]); }

  FISSUE(0); FISSUE(1);
  for (int kt = 0; kt < 16; kt++){
    int bf = kt & 3;
    if (kt + 2 < 16) FISSUE(kt + 2);
    if (kt <= 13)      { asm volatile("s_waitcnt vmcnt(4)" ::: "memory"); }
    else if (kt == 14) { asm volatile("s_waitcnt vmcnt(2)" ::: "memory"); }
    else               { asm volatile("s_waitcnt vmcnt(0)" ::: "memory"); }
    __builtin_amdgcn_sched_barrier(0);
    __builtin_amdgcn_s_barrier();
    __builtin_amdgcn_sched_barrier(0);

    short8 fa[2], fb[2];
    #pragma unroll
    for (int f = 0; f < 2; f++){
      int fra = wr*32 + f*16 + lrow;
      fa[f] = *(const short8*)&SM[bf][0][fra*32 + ((glog ^ ((fra>>1)&3))<<3)];
      int frb = wc*32 + f*16 + lrow;
      fb[f] = *(const short8*)&SM[bf][1][frb*32 + ((glog ^ ((frb>>1)&3))<<3)];
    }
    __builtin_amdgcn_s_setprio(1);
    #pragma unroll
    for (int fi = 0; fi < 2; fi++)
      #pragma unroll
      for (int fj = 0; fj < 2; fj++)
        acc[fi][fj] = __builtin_amdgcn_mfma_f32_16x16x32_bf16(fa[fi], fb[fj], acc[fi][fj], 0,0,0);
    __builtin_amdgcn_s_setprio(0);
  }
  #undef FISSUE

  #pragma unroll
  for (int fi = 0; fi < 2; fi++)
    #pragma unroll
    for (int fj = 0; fj < 2; fj++)
      #pragma unroll
      for (int e = 0; e < 4; e++){
        int gi = i0 + wr*32 + fi*16 + (lane>>4)*4 + e;
        int gj = j0 + wc*32 + fj*16 + lrow;
        size_t o = (size_t)gi*NDIM + gj;
        float vi = bf2f(P[o]) + acc[fi][fj][e];
        unsigned short hi = f2bf(vi);
        VIh[o] = hi; VIl[o] = f2bf(vi - bf2f(hi));
      }
}

// ------- Z2: 16-wave, tile 128(i) x 64(a), 3-buf DMA pipeline; fused q partials -------
__global__ __launch_bounds__(1024) void k_gemmZ2(const unsigned short* __restrict__ Xth,
    const unsigned short* __restrict__ Xtl, const unsigned short* __restrict__ VIh,
    const unsigned short* __restrict__ VIl, unsigned short* __restrict__ Zt,
    float* __restrict__ q){
  int i0 = blockIdx.x * 128, j0 = blockIdx.y * 64;
  __shared__ __align__(16) unsigned short SMA[3][2][128*32];
  __shared__ __align__(16) unsigned short SMB[3][2][64*32];
  int t = threadIdx.x, lane = t & 63, wave = t >> 6;
  int wr = wave >> 2, wc = wave & 3;
  f32x4 acc[2];
  acc[0] = (f32x4){0.f,0.f,0.f,0.f}; acc[1] = (f32x4){0.f,0.f,0.f,0.f};

  int srow = lane >> 2;
  int sgk  = (lane & 3) ^ ((srow >> 1) & 3);
  int lrow = lane & 15, glog = lane >> 4;

  const unsigned short* srcA0 = Xth + (size_t)(i0 + (wave&7)*16 + srow)*NDIM + sgk*8;
  const unsigned short* srcA1 = Xtl + (size_t)(i0 + (wave&7)*16 + srow)*NDIM + sgk*8;
  int gB = wave & 3;
  const unsigned short* srcB = ((wave < 12) ? VIh : VIl) + (size_t)(j0 + gB*16 + srow)*NDIM + sgk*8;
  int mB = (wave < 12) ? 0 : 1;
  int gA = wave & 7;

  #define ZISSUE(batch) { int kb = (batch)*32; int bf = (batch)%3; \
    if (wave < 8){ gload16(srcA0 + kb, &SMA[bf][0][gA*512]); \
                   gload16(srcA1 + kb, &SMA[bf][1][gA*512]); } \
    else         { gload16(srcB  + kb, &SMB[bf][mB][gB*512]); } }

  ZISSUE(0); ZISSUE(1);
  for (int kt = 0; kt < 16; kt++){
    int bf = kt % 3;
    if (kt + 2 < 16) ZISSUE(kt + 2);
    if (wave < 8){
      if (kt < 14)       { asm volatile("s_waitcnt vmcnt(4)" ::: "memory"); }
      else if (kt == 14) { asm volatile("s_waitcnt vmcnt(2)" ::: "memory"); }
      else               { asm volatile("s_waitcnt vmcnt(0)" ::: "memory"); }
    } else {
      if (kt < 14)       { asm volatile("s_waitcnt vmcnt(2)" ::: "memory"); }
      else if (kt == 14) { asm volatile("s_waitcnt vmcnt(1)" ::: "memory"); }
      else               { asm volatile("s_waitcnt vmcnt(0)" ::: "memory"); }
    }
    __builtin_amdgcn_sched_barrier(0);
    __builtin_amdgcn_s_barrier();
    __builtin_amdgcn_sched_barrier(0);

    short8 ah[2], al[2], bh, bl;
    #pragma unroll
    for (int f = 0; f < 2; f++){
      int fra = wr*32 + f*16 + lrow;
      int offa = fra*32 + ((glog ^ ((fra>>1)&3))<<3);
      ah[f] = *(const short8*)&SMA[bf][0][offa];
      al[f] = *(const short8*)&SMA[bf][1][offa];
    }
    {
      int frb = wc*16 + lrow;
      int offb = frb*32 + ((glog ^ ((frb>>1)&3))<<3);
      bh = *(const short8*)&SMB[bf][0][offb];
      bl = *(const short8*)&SMB[bf][1][offb];
    }
    __builtin_amdgcn_s_setprio(1);
    #pragma unroll
    for (int fi = 0; fi < 2; fi++){
      acc[fi] = __builtin_amdgcn_mfma_f32_16x16x32_bf16(ah[fi], bh, acc[fi], 0,0,0);
      acc[fi] = __builtin_amdgcn_mfma_f32_16x16x32_bf16(ah[fi], bl, acc[fi], 0,0,0);
      acc[fi] = __builtin_amdgcn_mfma_f32_16x16x32_bf16(al[fi], bh, acc[fi], 0,0,0);
    }
    __builtin_amdgcn_s_setprio(0);
    __builtin_amdgcn_sched_barrier(0);
    __builtin_amdgcn_s_barrier();
  }
  #undef ZISSUE

  // epilogue: write Zt and accumulate q[gi] partial dot over this block's 64 columns
  #pragma unroll
  for (int fi = 0; fi < 2; fi++)
    #pragma unroll
    for (int e = 0; e < 4; e++){
      int gi = i0 + wr*32 + fi*16 + (lane>>4)*4 + e;
      int gj = j0 + wc*16 + lrow;
      size_t o = (size_t)gi*NDIM + gj;
      unsigned short zb = f2bf(acc[fi][e]);
      Zt[o] = zb;
      float p = bf2f(zb) * bf2f(Xth[o]);
      p += __shfl_xor(p, 1, 64);
      p += __shfl_xor(p, 2, 64);
      p += __shfl_xor(p, 4, 64);
      p += __shfl_xor(p, 8, 64);
      if (lrow == 0) atomicAdd(&q[gi], p);
    }
}

// ------- G: 16-wave, BK=32, 4-buffer, double-step windows, one barrier per window -------
__global__ __launch_bounds__(1024) void k_G(const unsigned short* __restrict__ Xt,
        const unsigned short* __restrict__ Zt, const float* __restrict__ q,
        float* __restrict__ out){
  const int NT = NPTS/128; // 32
  int b = (int)blockIdx.x;
  b = (b & 7) * 66 + (b >> 3);     // XCD-bijective chunking (528 = 8*66)
  int ti = 0, rem = b;
  while (rem >= NT - ti){ rem -= NT - ti; ti++; }
  int tj = ti + rem;
  int i0 = ti*128, j0 = tj*128;

  __shared__ __align__(16) unsigned short SMEM[2*4*128*32];
  unsigned short (*At)[128*32] = (unsigned short (*)[128*32])SMEM;
  unsigned short (*Bt)[128*32] = (unsigned short (*)[128*32])(SMEM + 4*128*32);
  float* fsm = (float*)SMEM;

  int t = threadIdx.x, lane = t & 63, wave = t >> 6;   // wave 0..15
  int wr = wave >> 2, wc = wave & 3;                   // 4x4 wave grid, 32x32 sub-tile each
  f32x4 acc[2][2];
  #pragma unroll
  for (int a = 0; a < 2; a++)
    #pragma unroll
    for (int c = 0; c < 2; c++) acc[a][c] = (f32x4){0.f,0.f,0.f,0.f};

  int srow = lane >> 2;
  int sgk  = (lane & 3) ^ ((srow >> 1) & 3);
  int lrow = lane & 15;
  int glog = lane >> 4;

  int sg = wave & 7;
  int srcrow = sg*16 + srow;
  const unsigned short* src = (wave < 8)
      ? (Xt + (size_t)(i0 + srcrow)*NDIM + sgk*8)
      : (Zt + (size_t)(j0 + srcrow)*NDIM + sgk*8);
  unsigned short (*dstb)[128*32] = (wave < 8) ? At : Bt;

  #define ISSUE(batch) { int kb = (batch)*32; int bf = (batch)&3; \
    gload16(src + kb, &dstb[bf][sg*512]); }

  ISSUE(0); ISSUE(1);

  #pragma unroll
  for (int kt = 0; kt < 16; kt += 2){
    asm volatile("s_waitcnt vmcnt(0)" ::: "memory");
    __builtin_amdgcn_sched_barrier(0);
    __builtin_amdgcn_s_barrier();
    __builtin_amdgcn_sched_barrier(0);
    if (kt + 2 < 16){ ISSUE(kt + 2); ISSUE(kt + 3); }

    #pragma unroll
    for (int s2 = 0; s2 < 2; s2++){
      int cur = (kt + s2) & 3;
      short8 af[2], bfr[2];
      #pragma unroll
      for (int f = 0; f < 2; f++){
        int fra = wr*32 + f*16 + lrow;
        int frb = wc*32 + f*16 + lrow;
        af[f]  = *(const short8*)&At[cur][fra*32 + ((glog ^ ((fra>>1)&3))<<3)];
        bfr[f] = *(const short8*)&Bt[cur][frb*32 + ((glog ^ ((frb>>1)&3))<<3)];
      }
      __builtin_amdgcn_s_setprio(1);
      #pragma unroll
      for (int fi = 0; fi < 2; fi++)
        #pragma unroll
        for (int fj = 0; fj < 2; fj++)
          acc[fi][fj] = __builtin_amdgcn_mfma_f32_16x16x32_bf16(af[fi], bfr[fj], acc[fi][fj], 0, 0, 0);
      __builtin_amdgcn_s_setprio(0);
    }
  }
  #undef ISSUE
  __syncthreads();   // all reads done before epilogue overwrites SMEM

  #pragma unroll
  for (int fi = 0; fi < 2; fi++)
    #pragma unroll
    for (int fj = 0; fj < 2; fj++)
      #pragma unroll
      for (int e = 0; e < 4; e++){
        int r = wr*32 + fi*16 + (lane >> 4)*4 + e;
        int c = wc*32 + fj*16 + lrow;
        fsm[r*128 + c] = acc[fi][fj][e];
      }
  __syncthreads();

  #pragma unroll
  for (int i = 0; i < 8; i++){
    int row = wave*8 + i;
    int gi = i0 + row;
    float qi = q[gi];
    size_t rowbase = (size_t)gi*NPTS - ((size_t)gi*(gi+1))/2 - (size_t)gi - 1;
    float2 vv = *(float2*)&fsm[row*128 + lane*2];
    int gj0 = j0 + lane*2, gj1 = gj0 + 1;
    if (gi < gj0) out[rowbase + gj0] = sqrtf(fmaxf(qi + q[gj0] - 2.0f*vv.x, 1e-12f));
    if (gi < gj1) out[rowbase + gj1] = sqrtf(fmaxf(qi + q[gj1] - 2.0f*vv.y, 1e-12f));
  }
}

extern "C" void kernel_launch(void* const* d_in, const int* in_sizes, int n_in,
                              void* d_out, int out_size, void* d_ws, size_t ws_size,
                              hipStream_t stream) {
  (void)in_sizes; (void)n_in; (void)out_size; (void)ws_size;
  const float* x0 = (const float*)d_in[0];
  const float* x1 = (const float*)d_in[1];
  float* out = (float*)d_out;

  char* w = (char*)d_ws;
  float* mu     = (float*)w; w += 4096;
  float* q      = (float*)w; w += NPTS*4;
  unsigned short* E0 = (unsigned short*)w; w += (size_t)NDIM*NDIM*2;
  unsigned short* E1 = (unsigned short*)w; w += (size_t)NDIM*NDIM*2;
  unsigned short* P0 = (unsigned short*)w; w += (size_t)NDIM*NDIM*2;
  unsigned short* P1 = (unsigned short*)w; w += (size_t)NDIM*NDIM*2;
  unsigned short* Xch = (unsigned short*)w; w += (size_t)NDIM*NPTS*2;
  unsigned short* Xth = (unsigned short*)w; w += (size_t)NDIM*NPTS*2;
  unsigned short* Xtl = (unsigned short*)w; w += (size_t)NDIM*NPTS*2;
  char* uspan = w;
  unsigned short* VIh = (unsigned short*)uspan;
  unsigned short* VIl = VIh + (size_t)NDIM*NDIM;
  unsigned short* Zt  = VIl + (size_t)NDIM*NDIM;
  float* Vp = (float*)uspan;  // VZ x 1MB partials, dead after k_finVinit

  k_rowmean<<<dim3(512), dim3(256), 0, stream>>>(x0, x1, mu, q);
  k_prep<<<dim3(64,8), dim3(256), 0, stream>>>(x0, x1, mu, Xch, Xth, Xtl);
  k_V2<<<dim3(10, VZ), dim3(1024), 0, stream>>>(Xch, Vp);
  k_finVinit<<<dim3(512), dim3(64), 0, stream>>>(Vp, E0, P0);

  unsigned short *Ec = E0, *En = E1, *Pc = P0, *Pn = P1;
  for (int it = 0; it < 3; ++it){
    k_ns2<<<dim3(128), dim3(256), 0, stream>>>(Ec, Pc, En, Pn);
    unsigned short* tmp;
    tmp = Ec; Ec = En; En = tmp;
    tmp = Pc; Pc = Pn; Pn = tmp;
  }
  k_final2<<<dim3(64), dim3(256), 0, stream>>>(Pc, Ec, VIh, VIl);
  k_gemmZ2<<<dim3(32,8), dim3(1024), 0, stream>>>(Xth, Xtl, VIh, VIl, Zt, q);
  k_G<<<dim3(528), dim3(1024), 0, stream>>>(Xth, Zt, q, out);
}

// Round 20
// 101.218 us; speedup vs baseline: 1.7759x; 1.0187x over previous
//
#include <hip/hip_runtime.h>
#include <hip/hip_bf16.h>
#include <math.h>

#define NDIM 512
#define NPTS 4096
#define VZ 16

typedef __attribute__((ext_vector_type(4))) float f32x4;
typedef __attribute__((ext_vector_type(8))) short short8;

__device__ __forceinline__ const float* xrow(const float* x0, const float* x1, int r){
  return (r < 256) ? (x0 + (size_t)r * NPTS) : (x1 + (size_t)(r - 256) * NPTS);
}
__device__ __forceinline__ unsigned short f2bf(float f){
  __hip_bfloat16 h = __float2bfloat16(f);
  return *reinterpret_cast<unsigned short*>(&h);
}
__device__ __forceinline__ float bf2f(unsigned short u){
  return __uint_as_float(((unsigned int)u) << 16);
}
__device__ __forceinline__ void gload16(const void* g, void* l){
  __builtin_amdgcn_global_load_lds((const __attribute__((address_space(1))) void*)g,
                                   (__attribute__((address_space(3))) void*)l, 16, 0, 0);
}

// ---------------- row means of X (512 rows x 4096); also zeroes q ----------------
__global__ void k_rowmean(const float* __restrict__ x0, const float* __restrict__ x1,
                          float* __restrict__ mu, float* __restrict__ q){
  int r = blockIdx.x;
  if (threadIdx.x < 8) q[r*8 + threadIdx.x] = 0.f;   // 512 blocks x 8 = 4096
  const float4* row4 = (const float4*)xrow(x0, x1, r);
  float s = 0.f;
  for (int c = threadIdx.x; c < NPTS/4; c += 256){
    float4 v = row4[c];
    s += v.x + v.y + v.z + v.w;
  }
  __shared__ float red[256];
  red[threadIdx.x] = s; __syncthreads();
  for (int off = 128; off > 0; off >>= 1){
    if (threadIdx.x < off) red[threadIdx.x] += red[threadIdx.x + off];
    __syncthreads();
  }
  if (threadIdx.x == 0) mu[r] = red[0] * (1.0f / NPTS);
}

// ------- prep: centered X in bf16; row-major hi (Xch) + transposed hi/lo (Xth/Xtl) -------
__global__ __launch_bounds__(256) void k_prep(const float* __restrict__ x0, const float* __restrict__ x1,
      const float* __restrict__ mu,
      unsigned short* __restrict__ Xch,
      unsigned short* __restrict__ Xth, unsigned short* __restrict__ Xtl){
  __shared__ float tile[64][65];
  int i0 = blockIdx.x * 64, a0 = blockIdx.y * 64;
  int t = threadIdx.x;
  int r = t >> 2, cg = (t & 3) * 16;
  const float* row = xrow(x0, x1, a0 + r);
  float m = mu[a0 + r];
  unsigned short h16[16] __attribute__((aligned(16)));
  #pragma unroll
  for (int e = 0; e < 16; e += 4){
    float4 v = *(const float4*)(row + i0 + cg + e);
    v.x -= m; v.y -= m; v.z -= m; v.w -= m;
    tile[r][cg+e] = v.x; tile[r][cg+e+1] = v.y; tile[r][cg+e+2] = v.z; tile[r][cg+e+3] = v.w;
    h16[e]   = f2bf(v.x);
    h16[e+1] = f2bf(v.y);
    h16[e+2] = f2bf(v.z);
    h16[e+3] = f2bf(v.w);
  }
  unsigned short* dst = Xch + (size_t)(a0+r)*NPTS + i0 + cg;
  *(uint4*)dst = *(uint4*)&h16[0]; *(uint4*)(dst+8) = *(uint4*)&h16[8];
  __syncthreads();
  unsigned short th[16] __attribute__((aligned(16)));
  unsigned short tl[16] __attribute__((aligned(16)));
  #pragma unroll
  for (int e = 0; e < 16; e++){
    float v = tile[cg+e][r];
    th[e] = f2bf(v); tl[e] = f2bf(v - bf2f(th[e]));
  }
  unsigned short* d2 = Xth + (size_t)(i0 + r)*NDIM + a0 + cg;
  *(uint4*)d2 = *(uint4*)&th[0]; *(uint4*)(d2+8) = *(uint4*)&th[8];
  d2 = Xtl + (size_t)(i0 + r)*NDIM + a0 + cg;
  *(uint4*)d2 = *(uint4*)&tl[0]; *(uint4*)(d2+8) = *(uint4*)&tl[8];
}

// ------- V2: hi-only. 16-wave blocks, 128x128 tri-tiles x 16 K-slices, 3-buf DMA -------
__global__ __launch_bounds__(1024) void k_V2(const unsigned short* __restrict__ Xch,
        float* __restrict__ Vp){
  int b = blockIdx.x;                  // 0..9 upper-tri tile of 4x4
  int ti = 0, rem = b;
  while (rem >= 4 - ti){ rem -= 4 - ti; ti++; }
  int tj = ti + rem;
  int i0 = ti*128, j0 = tj*128;
  int z = blockIdx.y;                  // 0..15
  size_t kbase = (size_t)z * (NPTS/VZ);  // 256-wide K slice

  __shared__ __align__(16) unsigned short SM[3][2][128*32];  // {Ah,Bh} x 8KB, 3 bufs = 48KB
  int t = threadIdx.x, lane = t & 63, wave = t >> 6;
  int wr = wave >> 2, wc = wave & 3;
  f32x4 acc[2][2];
  #pragma unroll
  for (int a = 0; a < 2; a++)
    #pragma unroll
    for (int c = 0; c < 2; c++) acc[a][c] = (f32x4){0.f,0.f,0.f,0.f};

  int srow = lane >> 2;
  int sgk  = (lane & 3) ^ ((srow >> 1) & 3);
  int lrow = lane & 15, glog = lane >> 4;

  int m0 = wave >> 3, g0 = wave & 7;
  int r0 = ((m0 == 0) ? i0 : j0) + g0*16 + srow;
  const unsigned short* src0 = Xch + (size_t)r0*NPTS + kbase + sgk*8;

  #define VISSUE(batch) { int kb = (batch)*32; int bf = (batch)%3; \
    gload16(src0 + kb, &SM[bf][m0][g0*512]); }

  VISSUE(0); VISSUE(1);
  for (int kt = 0; kt < 8; kt++){
    int bf = kt % 3;
    if (kt + 2 < 8) VISSUE(kt + 2);
    if (kt < 6)       { asm volatile("s_waitcnt vmcnt(2)" ::: "memory"); }
    else if (kt == 6) { asm volatile("s_waitcnt vmcnt(1)" ::: "memory"); }
    else              { asm volatile("s_waitcnt vmcnt(0)" ::: "memory"); }
    __builtin_amdgcn_sched_barrier(0);
    __builtin_amdgcn_s_barrier();
    __builtin_amdgcn_sched_barrier(0);

    short8 ah[2], bh[2];
    #pragma unroll
    for (int f = 0; f < 2; f++){
      int fra = wr*32 + f*16 + lrow;
      ah[f] = *(const short8*)&SM[bf][0][fra*32 + ((glog ^ ((fra>>1)&3))<<3)];
      int frb = wc*32 + f*16 + lrow;
      bh[f] = *(const short8*)&SM[bf][1][frb*32 + ((glog ^ ((frb>>1)&3))<<3)];
    }
    __builtin_amdgcn_s_setprio(1);
    #pragma unroll
    for (int fi = 0; fi < 2; fi++)
      #pragma unroll
      for (int fj = 0; fj < 2; fj++)
        acc[fi][fj] = __builtin_amdgcn_mfma_f32_16x16x32_bf16(ah[fi], bh[fj], acc[fi][fj], 0,0,0);
    __builtin_amdgcn_s_setprio(0);
    __builtin_amdgcn_sched_barrier(0);
    __builtin_amdgcn_s_barrier();
  }
  #undef VISSUE

  float* dst = Vp + (size_t)z*NDIM*NDIM;
  #pragma unroll
  for (int fi = 0; fi < 2; fi++)
    #pragma unroll
    for (int fj = 0; fj < 2; fj++)
      #pragma unroll
      for (int e = 0; e < 4; e++){
        int gi = i0 + wr*32 + fi*16 + (lane>>4)*4 + e;
        int gj = j0 + wc*32 + fj*16 + lrow;
        dst[(size_t)gi*NDIM + gj] = acc[fi][fj][e];
        if (ti != tj) dst[(size_t)gj*NDIM + gi] = acc[fi][fj][e];
      }
}

// ------- finVinit: V=sum(Vp)/4095 (regs only); E0 = I - cV -------
__global__ void k_finVinit(const float* __restrict__ Vp,
      unsigned short* __restrict__ E0){
  const float c = 0.869565217f;
  int r = blockIdx.x, lane = threadIdx.x; // 64 threads
  const size_t S = (size_t)NDIM*NDIM;
  float a[8] = {0,0,0,0,0,0,0,0};
  #pragma unroll
  for (int z = 0; z < VZ; z++){
    const float* p = Vp + z*S + (size_t)r*NDIM + lane*8;
    float4 u = *(const float4*)p;
    float4 v = *(const float4*)(p+4);
    a[0]+=u.x; a[1]+=u.y; a[2]+=u.z; a[3]+=u.w;
    a[4]+=v.x; a[5]+=v.y; a[6]+=v.z; a[7]+=v.w;
  }
  const float s = 1.0f/4095.0f;
  unsigned short e8[8] __attribute__((aligned(16)));
  #pragma unroll
  for (int e = 0; e < 8; e++){
    float v = a[e]*s;
    int col = lane*8 + e;
    e8[e] = f2bf(((col==r)?1.f:0.f) - c*v);
  }
  size_t o = (size_t)r*NDIM + lane*8;
  *(uint4*)&E0[o] = *(uint4*)e8;
}

// ------- ns2first: 64 blocks. E1 = E0*E0 (GEMM) ; P1 = c*(E0 + I) (elementwise) -------
__global__ __launch_bounds__(256) void k_ns2first(const unsigned short* __restrict__ E0,
      unsigned short* __restrict__ E1, unsigned short* __restrict__ P1){
  const float c = 0.869565217f;
  int b = blockIdx.x;
  int i0 = (b>>3)*64, j0 = (b&7)*64;
  __shared__ __align__(16) unsigned short SM[4][2][64*64];
  int t = threadIdx.x, lane = t & 63, wave = t >> 6;
  int wr = wave >> 1, wc = wave & 1;
  int lrow = lane & 15, glog = lane >> 4;
  f32x4 acc[2][2];
  #pragma unroll
  for (int a = 0; a < 2; a++)
    #pragma unroll
    for (int cc = 0; cc < 2; cc++) acc[a][cc] = (f32x4){0.f,0.f,0.f,0.f};

  int srow = lane >> 3;
  int sg8  = (lane & 7) ^ (srow & 7);
  int gA0 = wave*2, gA1 = wave*2 + 1;
  const unsigned short* srcA0 = E0 + (size_t)(i0 + gA0*8 + srow)*NDIM + sg8*8;
  const unsigned short* srcA1 = E0 + (size_t)(i0 + gA1*8 + srow)*NDIM + sg8*8;
  const unsigned short* srcB0 = E0 + (size_t)(j0 + gA0*8 + srow)*NDIM + sg8*8;
  const unsigned short* srcB1 = E0 + (size_t)(j0 + gA1*8 + srow)*NDIM + sg8*8;

  #define NISSUE(batch) { int kb = (batch)*64; int bf = (batch)&3; \
    gload16(srcA0 + kb, &SM[bf][0][gA0*512]); \
    gload16(srcA1 + kb, &SM[bf][0][gA1*512]); \
    gload16(srcB0 + kb, &SM[bf][1][gA0*512]); \
    gload16(srcB1 + kb, &SM[bf][1][gA1*512]); }

  NISSUE(0); NISSUE(1);
  for (int kt = 0; kt < 8; kt++){
    int bf = kt & 3;
    if (kt + 2 < 8) NISSUE(kt + 2);
    if (kt <= 5)      { asm volatile("s_waitcnt vmcnt(8)" ::: "memory"); }
    else if (kt == 6) { asm volatile("s_waitcnt vmcnt(4)" ::: "memory"); }
    else              { asm volatile("s_waitcnt vmcnt(0)" ::: "memory"); }
    __builtin_amdgcn_sched_barrier(0);
    __builtin_amdgcn_s_barrier();
    __builtin_amdgcn_sched_barrier(0);

    #pragma unroll
    for (int c2 = 0; c2 < 2; c2++){
      short8 fa[2], fb[2];
      #pragma unroll
      for (int f = 0; f < 2; f++){
        int fra = wr*32 + f*16 + lrow;
        fa[f] = *(const short8*)&SM[bf][0][fra*64 + (((c2*4+glog) ^ (fra&7))<<3)];
        int frb = wc*32 + f*16 + lrow;
        fb[f] = *(const short8*)&SM[bf][1][frb*64 + (((c2*4+glog) ^ (frb&7))<<3)];
      }
      __builtin_amdgcn_s_setprio(1);
      #pragma unroll
      for (int fi = 0; fi < 2; fi++)
        #pragma unroll
        for (int fj = 0; fj < 2; fj++)
          acc[fi][fj] = __builtin_amdgcn_mfma_f32_16x16x32_bf16(fa[fi], fb[fj], acc[fi][fj], 0,0,0);
      __builtin_amdgcn_s_setprio(0);
    }
  }
  #undef NISSUE

  #pragma unroll
  for (int fi = 0; fi < 2; fi++)
    #pragma unroll
    for (int fj = 0; fj < 2; fj++)
      #pragma unroll
      for (int e = 0; e < 4; e++){
        int gi = i0 + wr*32 + fi*16 + (lane>>4)*4 + e;
        int gj = j0 + wc*32 + fj*16 + lrow;
        size_t o = (size_t)gi*NDIM + gj;
        E1[o] = f2bf(acc[fi][fj][e]);
        P1[o] = f2bf(c*bf2f(E0[o]) + ((gi==gj)?c:0.f));
      }
}

// ------- ns2: DMA-pipelined fused NS iter. blocks 0-63: En=E*E ; 64-127: Pn=P+P*E -------
__global__ __launch_bounds__(256) void k_ns2(const unsigned short* __restrict__ E,
      const unsigned short* __restrict__ P,
      unsigned short* __restrict__ En, unsigned short* __restrict__ Pn){
  int b = blockIdx.x;
  int half = b >> 6, tile = b & 63;
  int i0 = (tile>>3)*64, j0 = (tile&7)*64;
  const unsigned short* Asrc = half ? P : E;
  __shared__ __align__(16) unsigned short SM[4][2][64*64];
  int t = threadIdx.x, lane = t & 63, wave = t >> 6;
  int wr = wave >> 1, wc = wave & 1;
  int lrow = lane & 15, glog = lane >> 4;
  f32x4 acc[2][2];
  #pragma unroll
  for (int a = 0; a < 2; a++)
    #pragma unroll
    for (int c = 0; c < 2; c++) acc[a][c] = (f32x4){0.f,0.f,0.f,0.f};

  int srow = lane >> 3;
  int sg8  = (lane & 7) ^ (srow & 7);
  int gA0 = wave*2, gA1 = wave*2 + 1;
  const unsigned short* srcA0 = Asrc + (size_t)(i0 + gA0*8 + srow)*NDIM + sg8*8;
  const unsigned short* srcA1 = Asrc + (size_t)(i0 + gA1*8 + srow)*NDIM + sg8*8;
  const unsigned short* srcB0 = E + (size_t)(j0 + gA0*8 + srow)*NDIM + sg8*8;
  const unsigned short* srcB1 = E + (size_t)(j0 + gA1*8 + srow)*NDIM + sg8*8;

  #define NISSUE(batch) { int kb = (batch)*64; int bf = (batch)&3; \
    gload16(srcA0 + kb, &SM[bf][0][gA0*512]); \
    gload16(srcA1 + kb, &SM[bf][0][gA1*512]); \
    gload16(srcB0 + kb, &SM[bf][1][gA0*512]); \
    gload16(srcB1 + kb, &SM[bf][1][gA1*512]); }

  NISSUE(0); NISSUE(1);
  for (int kt = 0; kt < 8; kt++){
    int bf = kt & 3;
    if (kt + 2 < 8) NISSUE(kt + 2);
    if (kt <= 5)      { asm volatile("s_waitcnt vmcnt(8)" ::: "memory"); }
    else if (kt == 6) { asm volatile("s_waitcnt vmcnt(4)" ::: "memory"); }
    else              { asm volatile("s_waitcnt vmcnt(0)" ::: "memory"); }
    __builtin_amdgcn_sched_barrier(0);
    __builtin_amdgcn_s_barrier();
    __builtin_amdgcn_sched_barrier(0);

    #pragma unroll
    for (int c = 0; c < 2; c++){
      short8 fa[2], fb[2];
      #pragma unroll
      for (int f = 0; f < 2; f++){
        int fra = wr*32 + f*16 + lrow;
        fa[f] = *(const short8*)&SM[bf][0][fra*64 + (((c*4+glog) ^ (fra&7))<<3)];
        int frb = wc*32 + f*16 + lrow;
        fb[f] = *(const short8*)&SM[bf][1][frb*64 + (((c*4+glog) ^ (frb&7))<<3)];
      }
      __builtin_amdgcn_s_setprio(1);
      #pragma unroll
      for (int fi = 0; fi < 2; fi++)
        #pragma unroll
        for (int fj = 0; fj < 2; fj++)
          acc[fi][fj] = __builtin_amdgcn_mfma_f32_16x16x32_bf16(fa[fi], fb[fj], acc[fi][fj], 0,0,0);
      __builtin_amdgcn_s_setprio(0);
    }
  }
  #undef NISSUE

  #pragma unroll
  for (int fi = 0; fi < 2; fi++)
    #pragma unroll
    for (int fj = 0; fj < 2; fj++)
      #pragma unroll
      for (int e = 0; e < 4; e++){
        int gi = i0 + wr*32 + fi*16 + (lane>>4)*4 + e;
        int gj = j0 + wc*32 + fj*16 + lrow;
        size_t o = (size_t)gi*NDIM + gj;
        if (half) Pn[o] = f2bf(bf2f(P[o]) + acc[fi][fj][e]);
        else      En[o] = f2bf(acc[fi][fj][e]);
      }
}

// ------- final2: VI = P + P*E3  (R == E3 identity; E3,P symmetric) -> VIh/VIl -------
__global__ __launch_bounds__(256) void k_final2(const unsigned short* __restrict__ P,
      const unsigned short* __restrict__ E3,
      unsigned short* __restrict__ VIh, unsigned short* __restrict__ VIl){
  int b = blockIdx.x;
  int i0 = (b>>3)*64, j0 = (b&7)*64;
  __shared__ __align__(16) unsigned short SM[4][2][64*32];
  int t = threadIdx.x, lane = t & 63, wave = t >> 6;
  int wr = wave >> 1, wc = wave & 1;
  int lrow = lane & 15, glog = lane >> 4;
  f32x4 acc[2][2];
  #pragma unroll
  for (int a = 0; a < 2; a++)
    #pragma unroll
    for (int c = 0; c < 2; c++) acc[a][c] = (f32x4){0.f,0.f,0.f,0.f};

  int srow = lane >> 2;
  int sg4  = (lane & 3) ^ ((srow >> 1) & 3);
  const unsigned short* s0 = P  + (size_t)(i0 + wave*16 + srow)*NDIM + sg4*8;
  const unsigned short* s1 = E3 + (size_t)(j0 + wave*16 + srow)*NDIM + sg4*8;

  #define FISSUE(batch) { int kb = (batch)*32; int bf = (batch)&3; \
    gload16(s0 + kb, &SM[bf][0][wave*512]); \
    gload16(s1 + kb, &SM[bf][1][wave*512]); }

  FISSUE(0); FISSUE(1);
  for (int kt = 0; kt < 16; kt++){
    int bf = kt & 3;
    if (kt + 2 < 16) FISSUE(kt + 2);
    if (kt <= 13)      { asm volatile("s_waitcnt vmcnt(4)" ::: "memory"); }
    else if (kt == 14) { asm volatile("s_waitcnt vmcnt(2)" ::: "memory"); }
    else               { asm volatile("s_waitcnt vmcnt(0)" ::: "memory"); }
    __builtin_amdgcn_sched_barrier(0);
    __builtin_amdgcn_s_barrier();
    __builtin_amdgcn_sched_barrier(0);

    short8 fa[2], fb[2];
    #pragma unroll
    for (int f = 0; f < 2; f++){
      int fra = wr*32 + f*16 + lrow;
      fa[f] = *(const short8*)&SM[bf][0][fra*32 + ((glog ^ ((fra>>1)&3))<<3)];
      int frb = wc*32 + f*16 + lrow;
      fb[f] = *(const short8*)&SM[bf][1][frb*32 + ((glog ^ ((frb>>1)&3))<<3)];
    }
    __builtin_amdgcn_s_setprio(1);
    #pragma unroll
    for (int fi = 0; fi < 2; fi++)
      #pragma unroll
      for (int fj = 0; fj < 2; fj++)
        acc[fi][fj] = __builtin_amdgcn_mfma_f32_16x16x32_bf16(fa[fi], fb[fj], acc[fi][fj], 0,0,0);
    __builtin_amdgcn_s_setprio(0);
  }
  #undef FISSUE

  #pragma unroll
  for (int fi = 0; fi < 2; fi++)
    #pragma unroll
    for (int fj = 0; fj < 2; fj++)
      #pragma unroll
      for (int e = 0; e < 4; e++){
        int gi = i0 + wr*32 + fi*16 + (lane>>4)*4 + e;
        int gj = j0 + wc*32 + fj*16 + lrow;
        size_t o = (size_t)gi*NDIM + gj;
        float vi = bf2f(P[o]) + acc[fi][fj][e];
        unsigned short hi = f2bf(vi);
        VIh[o] = hi; VIl[o] = f2bf(vi - bf2f(hi));
      }
}

// ------- Z2: 16-wave, tile 128(i) x 64(a), 3-buf DMA pipeline; fused q partials -------
__global__ __launch_bounds__(1024) void k_gemmZ2(const unsigned short* __restrict__ Xth,
    const unsigned short* __restrict__ Xtl, const unsigned short* __restrict__ VIh,
    const unsigned short* __restrict__ VIl, unsigned short* __restrict__ Zt,
    float* __restrict__ q){
  int i0 = blockIdx.x * 128, j0 = blockIdx.y * 64;
  __shared__ __align__(16) unsigned short SMA[3][2][128*32];
  __shared__ __align__(16) unsigned short SMB[3][2][64*32];
  int t = threadIdx.x, lane = t & 63, wave = t >> 6;
  int wr = wave >> 2, wc = wave & 3;
  f32x4 acc[2];
  acc[0] = (f32x4){0.f,0.f,0.f,0.f}; acc[1] = (f32x4){0.f,0.f,0.f,0.f};

  int srow = lane >> 2;
  int sgk  = (lane & 3) ^ ((srow >> 1) & 3);
  int lrow = lane & 15, glog = lane >> 4;

  const unsigned short* srcA0 = Xth + (size_t)(i0 + (wave&7)*16 + srow)*NDIM + sgk*8;
  const unsigned short* srcA1 = Xtl + (size_t)(i0 + (wave&7)*16 + srow)*NDIM + sgk*8;
  int gB = wave & 3;
  const unsigned short* srcB = ((wave < 12) ? VIh : VIl) + (size_t)(j0 + gB*16 + srow)*NDIM + sgk*8;
  int mB = (wave < 12) ? 0 : 1;
  int gA = wave & 7;

  #define ZISSUE(batch) { int kb = (batch)*32; int bf = (batch)%3; \
    if (wave < 8){ gload16(srcA0 + kb, &SMA[bf][0][gA*512]); \
                   gload16(srcA1 + kb, &SMA[bf][1][gA*512]); } \
    else         { gload16(srcB  + kb, &SMB[bf][mB][gB*512]); } }

  ZISSUE(0); ZISSUE(1);
  for (int kt = 0; kt < 16; kt++){
    int bf = kt % 3;
    if (kt + 2 < 16) ZISSUE(kt + 2);
    if (wave < 8){
      if (kt < 14)       { asm volatile("s_waitcnt vmcnt(4)" ::: "memory"); }
      else if (kt == 14) { asm volatile("s_waitcnt vmcnt(2)" ::: "memory"); }
      else               { asm volatile("s_waitcnt vmcnt(0)" ::: "memory"); }
    } else {
      if (kt < 14)       { asm volatile("s_waitcnt vmcnt(2)" ::: "memory"); }
      else if (kt == 14) { asm volatile("s_waitcnt vmcnt(1)" ::: "memory"); }
      else               { asm volatile("s_waitcnt vmcnt(0)" ::: "memory"); }
    }
    __builtin_amdgcn_sched_barrier(0);
    __builtin_amdgcn_s_barrier();
    __builtin_amdgcn_sched_barrier(0);

    short8 ah[2], al[2], bh, bl;
    #pragma unroll
    for (int f = 0; f < 2; f++){
      int fra = wr*32 + f*16 + lrow;
      int offa = fra*32 + ((glog ^ ((fra>>1)&3))<<3);
      ah[f] = *(const short8*)&SMA[bf][0][offa];
      al[f] = *(const short8*)&SMA[bf][1][offa];
    }
    {
      int frb = wc*16 + lrow;
      int offb = frb*32 + ((glog ^ ((frb>>1)&3))<<3);
      bh = *(const short8*)&SMB[bf][0][offb];
      bl = *(const short8*)&SMB[bf][1][offb];
    }
    __builtin_amdgcn_s_setprio(1);
    #pragma unroll
    for (int fi = 0; fi < 2; fi++){
      acc[fi] = __builtin_amdgcn_mfma_f32_16x16x32_bf16(ah[fi], bh, acc[fi], 0,0,0);
      acc[fi] = __builtin_amdgcn_mfma_f32_16x16x32_bf16(ah[fi], bl, acc[fi], 0,0,0);
      acc[fi] = __builtin_amdgcn_mfma_f32_16x16x32_bf16(al[fi], bh, acc[fi], 0,0,0);
    }
    __builtin_amdgcn_s_setprio(0);
    __builtin_amdgcn_sched_barrier(0);
    __builtin_amdgcn_s_barrier();
  }
  #undef ZISSUE

  #pragma unroll
  for (int fi = 0; fi < 2; fi++)
    #pragma unroll
    for (int e = 0; e < 4; e++){
      int gi = i0 + wr*32 + fi*16 + (lane>>4)*4 + e;
      int gj = j0 + wc*16 + lrow;
      size_t o = (size_t)gi*NDIM + gj;
      unsigned short zb = f2bf(acc[fi][e]);
      Zt[o] = zb;
      float p = bf2f(zb) * bf2f(Xth[o]);
      p += __shfl_xor(p, 1, 64);
      p += __shfl_xor(p, 2, 64);
      p += __shfl_xor(p, 4, 64);
      p += __shfl_xor(p, 8, 64);
      if (lrow == 0) atomicAdd(&q[gi], p);
    }
}

// ------- G: 16-wave, BK=32, 4-buffer, double-step windows, one barrier per window -------
__global__ __launch_bounds__(1024) void k_G(const unsigned short* __restrict__ Xt,
        const unsigned short* __restrict__ Zt, const float* __restrict__ q,
        float* __restrict__ out){
  const int NT = NPTS/128; // 32
  int b = (int)blockIdx.x;
  b = (b & 7) * 66 + (b >> 3);     // XCD-bijective chunking (528 = 8*66)
  int ti = 0, rem = b;
  while (rem >= NT - ti){ rem -= NT - ti; ti++; }
  int tj = ti + rem;
  int i0 = ti*128, j0 = tj*128;

  __shared__ __align__(16) unsigned short SMEM[2*4*128*32];
  unsigned short (*At)[128*32] = (unsigned short (*)[128*32])SMEM;
  unsigned short (*Bt)[128*32] = (unsigned short (*)[128*32])(SMEM + 4*128*32);
  float* fsm = (float*)SMEM;

  int t = threadIdx.x, lane = t & 63, wave = t >> 6;   // wave 0..15
  int wr = wave >> 2, wc = wave & 3;                   // 4x4 wave grid, 32x32 sub-tile each
  f32x4 acc[2][2];
  #pragma unroll
  for (int a = 0; a < 2; a++)
    #pragma unroll
    for (int c = 0; c < 2; c++) acc[a][c] = (f32x4){0.f,0.f,0.f,0.f};

  int srow = lane >> 2;
  int sgk  = (lane & 3) ^ ((srow >> 1) & 3);
  int lrow = lane & 15;
  int glog = lane >> 4;

  int sg = wave & 7;
  int srcrow = sg*16 + srow;
  const unsigned short* src = (wave < 8)
      ? (Xt + (size_t)(i0 + srcrow)*NDIM + sgk*8)
      : (Zt + (size_t)(j0 + srcrow)*NDIM + sgk*8);
  unsigned short (*dstb)[128*32] = (wave < 8) ? At : Bt;

  #define ISSUE(batch) { int kb = (batch)*32; int bf = (batch)&3; \
    gload16(src + kb, &dstb[bf][sg*512]); }

  ISSUE(0); ISSUE(1);

  #pragma unroll
  for (int kt = 0; kt < 16; kt += 2){
    asm volatile("s_waitcnt vmcnt(0)" ::: "memory");
    __builtin_amdgcn_sched_barrier(0);
    __builtin_amdgcn_s_barrier();
    __builtin_amdgcn_sched_barrier(0);
    if (kt + 2 < 16){ ISSUE(kt + 2); ISSUE(kt + 3); }

    #pragma unroll
    for (int s2 = 0; s2 < 2; s2++){
      int cur = (kt + s2) & 3;
      short8 af[2], bfr[2];
      #pragma unroll
      for (int f = 0; f < 2; f++){
        int fra = wr*32 + f*16 + lrow;
        int frb = wc*32 + f*16 + lrow;
        af[f]  = *(const short8*)&At[cur][fra*32 + ((glog ^ ((fra>>1)&3))<<3)];
        bfr[f] = *(const short8*)&Bt[cur][frb*32 + ((glog ^ ((frb>>1)&3))<<3)];
      }
      __builtin_amdgcn_s_setprio(1);
      #pragma unroll
      for (int fi = 0; fi < 2; fi++)
        #pragma unroll
        for (int fj = 0; fj < 2; fj++)
          acc[fi][fj] = __builtin_amdgcn_mfma_f32_16x16x32_bf16(af[fi], bfr[fj], acc[fi][fj], 0, 0, 0);
      __builtin_amdgcn_s_setprio(0);
    }
  }
  #undef ISSUE
  __syncthreads();   // all reads done before epilogue overwrites SMEM

  #pragma unroll
  for (int fi = 0; fi < 2; fi++)
    #pragma unroll
    for (int fj = 0; fj < 2; fj++)
      #pragma unroll
      for (int e = 0; e < 4; e++){
        int r = wr*32 + fi*16 + (lane >> 4)*4 + e;
        int c = wc*32 + fj*16 + lrow;
        fsm[r*128 + c] = acc[fi][fj][e];
      }
  __syncthreads();

  #pragma unroll
  for (int i = 0; i < 8; i++){
    int row = wave*8 + i;
    int gi = i0 + row;
    float qi = q[gi];
    size_t rowbase = (size_t)gi*NPTS - ((size_t)gi*(gi+1))/2 - (size_t)gi - 1;
    float2 vv = *(float2*)&fsm[row*128 + lane*2];
    int gj0 = j0 + lane*2, gj1 = gj0 + 1;
    if (gi < gj0) out[rowbase + gj0] = sqrtf(fmaxf(qi + q[gj0] - 2.0f*vv.x, 1e-12f));
    if (gi < gj1) out[rowbase + gj1] = sqrtf(fmaxf(qi + q[gj1] - 2.0f*vv.y, 1e-12f));
  }
}

extern "C" void kernel_launch(void* const* d_in, const int* in_sizes, int n_in,
                              void* d_out, int out_size, void* d_ws, size_t ws_size,
                              hipStream_t stream) {
  (void)in_sizes; (void)n_in; (void)out_size; (void)ws_size;
  const float* x0 = (const float*)d_in[0];
  const float* x1 = (const float*)d_in[1];
  float* out = (float*)d_out;

  char* w = (char*)d_ws;
  float* mu     = (float*)w; w += 4096;
  float* q      = (float*)w; w += NPTS*4;
  unsigned short* E0 = (unsigned short*)w; w += (size_t)NDIM*NDIM*2;
  unsigned short* E1 = (unsigned short*)w; w += (size_t)NDIM*NDIM*2;
  unsigned short* P0 = (unsigned short*)w; w += (size_t)NDIM*NDIM*2;
  unsigned short* P1 = (unsigned short*)w; w += (size_t)NDIM*NDIM*2;
  unsigned short* Xch = (unsigned short*)w; w += (size_t)NDIM*NPTS*2;
  unsigned short* Xth = (unsigned short*)w; w += (size_t)NDIM*NPTS*2;
  unsigned short* Xtl = (unsigned short*)w; w += (size_t)NDIM*NPTS*2;
  char* uspan = w;
  unsigned short* VIh = (unsigned short*)uspan;
  unsigned short* VIl = VIh + (size_t)NDIM*NDIM;
  unsigned short* Zt  = VIl + (size_t)NDIM*NDIM;
  float* Vp = (float*)uspan;  // VZ x 1MB partials, dead after k_finVinit

  k_rowmean<<<dim3(512), dim3(256), 0, stream>>>(x0, x1, mu, q);
  k_prep<<<dim3(64,8), dim3(256), 0, stream>>>(x0, x1, mu, Xch, Xth, Xtl);
  k_V2<<<dim3(10, VZ), dim3(1024), 0, stream>>>(Xch, Vp);
  k_finVinit<<<dim3(512), dim3(64), 0, stream>>>(Vp, E0);

  // chain: E0 -> (E1, P1=c(I+E0)) -> (E2,P2) -> (E3,P3) -> VI
  k_ns2first<<<dim3(64), dim3(256), 0, stream>>>(E0, E1, P0);       // E1, P1(in P0)
  k_ns2<<<dim3(128), dim3(256), 0, stream>>>(E1, P0, E0, P1);       // E2(in E0), P2(in P1)
  k_ns2<<<dim3(128), dim3(256), 0, stream>>>(E0, P1, E1, P0);       // E3(in E1), P3(in P0)
  k_final2<<<dim3(64), dim3(256), 0, stream>>>(P0, E1, VIh, VIl);
  k_gemmZ2<<<dim3(32,8), dim3(1024), 0, stream>>>(Xth, Xtl, VIh, VIl, Zt, q);
  k_G<<<dim3(528), dim3(1024), 0, stream>>>(Xth, Zt, q, out);
}